// Round 5
// baseline (5846.891 us; speedup 1.0000x reference)
//
#include <hip/hip_runtime.h>

typedef unsigned short u16;

#define B_   16
#define L_   495
#define D_   384
#define DI_  768
#define DS_  16
#define DTR_ 24

__device__ __forceinline__ float bf2f(u16 u) {
    return __uint_as_float(((unsigned)u) << 16);
}
__device__ __forceinline__ u16 f2bf(float f) {
    unsigned u = __float_as_uint(f);
    unsigned r = 0x7fffu + ((u >> 16) & 1u);
    return (u16)((u + r) >> 16);
}
__device__ __forceinline__ float silu_f(float x) {
    return x / (1.f + __expf(-x));
}

// ---- dtype detector: A_log values are in [0, 2.78]. flag=1 -> bf16, 0 -> f32.
__global__ __launch_bounds__(256) void detect_kernel(
    const u16* __restrict__ alog_raw, int* __restrict__ flag)
{
    __shared__ int s_bad;
    if (threadIdx.x == 0) s_bad = 0;
    __syncthreads();
    int bad = 0;
    for (int i = threadIdx.x; i < 98304; i += 256) {
        float v = bf2f(alog_raw[i]);
        if (!(v >= -1e-3f && v <= 2.8f)) bad = 1;
    }
    if (bad) atomicAdd(&s_bad, 1);
    __syncthreads();
    if (threadIdx.x == 0) *flag = (s_bad == 0) ? 1 : 0;
}

// ---- batched convert: all 14 tensors in one launch (blockIdx.y = tensor)
struct CvtArgs {
    const void* src[14];
    float* dst[14];
    int n[14];
};
__global__ __launch_bounds__(256) void cvt_all_kernel(CvtArgs a, const int* __restrict__ flag)
{
    int t = blockIdx.y;
    int i = blockIdx.x * 256 + threadIdx.x;
    if (i >= a.n[t]) return;
    if (*flag) a.dst[t][i] = bf2f(((const u16*)a.src[t])[i]);
    else       a.dst[t][i] = ((const float*)a.src[t])[i];
}

// hidden[b,l,c] = concat(cjv[:247], cls, cjv[247:]) + pos_embed
__global__ __launch_bounds__(256) void build_hidden_kernel(
    const float* __restrict__ cjv, const float* __restrict__ cls,
    const float* __restrict__ pos, float* __restrict__ hidden)
{
    int i = blockIdx.x * 256 + threadIdx.x;
    int c = i % D_;
    int l = (i / D_) % L_;
    int b = i / (D_ * L_);
    float v;
    if (l < 247)       v = cjv[((size_t)b * 494 + l) * D_ + c];
    else if (l == 247) v = cls[c];
    else               v = cjv[((size_t)b * 494 + (l - 1)) * D_ + c];
    hidden[i] = v + pos[(size_t)l * D_ + c];
}

// resid = hidden (+ resid); hidden <- rmsnorm(resid)*w   (in-place norm)
__global__ __launch_bounds__(128) void resnorm_kernel(
    float* __restrict__ hidden, float* __restrict__ resid,
    const float* __restrict__ w, int first)
{
    int m = blockIdx.x, tid = threadIdx.x;
    size_t base = (size_t)m * D_;
    float v[3]; float ss = 0.f;
#pragma unroll
    for (int i = 0; i < 3; ++i) {
        int c = tid + i * 128;
        float r = hidden[base + c];
        if (!first) r += resid[base + c];
        resid[base + c] = r;
        v[i] = r; ss += r * r;
    }
    ss += __shfl_xor(ss, 32); ss += __shfl_xor(ss, 16); ss += __shfl_xor(ss, 8);
    ss += __shfl_xor(ss, 4);  ss += __shfl_xor(ss, 2);  ss += __shfl_xor(ss, 1);
    __shared__ float sred[2];
    if ((tid & 63) == 0) sred[tid >> 6] = ss;
    __syncthreads();
    float scale = rsqrtf((sred[0] + sred[1]) * (1.f / D_) + 1e-5f);
#pragma unroll
    for (int i = 0; i < 3; ++i) {
        int c = tid + i * 128;
        hidden[base + c] = v[i] * scale * w[c];
    }
}

// C(M,N) = alpha * A(M,K) @ W(N,K)^T   (A f32 or bf16; W f32; C f32 or bf16)
#define BM 64
#define BN 64
#define BKg 16
template<int AF32, int CF32>
__global__ __launch_bounds__(256) void gemm_aw_t(
    const void* __restrict__ Av, const float* __restrict__ W, void* __restrict__ Cv,
    int M, int N, int K, int ldc, float alpha)
{
    __shared__ float As[BKg][BM + 1];
    __shared__ float Ws[BKg][BN + 1];
    int m0 = blockIdx.x * BM, n0 = blockIdx.y * BN;
    int tid = threadIdx.x;
    int ty = tid >> 4, tx = tid & 15;
    int lr = tid >> 2, lk = (tid & 3) << 2;
    float acc[4][4] = {};
    for (int k0 = 0; k0 < K; k0 += BKg) {
        int am = m0 + lr;
        float a0 = 0.f, a1 = 0.f, a2 = 0.f, a3 = 0.f;
        if (am < M) {
            if (AF32) {
                float4 av = *reinterpret_cast<const float4*>(
                    (const float*)Av + (size_t)am * K + k0 + lk);
                a0 = av.x; a1 = av.y; a2 = av.z; a3 = av.w;
            } else {
                ushort4 av = *reinterpret_cast<const ushort4*>(
                    (const u16*)Av + (size_t)am * K + k0 + lk);
                a0 = bf2f(av.x); a1 = bf2f(av.y); a2 = bf2f(av.z); a3 = bf2f(av.w);
            }
        }
        As[lk][lr] = a0; As[lk + 1][lr] = a1; As[lk + 2][lr] = a2; As[lk + 3][lr] = a3;
        float4 wv = *reinterpret_cast<const float4*>(W + (size_t)(n0 + lr) * K + k0 + lk);
        Ws[lk][lr] = wv.x; Ws[lk + 1][lr] = wv.y;
        Ws[lk + 2][lr] = wv.z; Ws[lk + 3][lr] = wv.w;
        __syncthreads();
#pragma unroll
        for (int kk = 0; kk < BKg; ++kk) {
            float b0 = As[kk][ty * 4], b1 = As[kk][ty * 4 + 1];
            float b2 = As[kk][ty * 4 + 2], b3 = As[kk][ty * 4 + 3];
            float c0 = Ws[kk][tx * 4], c1 = Ws[kk][tx * 4 + 1];
            float c2 = Ws[kk][tx * 4 + 2], c3 = Ws[kk][tx * 4 + 3];
            acc[0][0] += b0 * c0; acc[0][1] += b0 * c1; acc[0][2] += b0 * c2; acc[0][3] += b0 * c3;
            acc[1][0] += b1 * c0; acc[1][1] += b1 * c1; acc[1][2] += b1 * c2; acc[1][3] += b1 * c3;
            acc[2][0] += b2 * c0; acc[2][1] += b2 * c1; acc[2][2] += b2 * c2; acc[2][3] += b2 * c3;
            acc[3][0] += b3 * c0; acc[3][1] += b3 * c1; acc[3][2] += b3 * c2; acc[3][3] += b3 * c3;
        }
        __syncthreads();
    }
#pragma unroll
    for (int i = 0; i < 4; ++i) {
        int m = m0 + ty * 4 + i;
        if (m >= M) continue;
#pragma unroll
        for (int j = 0; j < 4; ++j) {
            float val = alpha * acc[i][j];
            if (CF32) ((float*)Cv)[(size_t)m * ldc + n0 + tx * 4 + j] = val;
            else      ((u16*)Cv)[(size_t)m * ldc + n0 + tx * 4 + j] = f2bf(val);
        }
    }
}

// causal depthwise conv (K=4) + bias + silu, in scan order; xin = xz[:, :768]
__global__ __launch_bounds__(256) void conv_silu_kernel(
    const u16* __restrict__ xz, const float* __restrict__ cw,
    const float* __restrict__ cb, u16* __restrict__ xc, int rev)
{
    int i = blockIdx.x * 256 + threadIdx.x;
    int d = i % DI_;
    int s = (i / DI_) % L_;
    int b = i / (DI_ * L_);
    float acc = cb[d];
#pragma unroll
    for (int k = 0; k < 4; ++k) {
        int t = s - 3 + k;
        if (t >= 0) {
            int lorig = rev ? (L_ - 1 - t) : t;
            acc += cw[d * 4 + k] * bf2f(xz[((size_t)b * L_ + lorig) * 1536 + d]);
        }
    }
    xc[i] = f2bf(silu_f(acc));
}

// dbl(m, 56) = xc(m, 768) @ xpW(56,768)^T ; one block per token
__global__ __launch_bounds__(256) void xproj_kernel(
    const u16* __restrict__ xc, const float* __restrict__ xpW, float* __restrict__ dbl)
{
    int m = blockIdx.x;
    __shared__ float xs[DI_];
    int tid = threadIdx.x;
    for (int i = tid; i < DI_; i += 256) xs[i] = bf2f(xc[(size_t)m * DI_ + i]);
    __syncthreads();
    int wave = tid >> 6, lane = tid & 63;
    for (int e = wave; e < 56; e += 4) {
        const float* wr = xpW + (size_t)e * DI_;
        float s = 0.f;
#pragma unroll
        for (int i = 0; i < DI_ / 64; ++i) s += xs[lane + 64 * i] * wr[lane + 64 * i];
        s += __shfl_xor(s, 32); s += __shfl_xor(s, 16); s += __shfl_xor(s, 8);
        s += __shfl_xor(s, 4);  s += __shfl_xor(s, 2);  s += __shfl_xor(s, 1);
        if (lane == 0) dbl[(size_t)m * 56 + e] = s;
    }
}

// ======================= scan v3 =======================
// One lane per (b,d) channel; 16 states in registers; dt_proj fused
// (24 dtW weights/lane in regs); chunked T=16 software pipeline:
// chunk c+1 global loads issued before computing chunk c; dt/B/C rows
// staged to LDS via registers with lgkm-only waits (no __syncthreads,
// single wave per block).
#define TCH 16
template<int REV>   // REV=1: reversed direction + accumulate into ysum
__global__ __launch_bounds__(64) void scan_v3_kernel(
    const u16* __restrict__ xc, const float* __restrict__ dbl,
    const u16* __restrict__ xz, const float* __restrict__ dtW,
    const float* __restrict__ dtb, const float* __restrict__ Alog,
    const float* __restrict__ Dp, u16* __restrict__ ysum)
{
    int lane = threadIdx.x;
    int b = blockIdx.x / 12;
    int d = (blockIdx.x % 12) * 64 + lane;
    size_t mb = (size_t)b * L_;

    // per-channel constants in registers
    float A[16];
    {
        const float4* ap = reinterpret_cast<const float4*>(Alog + (size_t)d * 16);
#pragma unroll
        for (int i = 0; i < 4; ++i) {
            float4 a4 = ap[i];
            A[4 * i + 0] = -__expf(a4.x); A[4 * i + 1] = -__expf(a4.y);
            A[4 * i + 2] = -__expf(a4.z); A[4 * i + 3] = -__expf(a4.w);
        }
    }
    float W[24];
    {
        const float4* wp = reinterpret_cast<const float4*>(dtW + (size_t)d * 24);
#pragma unroll
        for (int i = 0; i < 6; ++i) {
            float4 w4 = wp[i];
            W[4 * i + 0] = w4.x; W[4 * i + 1] = w4.y;
            W[4 * i + 2] = w4.z; W[4 * i + 3] = w4.w;
        }
    }
    float bias = dtb[d];
    float Dval = Dp[d];
    float h[16];
#pragma unroll
    for (int i = 0; i < 16; ++i) h[i] = 0.f;

    __shared__ __align__(16) float sd[TCH * 56];   // dt/B/C rows for current chunk

    // double-buffered register chunk data (raw u16 to keep loads unconverted)
    unsigned xcr[2][TCH], zr[2][TCH], yor_[2][TCH];
    float dblr[2][14];

    const int nch = (L_ + TCH - 1) / TCH;   // 31

    // ---- issue chunk's global loads into register buffer cb
    auto issue_global = [&](int cb, int t0) {
#pragma unroll
        for (int i = 0; i < TCH; ++i) {
            int t = t0 + i;
            if (t < L_) {
                int lorig = REV ? (L_ - 1 - t) : t;
                xcr[cb][i] = xc[(mb + t) * DI_ + d];
                zr[cb][i]  = xz[(mb + lorig) * 1536 + 768 + d];
                if (REV) yor_[cb][i] = ysum[(mb + lorig) * DI_ + d];
            } else {
                xcr[cb][i] = 0; zr[cb][i] = 0; if (REV) yor_[cb][i] = 0;
            }
        }
        int tot = ((L_ - t0) < TCH ? (L_ - t0) : TCH) * 56;
#pragma unroll
        for (int i = 0; i < 14; ++i) {
            int f = lane + 64 * i;
            dblr[cb][i] = (f < tot) ? dbl[(mb + t0) * 56 + f] : 0.f;
        }
    };

    // ---- commit register-staged dbl rows to LDS
    auto lds_commit = [&](int cb, int t0) {
        int tot = ((L_ - t0) < TCH ? (L_ - t0) : TCH) * 56;
#pragma unroll
        for (int i = 0; i < 14; ++i) {
            int f = lane + 64 * i;
            if (f < tot) sd[f] = dblr[cb][i];
        }
    };

    issue_global(0, 0);
    __asm__ volatile("" ::: "memory");
    lds_commit(0, 0);
    __asm__ volatile("s_waitcnt lgkmcnt(0)" ::: "memory");

    for (int c = 0; c < nch; ++c) {
        int cb = c & 1;
        int t0 = c * TCH;
        if (c + 1 < nch) issue_global(cb ^ 1, t0 + TCH);

        // ---- compute chunk c from LDS + register buffer cb
#pragma unroll
        for (int i = 0; i < TCH; ++i) {
            int t = t0 + i;
            if (t >= L_) break;
            // delta = softplus(dt . W + bias)
            float s = bias;
            const float4* pd = reinterpret_cast<const float4*>(&sd[i * 56]);
#pragma unroll
            for (int r = 0; r < 6; ++r) {
                float4 d4 = pd[r];
                s += W[4 * r + 0] * d4.x + W[4 * r + 1] * d4.y
                   + W[4 * r + 2] * d4.z + W[4 * r + 3] * d4.w;
            }
            float dl = (s > 20.f) ? s : __logf(1.f + __expf(s));

            float xv = bf2f((u16)xcr[cb][i]);
            float dlxv = dl * xv;
            const float4* pb = reinterpret_cast<const float4*>(&sd[i * 56 + 24]);
            const float4* pc = reinterpret_cast<const float4*>(&sd[i * 56 + 40]);
            float a0 = 0.f, a1 = 0.f, a2 = 0.f, a3 = 0.f;
#pragma unroll
            for (int j = 0; j < 4; ++j) {
                float4 B4 = pb[j], C4 = pc[j];
                float e0 = __expf(dl * A[4 * j + 0]);
                float e1 = __expf(dl * A[4 * j + 1]);
                float e2 = __expf(dl * A[4 * j + 2]);
                float e3 = __expf(dl * A[4 * j + 3]);
                h[4 * j + 0] = e0 * h[4 * j + 0] + dlxv * B4.x;
                h[4 * j + 1] = e1 * h[4 * j + 1] + dlxv * B4.y;
                h[4 * j + 2] = e2 * h[4 * j + 2] + dlxv * B4.z;
                h[4 * j + 3] = e3 * h[4 * j + 3] + dlxv * B4.w;
                a0 += h[4 * j + 0] * C4.x;
                a1 += h[4 * j + 1] * C4.y;
                a2 += h[4 * j + 2] * C4.z;
                a3 += h[4 * j + 3] * C4.w;
            }
            float y = (a0 + a1) + (a2 + a3) + xv * Dval;
            y *= silu_f(bf2f((u16)zr[cb][i]));
            int lorig = REV ? (L_ - 1 - t) : t;
            if (REV) y += bf2f((u16)yor_[cb][i]);
            ysum[(mb + lorig) * DI_ + d] = f2bf(y);
        }

        if (c + 1 < nch) {
            __asm__ volatile("" ::: "memory");
            lds_commit(cb ^ 1, t0 + TCH);
            __asm__ volatile("s_waitcnt lgkmcnt(0)" ::: "memory");
        }
    }
}

// final: residual+hidden, rmsnorm, permute+slice, store bf16 or f32 per flag
__global__ __launch_bounds__(128) void final_kernel(
    const float* __restrict__ hidden, const float* __restrict__ resid,
    const float* __restrict__ w, void* __restrict__ out,
    const int* __restrict__ flag)
{
    int blk = blockIdx.x;
    int b = blk / 446, tok = blk % 446;
    int lorig; size_t dst;
    if (tok == 0)      { lorig = 247; dst = (size_t)b * D_; }
    else if (tok <= 14){ int j = tok - 1; lorig = 49 + j; dst = 6144 + ((size_t)b * 14 + j) * D_; }
    else               { int v = tok - 15; lorig = (v < 184) ? (63 + v) : (64 + v);
                         dst = 92160 + ((size_t)b * 431 + v) * D_; }
    size_t base = ((size_t)b * L_ + lorig) * D_;
    int tid = threadIdx.x;
    float v3[3]; float ss = 0.f;
#pragma unroll
    for (int i = 0; i < 3; ++i) {
        int c = tid + i * 128;
        float r = hidden[base + c] + resid[base + c];
        v3[i] = r; ss += r * r;
    }
    ss += __shfl_xor(ss, 32); ss += __shfl_xor(ss, 16); ss += __shfl_xor(ss, 8);
    ss += __shfl_xor(ss, 4);  ss += __shfl_xor(ss, 2);  ss += __shfl_xor(ss, 1);
    __shared__ float sred[2];
    if ((tid & 63) == 0) sred[tid >> 6] = ss;
    __syncthreads();
    float scale = rsqrtf((sred[0] + sred[1]) * (1.f / D_) + 1e-5f);
    int isbf = *flag;
#pragma unroll
    for (int i = 0; i < 3; ++i) {
        int c = tid + i * 128;
        float val = v3[i] * scale * w[c];
        if (isbf) ((u16*)out)[dst + c] = f2bf(val);
        else      ((float*)out)[dst + c] = val;
    }
}

extern "C" void kernel_launch(void* const* d_in, const int* in_sizes, int n_in,
                              void* d_out, int out_size, void* d_ws, size_t ws_size,
                              hipStream_t stream) {
    // ---- workspace layout (~104 MB)
    char* wsb = (char*)d_ws;
    int* flag = (int*)wsb;  wsb += 16;

    const int cn[14] = {3035136, 384, 190080, 2359296, 24576, 6144, 344064,
                        147456, 6144, 98304, 6144, 1179648, 1536, 384};
    const int raw_idx[14] = {0, 2, 3, 4, 5, 6, 7, 8, 9, 10, 11, 12, 13, 14};
    float* canon[14];
    for (int i = 0; i < 14; ++i) { canon[i] = (float*)wsb; wsb += (size_t)cn[i] * 4; }
    const float* cjv  = canon[0];
    const float* cls  = canon[1];
    const float* pos  = canon[2];
    const float* inW  = canon[3];
    const float* cW   = canon[4];
    const float* cB   = canon[5];
    const float* xpW  = canon[6];
    const float* dtW  = canon[7];
    const float* dtB  = canon[8];
    const float* Alog = canon[9];
    const float* Dsk  = canon[10];
    const float* outW = canon[11];
    const float* nw   = canon[12];
    const float* fnw  = canon[13];

    const int M = B_ * L_;  // 7920 tokens
    float* hidden = (float*)wsb;  wsb += (size_t)M * D_ * 4;
    float* resid  = (float*)wsb;  wsb += (size_t)M * D_ * 4;
    float* dbl    = (float*)wsb;  wsb += (size_t)M * 56 * 4;
    u16*   xz     = (u16*)wsb;    wsb += (size_t)M * 1536 * 2;
    u16*   xc     = (u16*)wsb;    wsb += (size_t)M * DI_ * 2;
    u16*   ysum   = (u16*)wsb;    wsb += (size_t)M * DI_ * 2;

    detect_kernel<<<1, 256, 0, stream>>>((const u16*)d_in[10], flag);
    {
        CvtArgs ca;
        int maxn = 0;
        for (int i = 0; i < 14; ++i) {
            ca.src[i] = d_in[raw_idx[i]]; ca.dst[i] = canon[i]; ca.n[i] = cn[i];
            if (cn[i] > maxn) maxn = cn[i];
        }
        cvt_all_kernel<<<dim3((maxn + 255) / 256, 14), 256, 0, stream>>>(ca, flag);
    }

    build_hidden_kernel<<<(M * D_) / 256, 256, 0, stream>>>(cjv, cls, pos, hidden);

    for (int l = 0; l < 4; ++l) {
        resnorm_kernel<<<M, 128, 0, stream>>>(hidden, resid, nw + (size_t)l * D_, l == 0);
        gemm_aw_t<1, 0><<<dim3((M + BM - 1) / BM, 1536 / BN), 256, 0, stream>>>(
            hidden, inW + (size_t)l * 1536 * D_, xz, M, 1536, D_, 1536, 1.f);
        for (int dir = 0; dir < 2; ++dir) {
            int ld = l * 2 + dir;
            conv_silu_kernel<<<(M * DI_) / 256, 256, 0, stream>>>(
                xz, cW + (size_t)ld * DI_ * 4, cB + (size_t)ld * DI_, xc, dir);
            xproj_kernel<<<M, 256, 0, stream>>>(xc, xpW + (size_t)ld * 56 * DI_, dbl);
            if (dir == 0)
                scan_v3_kernel<0><<<B_ * 12, 64, 0, stream>>>(
                    xc, dbl, xz, dtW + (size_t)ld * DI_ * DTR_, dtB + (size_t)ld * DI_,
                    Alog + (size_t)ld * DI_ * DS_, Dsk + (size_t)ld * DI_, ysum);
            else
                scan_v3_kernel<1><<<B_ * 12, 64, 0, stream>>>(
                    xc, dbl, xz, dtW + (size_t)ld * DI_ * DTR_, dtB + (size_t)ld * DI_,
                    Alog + (size_t)ld * DI_ * DS_, Dsk + (size_t)ld * DI_, ysum);
        }
        gemm_aw_t<0, 1><<<dim3((M + BM - 1) / BM, D_ / BN), 256, 0, stream>>>(
            ysum, outW + (size_t)l * D_ * DI_, hidden, M, D_, DI_, D_, 0.5f);
    }

    final_kernel<<<B_ * 446, 128, 0, stream>>>(hidden, resid, fnw, d_out, flag);
}

// Round 6
// 3134.466 us; speedup vs baseline: 1.8654x; 1.8654x over previous
//
#include <hip/hip_runtime.h>

typedef unsigned short u16;

#define B_   16
#define L_   495
#define D_   384
#define DI_  768
#define DS_  16
#define DTR_ 24
#define SEG  8
#define TL   62   // ceil(495/8)

__device__ __forceinline__ float bf2f(u16 u) {
    return __uint_as_float(((unsigned)u) << 16);
}
__device__ __forceinline__ u16 f2bf(float f) {
    unsigned u = __float_as_uint(f);
    unsigned r = 0x7fffu + ((u >> 16) & 1u);
    return (u16)((u + r) >> 16);
}
__device__ __forceinline__ float silu_f(float x) {
    return x / (1.f + __expf(-x));
}

// ---- dtype detector: A_log values are in [0, 2.78]. flag=1 -> bf16, 0 -> f32.
__global__ __launch_bounds__(256) void detect_kernel(
    const u16* __restrict__ alog_raw, int* __restrict__ flag)
{
    __shared__ int s_bad;
    if (threadIdx.x == 0) s_bad = 0;
    __syncthreads();
    int bad = 0;
    for (int i = threadIdx.x; i < 98304; i += 256) {
        float v = bf2f(alog_raw[i]);
        if (!(v >= -1e-3f && v <= 2.8f)) bad = 1;
    }
    if (bad) atomicAdd(&s_bad, 1);
    __syncthreads();
    if (threadIdx.x == 0) *flag = (s_bad == 0) ? 1 : 0;
}

// ---- batched convert: all 14 tensors in one launch (blockIdx.y = tensor)
struct CvtArgs {
    const void* src[14];
    float* dst[14];
    int n[14];
};
__global__ __launch_bounds__(256) void cvt_all_kernel(CvtArgs a, const int* __restrict__ flag)
{
    int t = blockIdx.y;
    int i = blockIdx.x * 256 + threadIdx.x;
    if (i >= a.n[t]) return;
    if (*flag) a.dst[t][i] = bf2f(((const u16*)a.src[t])[i]);
    else       a.dst[t][i] = ((const float*)a.src[t])[i];
}

// hidden[b,l,c] = concat(cjv[:247], cls, cjv[247:]) + pos_embed
__global__ __launch_bounds__(256) void build_hidden_kernel(
    const float* __restrict__ cjv, const float* __restrict__ cls,
    const float* __restrict__ pos, float* __restrict__ hidden)
{
    int i = blockIdx.x * 256 + threadIdx.x;
    int c = i % D_;
    int l = (i / D_) % L_;
    int b = i / (D_ * L_);
    float v;
    if (l < 247)       v = cjv[((size_t)b * 494 + l) * D_ + c];
    else if (l == 247) v = cls[c];
    else               v = cjv[((size_t)b * 494 + (l - 1)) * D_ + c];
    hidden[i] = v + pos[(size_t)l * D_ + c];
}

// resid = hidden (+ resid); hidden <- rmsnorm(resid)*w   (in-place norm)
__global__ __launch_bounds__(128) void resnorm_kernel(
    float* __restrict__ hidden, float* __restrict__ resid,
    const float* __restrict__ w, int first)
{
    int m = blockIdx.x, tid = threadIdx.x;
    size_t base = (size_t)m * D_;
    float v[3]; float ss = 0.f;
#pragma unroll
    for (int i = 0; i < 3; ++i) {
        int c = tid + i * 128;
        float r = hidden[base + c];
        if (!first) r += resid[base + c];
        resid[base + c] = r;
        v[i] = r; ss += r * r;
    }
    ss += __shfl_xor(ss, 32); ss += __shfl_xor(ss, 16); ss += __shfl_xor(ss, 8);
    ss += __shfl_xor(ss, 4);  ss += __shfl_xor(ss, 2);  ss += __shfl_xor(ss, 1);
    __shared__ float sred[2];
    if ((tid & 63) == 0) sred[tid >> 6] = ss;
    __syncthreads();
    float scale = rsqrtf((sred[0] + sred[1]) * (1.f / D_) + 1e-5f);
#pragma unroll
    for (int i = 0; i < 3; ++i) {
        int c = tid + i * 128;
        hidden[base + c] = v[i] * scale * w[c];
    }
}

// C(M,N) = alpha * A(M,K) @ W(N,K)^T   (A f32 or bf16; W f32; C f32 or bf16)
#define BM 64
#define BN 64
#define BKg 16
template<int AF32, int CF32>
__global__ __launch_bounds__(256) void gemm_aw_t(
    const void* __restrict__ Av, const float* __restrict__ W, void* __restrict__ Cv,
    int M, int N, int K, int ldc, float alpha)
{
    __shared__ float As[BKg][BM + 1];
    __shared__ float Ws[BKg][BN + 1];
    int m0 = blockIdx.x * BM, n0 = blockIdx.y * BN;
    int tid = threadIdx.x;
    int ty = tid >> 4, tx = tid & 15;
    int lr = tid >> 2, lk = (tid & 3) << 2;
    float acc[4][4] = {};
    for (int k0 = 0; k0 < K; k0 += BKg) {
        int am = m0 + lr;
        float a0 = 0.f, a1 = 0.f, a2 = 0.f, a3 = 0.f;
        if (am < M) {
            if (AF32) {
                float4 av = *reinterpret_cast<const float4*>(
                    (const float*)Av + (size_t)am * K + k0 + lk);
                a0 = av.x; a1 = av.y; a2 = av.z; a3 = av.w;
            } else {
                ushort4 av = *reinterpret_cast<const ushort4*>(
                    (const u16*)Av + (size_t)am * K + k0 + lk);
                a0 = bf2f(av.x); a1 = bf2f(av.y); a2 = bf2f(av.z); a3 = bf2f(av.w);
            }
        }
        As[lk][lr] = a0; As[lk + 1][lr] = a1; As[lk + 2][lr] = a2; As[lk + 3][lr] = a3;
        float4 wv = *reinterpret_cast<const float4*>(W + (size_t)(n0 + lr) * K + k0 + lk);
        Ws[lk][lr] = wv.x; Ws[lk + 1][lr] = wv.y;
        Ws[lk + 2][lr] = wv.z; Ws[lk + 3][lr] = wv.w;
        __syncthreads();
#pragma unroll
        for (int kk = 0; kk < BKg; ++kk) {
            float b0 = As[kk][ty * 4], b1 = As[kk][ty * 4 + 1];
            float b2 = As[kk][ty * 4 + 2], b3 = As[kk][ty * 4 + 3];
            float c0 = Ws[kk][tx * 4], c1 = Ws[kk][tx * 4 + 1];
            float c2 = Ws[kk][tx * 4 + 2], c3 = Ws[kk][tx * 4 + 3];
            acc[0][0] += b0 * c0; acc[0][1] += b0 * c1; acc[0][2] += b0 * c2; acc[0][3] += b0 * c3;
            acc[1][0] += b1 * c0; acc[1][1] += b1 * c1; acc[1][2] += b1 * c2; acc[1][3] += b1 * c3;
            acc[2][0] += b2 * c0; acc[2][1] += b2 * c1; acc[2][2] += b2 * c2; acc[2][3] += b2 * c3;
            acc[3][0] += b3 * c0; acc[3][1] += b3 * c1; acc[3][2] += b3 * c2; acc[3][3] += b3 * c3;
        }
        __syncthreads();
    }
#pragma unroll
    for (int i = 0; i < 4; ++i) {
        int m = m0 + ty * 4 + i;
        if (m >= M) continue;
#pragma unroll
        for (int j = 0; j < 4; ++j) {
            float val = alpha * acc[i][j];
            if (CF32) ((float*)Cv)[(size_t)m * ldc + n0 + tx * 4 + j] = val;
            else      ((u16*)Cv)[(size_t)m * ldc + n0 + tx * 4 + j] = f2bf(val);
        }
    }
}

// causal depthwise conv (K=4) + bias + silu, in scan order; xin = xz[:, :768]
__global__ __launch_bounds__(256) void conv_silu_kernel(
    const u16* __restrict__ xz, const float* __restrict__ cw,
    const float* __restrict__ cb, u16* __restrict__ xc, int rev)
{
    int i = blockIdx.x * 256 + threadIdx.x;
    int d = i % DI_;
    int s = (i / DI_) % L_;
    int b = i / (DI_ * L_);
    float acc = cb[d];
#pragma unroll
    for (int k = 0; k < 4; ++k) {
        int t = s - 3 + k;
        if (t >= 0) {
            int lorig = rev ? (L_ - 1 - t) : t;
            acc += cw[d * 4 + k] * bf2f(xz[((size_t)b * L_ + lorig) * 1536 + d]);
        }
    }
    xc[i] = f2bf(silu_f(acc));
}

// dbl(m, 56) = xc(m, 768) @ xpW(56,768)^T ; one block per token
__global__ __launch_bounds__(256) void xproj_kernel(
    const u16* __restrict__ xc, const float* __restrict__ xpW, float* __restrict__ dbl)
{
    int m = blockIdx.x;
    __shared__ float xs[DI_];
    int tid = threadIdx.x;
    for (int i = tid; i < DI_; i += 256) xs[i] = bf2f(xc[(size_t)m * DI_ + i]);
    __syncthreads();
    int wave = tid >> 6, lane = tid & 63;
    for (int e = wave; e < 56; e += 4) {
        const float* wr = xpW + (size_t)e * DI_;
        float s = 0.f;
#pragma unroll
        for (int i = 0; i < DI_ / 64; ++i) s += xs[lane + 64 * i] * wr[lane + 64 * i];
        s += __shfl_xor(s, 32); s += __shfl_xor(s, 16); s += __shfl_xor(s, 8);
        s += __shfl_xor(s, 4);  s += __shfl_xor(s, 2);  s += __shfl_xor(s, 1);
        if (lane == 0) dbl[(size_t)m * 56 + e] = s;
    }
}

// ================= segmented selective scan =================
// Phase 1: per-segment local scan with h0=0; emits per-state decay product
// P = prod(dA) and local end-state q. Phase 2: sequential combine over the 8
// segments (hin[s+1] = P[s]*hin[s] + q[s]), rewriting q <- hin. Phase 3:
// rescan each segment from its true hin, producing y. dt_proj fused in both
// scan phases (24 weights/lane in registers). Lane = channel d; 16 states in
// registers. Parallelism: B*12*SEG = 1536 waves (~6/CU).

__device__ __forceinline__ float dt_delta(
    const float* __restrict__ row, const float* W, float bias)
{
    float s = bias;
    const float4* pd = reinterpret_cast<const float4*>(row);
#pragma unroll
    for (int r = 0; r < 6; ++r) {
        float4 d4 = pd[r];
        s += W[4 * r + 0] * d4.x + W[4 * r + 1] * d4.y
           + W[4 * r + 2] * d4.z + W[4 * r + 3] * d4.w;
    }
    return (s > 20.f) ? s : __logf(1.f + __expf(s));
}

__global__ __launch_bounds__(64) void scan_part1_kernel(
    const u16* __restrict__ xc, const float* __restrict__ dbl,
    const float* __restrict__ dtW, const float* __restrict__ dtb,
    const float* __restrict__ Alog,
    float* __restrict__ P_buf, float* __restrict__ q_buf)
{
    int lane = threadIdx.x;
    int blk = blockIdx.x;
    int s = blk % SEG;
    int bd = blk / SEG;
    int b = bd / 12, dblk = bd % 12;
    int d = dblk * 64 + lane;
    size_t mb = (size_t)b * L_;
    int t0 = s * TL;
    int t1 = (t0 + TL < L_) ? (t0 + TL) : L_;

    float A[16];
    {
        const float4* ap = reinterpret_cast<const float4*>(Alog + (size_t)d * 16);
#pragma unroll
        for (int i = 0; i < 4; ++i) {
            float4 a4 = ap[i];
            A[4 * i + 0] = -__expf(a4.x); A[4 * i + 1] = -__expf(a4.y);
            A[4 * i + 2] = -__expf(a4.z); A[4 * i + 3] = -__expf(a4.w);
        }
    }
    float W[24];
    {
        const float4* wp = reinterpret_cast<const float4*>(dtW + (size_t)d * 24);
#pragma unroll
        for (int i = 0; i < 6; ++i) {
            float4 w4 = wp[i];
            W[4 * i + 0] = w4.x; W[4 * i + 1] = w4.y;
            W[4 * i + 2] = w4.z; W[4 * i + 3] = w4.w;
        }
    }
    float bias = dtb[d];
    float h[16], P[16];
#pragma unroll
    for (int i = 0; i < 16; ++i) { h[i] = 0.f; P[i] = 1.f; }

    for (int t = t0; t < t1; ++t) {
        const float* row = dbl + (mb + t) * 56;
        float dl = dt_delta(row, W, bias);
        float xv = bf2f(xc[(mb + t) * DI_ + d]);
        float dlxv = dl * xv;
        const float4* pb = reinterpret_cast<const float4*>(row + 24);
#pragma unroll
        for (int j = 0; j < 4; ++j) {
            float4 B4 = pb[j];
            float e0 = __expf(dl * A[4 * j + 0]);
            float e1 = __expf(dl * A[4 * j + 1]);
            float e2 = __expf(dl * A[4 * j + 2]);
            float e3 = __expf(dl * A[4 * j + 3]);
            h[4 * j + 0] = e0 * h[4 * j + 0] + dlxv * B4.x;
            h[4 * j + 1] = e1 * h[4 * j + 1] + dlxv * B4.y;
            h[4 * j + 2] = e2 * h[4 * j + 2] + dlxv * B4.z;
            h[4 * j + 3] = e3 * h[4 * j + 3] + dlxv * B4.w;
            P[4 * j + 0] *= e0; P[4 * j + 1] *= e1;
            P[4 * j + 2] *= e2; P[4 * j + 3] *= e3;
        }
    }
    size_t base = ((size_t)blk * 16) * 64 + lane;
#pragma unroll
    for (int n = 0; n < 16; ++n) {
        P_buf[base + (size_t)n * 64] = P[n];
        q_buf[base + (size_t)n * 64] = h[n];
    }
}

// Phase 2: per (b,d): hin[0]=0; hin[s+1] = P[s]*hin[s] + q[s]; q[s] <- hin[s]
__global__ __launch_bounds__(64) void scan_combine_kernel(
    const float* __restrict__ P_buf, float* __restrict__ q_buf)
{
    int lane = threadIdx.x;
    int bd = blockIdx.x;
    float h[16];
#pragma unroll
    for (int i = 0; i < 16; ++i) h[i] = 0.f;
    for (int s = 0; s < SEG; ++s) {
        size_t base = ((size_t)(bd * SEG + s) * 16) * 64 + lane;
#pragma unroll
        for (int n = 0; n < 16; ++n) {
            size_t idx = base + (size_t)n * 64;
            float Pv = P_buf[idx];
            float qv = q_buf[idx];
            q_buf[idx] = h[n];
            h[n] = Pv * h[n] + qv;
        }
    }
}

// Phase 3: rescan from true hin, produce y
template<int REV>
__global__ __launch_bounds__(64) void scan_part3_kernel(
    const u16* __restrict__ xc, const float* __restrict__ dbl,
    const u16* __restrict__ xz, const float* __restrict__ dtW,
    const float* __restrict__ dtb, const float* __restrict__ Alog,
    const float* __restrict__ Dp, const float* __restrict__ q_buf,
    u16* __restrict__ ysum)
{
    int lane = threadIdx.x;
    int blk = blockIdx.x;
    int s = blk % SEG;
    int bd = blk / SEG;
    int b = bd / 12, dblk = bd % 12;
    int d = dblk * 64 + lane;
    size_t mb = (size_t)b * L_;
    int t0 = s * TL;
    int t1 = (t0 + TL < L_) ? (t0 + TL) : L_;

    float A[16];
    {
        const float4* ap = reinterpret_cast<const float4*>(Alog + (size_t)d * 16);
#pragma unroll
        for (int i = 0; i < 4; ++i) {
            float4 a4 = ap[i];
            A[4 * i + 0] = -__expf(a4.x); A[4 * i + 1] = -__expf(a4.y);
            A[4 * i + 2] = -__expf(a4.z); A[4 * i + 3] = -__expf(a4.w);
        }
    }
    float W[24];
    {
        const float4* wp = reinterpret_cast<const float4*>(dtW + (size_t)d * 24);
#pragma unroll
        for (int i = 0; i < 6; ++i) {
            float4 w4 = wp[i];
            W[4 * i + 0] = w4.x; W[4 * i + 1] = w4.y;
            W[4 * i + 2] = w4.z; W[4 * i + 3] = w4.w;
        }
    }
    float bias = dtb[d];
    float Dval = Dp[d];
    float h[16];
    {
        size_t base = ((size_t)blk * 16) * 64 + lane;
#pragma unroll
        for (int n = 0; n < 16; ++n) h[n] = q_buf[base + (size_t)n * 64];
    }

    for (int t = t0; t < t1; ++t) {
        const float* row = dbl + (mb + t) * 56;
        float dl = dt_delta(row, W, bias);
        float xv = bf2f(xc[(mb + t) * DI_ + d]);
        float dlxv = dl * xv;
        const float4* pb = reinterpret_cast<const float4*>(row + 24);
        const float4* pc = reinterpret_cast<const float4*>(row + 40);
        float a0 = 0.f, a1 = 0.f, a2 = 0.f, a3 = 0.f;
#pragma unroll
        for (int j = 0; j < 4; ++j) {
            float4 B4 = pb[j], C4 = pc[j];
            float e0 = __expf(dl * A[4 * j + 0]);
            float e1 = __expf(dl * A[4 * j + 1]);
            float e2 = __expf(dl * A[4 * j + 2]);
            float e3 = __expf(dl * A[4 * j + 3]);
            h[4 * j + 0] = e0 * h[4 * j + 0] + dlxv * B4.x;
            h[4 * j + 1] = e1 * h[4 * j + 1] + dlxv * B4.y;
            h[4 * j + 2] = e2 * h[4 * j + 2] + dlxv * B4.z;
            h[4 * j + 3] = e3 * h[4 * j + 3] + dlxv * B4.w;
            a0 += h[4 * j + 0] * C4.x;
            a1 += h[4 * j + 1] * C4.y;
            a2 += h[4 * j + 2] * C4.z;
            a3 += h[4 * j + 3] * C4.w;
        }
        float y = (a0 + a1) + (a2 + a3) + xv * Dval;
        int lorig = REV ? (L_ - 1 - t) : t;
        y *= silu_f(bf2f(xz[(mb + lorig) * 1536 + 768 + d]));
        if (REV) y += bf2f(ysum[(mb + lorig) * DI_ + d]);
        ysum[(mb + lorig) * DI_ + d] = f2bf(y);
    }
}

// final: residual+hidden, rmsnorm, permute+slice, store bf16 or f32 per flag
__global__ __launch_bounds__(128) void final_kernel(
    const float* __restrict__ hidden, const float* __restrict__ resid,
    const float* __restrict__ w, void* __restrict__ out,
    const int* __restrict__ flag)
{
    int blk = blockIdx.x;
    int b = blk / 446, tok = blk % 446;
    int lorig; size_t dst;
    if (tok == 0)      { lorig = 247; dst = (size_t)b * D_; }
    else if (tok <= 14){ int j = tok - 1; lorig = 49 + j; dst = 6144 + ((size_t)b * 14 + j) * D_; }
    else               { int v = tok - 15; lorig = (v < 184) ? (63 + v) : (64 + v);
                         dst = 92160 + ((size_t)b * 431 + v) * D_; }
    size_t base = ((size_t)b * L_ + lorig) * D_;
    int tid = threadIdx.x;
    float v3[3]; float ss = 0.f;
#pragma unroll
    for (int i = 0; i < 3; ++i) {
        int c = tid + i * 128;
        float r = hidden[base + c] + resid[base + c];
        v3[i] = r; ss += r * r;
    }
    ss += __shfl_xor(ss, 32); ss += __shfl_xor(ss, 16); ss += __shfl_xor(ss, 8);
    ss += __shfl_xor(ss, 4);  ss += __shfl_xor(ss, 2);  ss += __shfl_xor(ss, 1);
    __shared__ float sred[2];
    if ((tid & 63) == 0) sred[tid >> 6] = ss;
    __syncthreads();
    float scale = rsqrtf((sred[0] + sred[1]) * (1.f / D_) + 1e-5f);
    int isbf = *flag;
#pragma unroll
    for (int i = 0; i < 3; ++i) {
        int c = tid + i * 128;
        float val = v3[i] * scale * w[c];
        if (isbf) ((u16*)out)[dst + c] = f2bf(val);
        else      ((float*)out)[dst + c] = val;
    }
}

extern "C" void kernel_launch(void* const* d_in, const int* in_sizes, int n_in,
                              void* d_out, int out_size, void* d_ws, size_t ws_size,
                              hipStream_t stream) {
    // ---- workspace layout (~117 MB)
    char* wsb = (char*)d_ws;
    int* flag = (int*)wsb;  wsb += 16;

    const int cn[14] = {3035136, 384, 190080, 2359296, 24576, 6144, 344064,
                        147456, 6144, 98304, 6144, 1179648, 1536, 384};
    const int raw_idx[14] = {0, 2, 3, 4, 5, 6, 7, 8, 9, 10, 11, 12, 13, 14};
    float* canon[14];
    for (int i = 0; i < 14; ++i) { canon[i] = (float*)wsb; wsb += (size_t)cn[i] * 4; }
    const float* cjv  = canon[0];
    const float* cls  = canon[1];
    const float* pos  = canon[2];
    const float* inW  = canon[3];
    const float* cW   = canon[4];
    const float* cB   = canon[5];
    const float* xpW  = canon[6];
    const float* dtW  = canon[7];
    const float* dtB  = canon[8];
    const float* Alog = canon[9];
    const float* Dsk  = canon[10];
    const float* outW = canon[11];
    const float* nw   = canon[12];
    const float* fnw  = canon[13];

    const int M = B_ * L_;  // 7920 tokens
    float* hidden = (float*)wsb;  wsb += (size_t)M * D_ * 4;
    float* resid  = (float*)wsb;  wsb += (size_t)M * D_ * 4;
    float* dbl    = (float*)wsb;  wsb += (size_t)M * 56 * 4;
    u16*   xz     = (u16*)wsb;    wsb += (size_t)M * 1536 * 2;
    u16*   xc     = (u16*)wsb;    wsb += (size_t)M * DI_ * 2;
    u16*   ysum   = (u16*)wsb;    wsb += (size_t)M * DI_ * 2;
    float* P_buf  = (float*)wsb;  wsb += (size_t)B_ * 12 * SEG * 16 * 64 * 4;  // 6.3 MB
    float* q_buf  = (float*)wsb;  wsb += (size_t)B_ * 12 * SEG * 16 * 64 * 4;  // 6.3 MB

    detect_kernel<<<1, 256, 0, stream>>>((const u16*)d_in[10], flag);
    {
        CvtArgs ca;
        int maxn = 0;
        for (int i = 0; i < 14; ++i) {
            ca.src[i] = d_in[raw_idx[i]]; ca.dst[i] = canon[i]; ca.n[i] = cn[i];
            if (cn[i] > maxn) maxn = cn[i];
        }
        cvt_all_kernel<<<dim3((maxn + 255) / 256, 14), 256, 0, stream>>>(ca, flag);
    }

    build_hidden_kernel<<<(M * D_) / 256, 256, 0, stream>>>(cjv, cls, pos, hidden);

    const int scan_grid = B_ * 12 * SEG;   // 1536
    for (int l = 0; l < 4; ++l) {
        resnorm_kernel<<<M, 128, 0, stream>>>(hidden, resid, nw + (size_t)l * D_, l == 0);
        gemm_aw_t<1, 0><<<dim3((M + BM - 1) / BM, 1536 / BN), 256, 0, stream>>>(
            hidden, inW + (size_t)l * 1536 * D_, xz, M, 1536, D_, 1536, 1.f);
        for (int dir = 0; dir < 2; ++dir) {
            int ld = l * 2 + dir;
            const float* dtWl = dtW + (size_t)ld * DI_ * DTR_;
            const float* dtBl = dtB + (size_t)ld * DI_;
            const float* All  = Alog + (size_t)ld * DI_ * DS_;
            const float* Dl   = Dsk + (size_t)ld * DI_;
            conv_silu_kernel<<<(M * DI_) / 256, 256, 0, stream>>>(
                xz, cW + (size_t)ld * DI_ * 4, cB + (size_t)ld * DI_, xc, dir);
            xproj_kernel<<<M, 256, 0, stream>>>(xc, xpW + (size_t)ld * 56 * DI_, dbl);
            scan_part1_kernel<<<scan_grid, 64, 0, stream>>>(
                xc, dbl, dtWl, dtBl, All, P_buf, q_buf);
            scan_combine_kernel<<<B_ * 12, 64, 0, stream>>>(P_buf, q_buf);
            if (dir == 0)
                scan_part3_kernel<0><<<scan_grid, 64, 0, stream>>>(
                    xc, dbl, xz, dtWl, dtBl, All, Dl, q_buf, ysum);
            else
                scan_part3_kernel<1><<<scan_grid, 64, 0, stream>>>(
                    xc, dbl, xz, dtWl, dtBl, All, Dl, q_buf, ysum);
        }
        gemm_aw_t<0, 1><<<dim3((M + BM - 1) / BM, D_ / BN), 256, 0, stream>>>(
            ysum, outW + (size_t)l * D_ * DI_, hidden, M, D_, DI_, D_, 0.5f);
    }

    final_kernel<<<B_ * 446, 128, 0, stream>>>(hidden, resid, fnw, d_out, flag);
}

// Round 7
// 2138.394 us; speedup vs baseline: 2.7342x; 1.4658x over previous
//
#include <hip/hip_runtime.h>

typedef unsigned short u16;
typedef __attribute__((ext_vector_type(8))) short short8;
typedef __attribute__((ext_vector_type(4))) float float4v;

#define B_   16
#define L_   495
#define D_   384
#define DI_  768
#define DS_  16
#define DTR_ 24
#define SEG  8
#define TL   62   // ceil(495/8)

__device__ __forceinline__ float bf2f(u16 u) {
    return __uint_as_float(((unsigned)u) << 16);
}
__device__ __forceinline__ u16 f2bf(float f) {
    unsigned u = __float_as_uint(f);
    unsigned r = 0x7fffu + ((u >> 16) & 1u);
    return (u16)((u + r) >> 16);
}
__device__ __forceinline__ float silu_f(float x) {
    return x / (1.f + __expf(-x));
}

// ---- dtype detector: A_log values are in [0, 2.78]. flag=1 -> bf16, 0 -> f32.
__global__ __launch_bounds__(256) void detect_kernel(
    const u16* __restrict__ alog_raw, int* __restrict__ flag)
{
    __shared__ int s_bad;
    if (threadIdx.x == 0) s_bad = 0;
    __syncthreads();
    int bad = 0;
    for (int i = threadIdx.x; i < 98304; i += 256) {
        float v = bf2f(alog_raw[i]);
        if (!(v >= -1e-3f && v <= 2.8f)) bad = 1;
    }
    if (bad) atomicAdd(&s_bad, 1);
    __syncthreads();
    if (threadIdx.x == 0) *flag = (s_bad == 0) ? 1 : 0;
}

// ---- batched convert (blockIdx.y = tensor). tobf: emit bf16 instead of f32.
struct CvtArgs {
    const void* src[14];
    void* dst[14];
    int n[14];
    int tobf[14];
};
__global__ __launch_bounds__(256) void cvt_all_kernel(CvtArgs a, const int* __restrict__ flag)
{
    int t = blockIdx.y;
    int i = blockIdx.x * 256 + threadIdx.x;
    if (i >= a.n[t]) return;
    int isbf = *flag;
    if (a.tobf[t]) {
        u16 v = isbf ? ((const u16*)a.src[t])[i] : f2bf(((const float*)a.src[t])[i]);
        ((u16*)a.dst[t])[i] = v;
    } else {
        float v = isbf ? bf2f(((const u16*)a.src[t])[i]) : ((const float*)a.src[t])[i];
        ((float*)a.dst[t])[i] = v;
    }
}

// hidden[b,l,c] = concat(cjv[:247], cls, cjv[247:]) + pos_embed
__global__ __launch_bounds__(256) void build_hidden_kernel(
    const float* __restrict__ cjv, const float* __restrict__ cls,
    const float* __restrict__ pos, float* __restrict__ hidden)
{
    int i = blockIdx.x * 256 + threadIdx.x;
    int c = i % D_;
    int l = (i / D_) % L_;
    int b = i / (D_ * L_);
    float v;
    if (l < 247)       v = cjv[((size_t)b * 494 + l) * D_ + c];
    else if (l == 247) v = cls[c];
    else               v = cjv[((size_t)b * 494 + (l - 1)) * D_ + c];
    hidden[i] = v + pos[(size_t)l * D_ + c];
}

// resid = hidden (+ resid); hbf <- bf16(rmsnorm(resid)*w)
__global__ __launch_bounds__(128) void resnorm_kernel(
    const float* __restrict__ hidden, float* __restrict__ resid,
    const float* __restrict__ w, u16* __restrict__ hbf, int first)
{
    int m = blockIdx.x, tid = threadIdx.x;
    size_t base = (size_t)m * D_;
    float v[3]; float ss = 0.f;
#pragma unroll
    for (int i = 0; i < 3; ++i) {
        int c = tid + i * 128;
        float r = hidden[base + c];
        if (!first) r += resid[base + c];
        resid[base + c] = r;
        v[i] = r; ss += r * r;
    }
    ss += __shfl_xor(ss, 32); ss += __shfl_xor(ss, 16); ss += __shfl_xor(ss, 8);
    ss += __shfl_xor(ss, 4);  ss += __shfl_xor(ss, 2);  ss += __shfl_xor(ss, 1);
    __shared__ float sred[2];
    if ((tid & 63) == 0) sred[tid >> 6] = ss;
    __syncthreads();
    float scale = rsqrtf((sred[0] + sred[1]) * (1.f / D_) + 1e-5f);
#pragma unroll
    for (int i = 0; i < 3; ++i) {
        int c = tid + i * 128;
        hbf[base + c] = f2bf(v[i] * scale * w[c]);
    }
}

// ============ MFMA GEMM: C(M,N) = alpha * A(M,K)bf16 @ W(N,K)bf16^T ============
// 128x128 tile, 4 waves (2x2 of 64x64), 4x4 16x16x32 fragments per wave.
// LDS stride 40 u16 (pad) -> conflict-free-ish ds_read_b128.
// Requires: K % 32 == 0, N % 128 == 0; M guarded (clamp load, guard store).
template<int CF32>
__global__ __launch_bounds__(256) void gemm_mfma_bt(
    const u16* __restrict__ A, const u16* __restrict__ W, void* __restrict__ Cv,
    int M, int N, int K, int ldc, float alpha)
{
    __shared__ __align__(16) u16 As[128 * 40];
    __shared__ __align__(16) u16 Ws[128 * 40];
    int tid = threadIdx.x;
    int wave = tid >> 6, lane = tid & 63;
    int m0 = blockIdx.x * 128, n0 = blockIdx.y * 128;
    int wm = (wave >> 1) * 64, wn = (wave & 1) * 64;
    int ml = lane & 15, quad = lane >> 4;

    float4v acc[4][4];
#pragma unroll
    for (int i = 0; i < 4; ++i)
#pragma unroll
        for (int j = 0; j < 4; ++j)
#pragma unroll
            for (int r = 0; r < 4; ++r) acc[i][j][r] = 0.f;

    int srow = tid >> 2;           // 0..63
    int scol = (tid & 3) * 8;      // 0,8,16,24

    for (int k0 = 0; k0 < K; k0 += 32) {
#pragma unroll
        for (int p = 0; p < 2; ++p) {
            int row = srow + p * 64;
            int gm = m0 + row; if (gm >= M) gm = M - 1;
            *(uint4*)&As[row * 40 + scol] =
                *(const uint4*)(A + (size_t)gm * K + k0 + scol);
            int gn = n0 + row;
            *(uint4*)&Ws[row * 40 + scol] =
                *(const uint4*)(W + (size_t)gn * K + k0 + scol);
        }
        __syncthreads();
        short8 af[4], bfr[4];
#pragma unroll
        for (int i = 0; i < 4; ++i) {
            af[i]  = *(const short8*)&As[(wm + i * 16 + ml) * 40 + quad * 8];
            bfr[i] = *(const short8*)&Ws[(wn + i * 16 + ml) * 40 + quad * 8];
        }
#pragma unroll
        for (int i = 0; i < 4; ++i)
#pragma unroll
            for (int j = 0; j < 4; ++j)
                acc[i][j] = __builtin_amdgcn_mfma_f32_16x16x32_bf16(
                    af[i], bfr[j], acc[i][j], 0, 0, 0);
        __syncthreads();
    }

#pragma unroll
    for (int i = 0; i < 4; ++i)
#pragma unroll
        for (int j = 0; j < 4; ++j)
#pragma unroll
            for (int r = 0; r < 4; ++r) {
                int m = m0 + wm + i * 16 + quad * 4 + r;
                if (m >= M) continue;
                int n = n0 + wn + j * 16 + ml;
                float val = alpha * acc[i][j][r];
                if (CF32) ((float*)Cv)[(size_t)m * ldc + n] = val;
                else      ((u16*)Cv)[(size_t)m * ldc + n] = f2bf(val);
            }
}

// causal depthwise conv (K=4) + bias + silu, in scan order; xin = xz[:, :768]
__global__ __launch_bounds__(256) void conv_silu_kernel(
    const u16* __restrict__ xz, const float* __restrict__ cw,
    const float* __restrict__ cb, u16* __restrict__ xc, int rev)
{
    int i = blockIdx.x * 256 + threadIdx.x;
    int d = i % DI_;
    int s = (i / DI_) % L_;
    int b = i / (DI_ * L_);
    float acc = cb[d];
#pragma unroll
    for (int k = 0; k < 4; ++k) {
        int t = s - 3 + k;
        if (t >= 0) {
            int lorig = rev ? (L_ - 1 - t) : t;
            acc += cw[d * 4 + k] * bf2f(xz[((size_t)b * L_ + lorig) * 1536 + d]);
        }
    }
    xc[i] = f2bf(silu_f(acc));
}

// dbl(m, 56) = xc(m, 768) @ xpW(56,768)^T ; one block per token
__global__ __launch_bounds__(256) void xproj_kernel(
    const u16* __restrict__ xc, const float* __restrict__ xpW, float* __restrict__ dbl)
{
    int m = blockIdx.x;
    __shared__ float xs[DI_];
    int tid = threadIdx.x;
    for (int i = tid; i < DI_; i += 256) xs[i] = bf2f(xc[(size_t)m * DI_ + i]);
    __syncthreads();
    int wave = tid >> 6, lane = tid & 63;
    for (int e = wave; e < 56; e += 4) {
        const float* wr = xpW + (size_t)e * DI_;
        float s = 0.f;
#pragma unroll
        for (int i = 0; i < DI_ / 64; ++i) s += xs[lane + 64 * i] * wr[lane + 64 * i];
        s += __shfl_xor(s, 32); s += __shfl_xor(s, 16); s += __shfl_xor(s, 8);
        s += __shfl_xor(s, 4);  s += __shfl_xor(s, 2);  s += __shfl_xor(s, 1);
        if (lane == 0) dbl[(size_t)m * 56 + e] = s;
    }
}

// ================= segmented selective scan =================
__device__ __forceinline__ float dt_delta(
    const float* __restrict__ row, const float* W, float bias)
{
    float s = bias;
    const float4* pd = reinterpret_cast<const float4*>(row);
#pragma unroll
    for (int r = 0; r < 6; ++r) {
        float4 d4 = pd[r];
        s += W[4 * r + 0] * d4.x + W[4 * r + 1] * d4.y
           + W[4 * r + 2] * d4.z + W[4 * r + 3] * d4.w;
    }
    return (s > 20.f) ? s : __logf(1.f + __expf(s));
}

__global__ __launch_bounds__(64) void scan_part1_kernel(
    const u16* __restrict__ xc, const float* __restrict__ dbl,
    const float* __restrict__ dtW, const float* __restrict__ dtb,
    const float* __restrict__ Alog,
    float* __restrict__ P_buf, float* __restrict__ q_buf)
{
    int lane = threadIdx.x;
    int blk = blockIdx.x;
    int s = blk % SEG;
    int bd = blk / SEG;
    int b = bd / 12, dblk = bd % 12;
    int d = dblk * 64 + lane;
    size_t mb = (size_t)b * L_;
    int t0 = s * TL;
    int t1 = (t0 + TL < L_) ? (t0 + TL) : L_;

    float A[16];
    {
        const float4* ap = reinterpret_cast<const float4*>(Alog + (size_t)d * 16);
#pragma unroll
        for (int i = 0; i < 4; ++i) {
            float4 a4 = ap[i];
            A[4 * i + 0] = -__expf(a4.x); A[4 * i + 1] = -__expf(a4.y);
            A[4 * i + 2] = -__expf(a4.z); A[4 * i + 3] = -__expf(a4.w);
        }
    }
    float W[24];
    {
        const float4* wp = reinterpret_cast<const float4*>(dtW + (size_t)d * 24);
#pragma unroll
        for (int i = 0; i < 6; ++i) {
            float4 w4 = wp[i];
            W[4 * i + 0] = w4.x; W[4 * i + 1] = w4.y;
            W[4 * i + 2] = w4.z; W[4 * i + 3] = w4.w;
        }
    }
    float bias = dtb[d];
    float h[16], P[16];
#pragma unroll
    for (int i = 0; i < 16; ++i) { h[i] = 0.f; P[i] = 1.f; }

    for (int t = t0; t < t1; ++t) {
        const float* row = dbl + (mb + t) * 56;
        float dl = dt_delta(row, W, bias);
        float xv = bf2f(xc[(mb + t) * DI_ + d]);
        float dlxv = dl * xv;
        const float4* pb = reinterpret_cast<const float4*>(row + 24);
#pragma unroll
        for (int j = 0; j < 4; ++j) {
            float4 B4 = pb[j];
            float e0 = __expf(dl * A[4 * j + 0]);
            float e1 = __expf(dl * A[4 * j + 1]);
            float e2 = __expf(dl * A[4 * j + 2]);
            float e3 = __expf(dl * A[4 * j + 3]);
            h[4 * j + 0] = e0 * h[4 * j + 0] + dlxv * B4.x;
            h[4 * j + 1] = e1 * h[4 * j + 1] + dlxv * B4.y;
            h[4 * j + 2] = e2 * h[4 * j + 2] + dlxv * B4.z;
            h[4 * j + 3] = e3 * h[4 * j + 3] + dlxv * B4.w;
            P[4 * j + 0] *= e0; P[4 * j + 1] *= e1;
            P[4 * j + 2] *= e2; P[4 * j + 3] *= e3;
        }
    }
    size_t base = ((size_t)blk * 16) * 64 + lane;
#pragma unroll
    for (int n = 0; n < 16; ++n) {
        P_buf[base + (size_t)n * 64] = P[n];
        q_buf[base + (size_t)n * 64] = h[n];
    }
}

// Phase 2: per (b,d): hin[0]=0; hin[s+1] = P[s]*hin[s] + q[s]; q[s] <- hin[s]
__global__ __launch_bounds__(64) void scan_combine_kernel(
    const float* __restrict__ P_buf, float* __restrict__ q_buf)
{
    int lane = threadIdx.x;
    int bd = blockIdx.x;
    float h[16];
#pragma unroll
    for (int i = 0; i < 16; ++i) h[i] = 0.f;
    for (int s = 0; s < SEG; ++s) {
        size_t base = ((size_t)(bd * SEG + s) * 16) * 64 + lane;
#pragma unroll
        for (int n = 0; n < 16; ++n) {
            size_t idx = base + (size_t)n * 64;
            float Pv = P_buf[idx];
            float qv = q_buf[idx];
            q_buf[idx] = h[n];
            h[n] = Pv * h[n] + qv;
        }
    }
}

// Phase 3: rescan from true hin, produce y
template<int REV>
__global__ __launch_bounds__(64) void scan_part3_kernel(
    const u16* __restrict__ xc, const float* __restrict__ dbl,
    const u16* __restrict__ xz, const float* __restrict__ dtW,
    const float* __restrict__ dtb, const float* __restrict__ Alog,
    const float* __restrict__ Dp, const float* __restrict__ q_buf,
    u16* __restrict__ ysum)
{
    int lane = threadIdx.x;
    int blk = blockIdx.x;
    int s = blk % SEG;
    int bd = blk / SEG;
    int b = bd / 12, dblk = bd % 12;
    int d = dblk * 64 + lane;
    size_t mb = (size_t)b * L_;
    int t0 = s * TL;
    int t1 = (t0 + TL < L_) ? (t0 + TL) : L_;

    float A[16];
    {
        const float4* ap = reinterpret_cast<const float4*>(Alog + (size_t)d * 16);
#pragma unroll
        for (int i = 0; i < 4; ++i) {
            float4 a4 = ap[i];
            A[4 * i + 0] = -__expf(a4.x); A[4 * i + 1] = -__expf(a4.y);
            A[4 * i + 2] = -__expf(a4.z); A[4 * i + 3] = -__expf(a4.w);
        }
    }
    float W[24];
    {
        const float4* wp = reinterpret_cast<const float4*>(dtW + (size_t)d * 24);
#pragma unroll
        for (int i = 0; i < 6; ++i) {
            float4 w4 = wp[i];
            W[4 * i + 0] = w4.x; W[4 * i + 1] = w4.y;
            W[4 * i + 2] = w4.z; W[4 * i + 3] = w4.w;
        }
    }
    float bias = dtb[d];
    float Dval = Dp[d];
    float h[16];
    {
        size_t base = ((size_t)blk * 16) * 64 + lane;
#pragma unroll
        for (int n = 0; n < 16; ++n) h[n] = q_buf[base + (size_t)n * 64];
    }

    for (int t = t0; t < t1; ++t) {
        const float* row = dbl + (mb + t) * 56;
        float dl = dt_delta(row, W, bias);
        float xv = bf2f(xc[(mb + t) * DI_ + d]);
        float dlxv = dl * xv;
        const float4* pb = reinterpret_cast<const float4*>(row + 24);
        const float4* pc = reinterpret_cast<const float4*>(row + 40);
        float a0 = 0.f, a1 = 0.f, a2 = 0.f, a3 = 0.f;
#pragma unroll
        for (int j = 0; j < 4; ++j) {
            float4 B4 = pb[j], C4 = pc[j];
            float e0 = __expf(dl * A[4 * j + 0]);
            float e1 = __expf(dl * A[4 * j + 1]);
            float e2 = __expf(dl * A[4 * j + 2]);
            float e3 = __expf(dl * A[4 * j + 3]);
            h[4 * j + 0] = e0 * h[4 * j + 0] + dlxv * B4.x;
            h[4 * j + 1] = e1 * h[4 * j + 1] + dlxv * B4.y;
            h[4 * j + 2] = e2 * h[4 * j + 2] + dlxv * B4.z;
            h[4 * j + 3] = e3 * h[4 * j + 3] + dlxv * B4.w;
            a0 += h[4 * j + 0] * C4.x;
            a1 += h[4 * j + 1] * C4.y;
            a2 += h[4 * j + 2] * C4.z;
            a3 += h[4 * j + 3] * C4.w;
        }
        float y = (a0 + a1) + (a2 + a3) + xv * Dval;
        int lorig = REV ? (L_ - 1 - t) : t;
        y *= silu_f(bf2f(xz[(mb + lorig) * 1536 + 768 + d]));
        if (REV) y += bf2f(ysum[(mb + lorig) * DI_ + d]);
        ysum[(mb + lorig) * DI_ + d] = f2bf(y);
    }
}

// final: residual+hidden, rmsnorm, permute+slice, store bf16 or f32 per flag
__global__ __launch_bounds__(128) void final_kernel(
    const float* __restrict__ hidden, const float* __restrict__ resid,
    const float* __restrict__ w, void* __restrict__ out,
    const int* __restrict__ flag)
{
    int blk = blockIdx.x;
    int b = blk / 446, tok = blk % 446;
    int lorig; size_t dst;
    if (tok == 0)      { lorig = 247; dst = (size_t)b * D_; }
    else if (tok <= 14){ int j = tok - 1; lorig = 49 + j; dst = 6144 + ((size_t)b * 14 + j) * D_; }
    else               { int v = tok - 15; lorig = (v < 184) ? (63 + v) : (64 + v);
                         dst = 92160 + ((size_t)b * 431 + v) * D_; }
    size_t base = ((size_t)b * L_ + lorig) * D_;
    int tid = threadIdx.x;
    float v3[3]; float ss = 0.f;
#pragma unroll
    for (int i = 0; i < 3; ++i) {
        int c = tid + i * 128;
        float r = hidden[base + c] + resid[base + c];
        v3[i] = r; ss += r * r;
    }
    ss += __shfl_xor(ss, 32); ss += __shfl_xor(ss, 16); ss += __shfl_xor(ss, 8);
    ss += __shfl_xor(ss, 4);  ss += __shfl_xor(ss, 2);  ss += __shfl_xor(ss, 1);
    __shared__ float sred[2];
    if ((tid & 63) == 0) sred[tid >> 6] = ss;
    __syncthreads();
    float scale = rsqrtf((sred[0] + sred[1]) * (1.f / D_) + 1e-5f);
    int isbf = *flag;
#pragma unroll
    for (int i = 0; i < 3; ++i) {
        int c = tid + i * 128;
        float val = v3[i] * scale * w[c];
        if (isbf) ((u16*)out)[dst + c] = f2bf(val);
        else      ((float*)out)[dst + c] = val;
    }
}

extern "C" void kernel_launch(void* const* d_in, const int* in_sizes, int n_in,
                              void* d_out, int out_size, void* d_ws, size_t ws_size,
                              hipStream_t stream) {
    // ---- workspace layout (~116 MB)
    char* wsb = (char*)d_ws;
    int* flag = (int*)wsb;  wsb += 16;

    const int cn[14] = {3035136, 384, 190080, 2359296, 24576, 6144, 344064,
                        147456, 6144, 98304, 6144, 1179648, 1536, 384};
    const int raw_idx[14] = {0, 2, 3, 4, 5, 6, 7, 8, 9, 10, 11, 12, 13, 14};
    const int tobf[14]    = {0, 0, 0, 1, 0, 0, 0, 0, 0, 0, 0, 1, 0, 0};
    void* canon[14];
    for (int i = 0; i < 14; ++i) {
        canon[i] = (void*)wsb;
        wsb += (size_t)cn[i] * (tobf[i] ? 2 : 4);
    }
    const float* cjv  = (const float*)canon[0];
    const float* cls  = (const float*)canon[1];
    const float* pos  = (const float*)canon[2];
    const u16*   inWb = (const u16*)canon[3];
    const float* cW   = (const float*)canon[4];
    const float* cB   = (const float*)canon[5];
    const float* xpW  = (const float*)canon[6];
    const float* dtW  = (const float*)canon[7];
    const float* dtB  = (const float*)canon[8];
    const float* Alog = (const float*)canon[9];
    const float* Dsk  = (const float*)canon[10];
    const u16*   outWb= (const u16*)canon[11];
    const float* nw   = (const float*)canon[12];
    const float* fnw  = (const float*)canon[13];

    const int M = B_ * L_;  // 7920 tokens
    float* hidden = (float*)wsb;  wsb += (size_t)M * D_ * 4;
    float* resid  = (float*)wsb;  wsb += (size_t)M * D_ * 4;
    float* dbl    = (float*)wsb;  wsb += (size_t)M * 56 * 4;
    u16*   xz     = (u16*)wsb;    wsb += (size_t)M * 1536 * 2;
    u16*   xc     = (u16*)wsb;    wsb += (size_t)M * DI_ * 2;
    u16*   ysum   = (u16*)wsb;    wsb += (size_t)M * DI_ * 2;
    u16*   hbf    = (u16*)wsb;    wsb += (size_t)M * D_ * 2;
    float* P_buf  = (float*)wsb;  wsb += (size_t)B_ * 12 * SEG * 16 * 64 * 4;
    float* q_buf  = (float*)wsb;  wsb += (size_t)B_ * 12 * SEG * 16 * 64 * 4;

    detect_kernel<<<1, 256, 0, stream>>>((const u16*)d_in[10], flag);
    {
        CvtArgs ca;
        int maxn = 0;
        for (int i = 0; i < 14; ++i) {
            ca.src[i] = d_in[raw_idx[i]]; ca.dst[i] = canon[i];
            ca.n[i] = cn[i]; ca.tobf[i] = tobf[i];
            if (cn[i] > maxn) maxn = cn[i];
        }
        cvt_all_kernel<<<dim3((maxn + 255) / 256, 14), 256, 0, stream>>>(ca, flag);
    }

    build_hidden_kernel<<<(M * D_) / 256, 256, 0, stream>>>(cjv, cls, pos, hidden);

    const int scan_grid = B_ * 12 * SEG;   // 1536
    const int gmb = (M + 127) / 128;       // 62
    for (int l = 0; l < 4; ++l) {
        resnorm_kernel<<<M, 128, 0, stream>>>(hidden, resid, nw + (size_t)l * D_, hbf, l == 0);
        gemm_mfma_bt<0><<<dim3(gmb, 1536 / 128), 256, 0, stream>>>(
            hbf, inWb + (size_t)l * 1536 * D_, xz, M, 1536, D_, 1536, 1.f);
        for (int dir = 0; dir < 2; ++dir) {
            int ld = l * 2 + dir;
            const float* dtWl = dtW + (size_t)ld * DI_ * DTR_;
            const float* dtBl = dtB + (size_t)ld * DI_;
            const float* All  = Alog + (size_t)ld * DI_ * DS_;
            const float* Dl   = Dsk + (size_t)ld * DI_;
            conv_silu_kernel<<<(M * DI_) / 256, 256, 0, stream>>>(
                xz, cW + (size_t)ld * DI_ * 4, cB + (size_t)ld * DI_, xc, dir);
            xproj_kernel<<<M, 256, 0, stream>>>(xc, xpW + (size_t)ld * 56 * DI_, dbl);
            scan_part1_kernel<<<scan_grid, 64, 0, stream>>>(
                xc, dbl, dtWl, dtBl, All, P_buf, q_buf);
            scan_combine_kernel<<<B_ * 12, 64, 0, stream>>>(P_buf, q_buf);
            if (dir == 0)
                scan_part3_kernel<0><<<scan_grid, 64, 0, stream>>>(
                    xc, dbl, xz, dtWl, dtBl, All, Dl, q_buf, ysum);
            else
                scan_part3_kernel<1><<<scan_grid, 64, 0, stream>>>(
                    xc, dbl, xz, dtWl, dtBl, All, Dl, q_buf, ysum);
        }
        gemm_mfma_bt<1><<<dim3(gmb, 384 / 128), 256, 0, stream>>>(
            ysum, outWb + (size_t)l * D_ * DI_, hidden, M, 384, DI_, 384, 0.5f);
    }

    final_kernel<<<B_ * 446, 128, 0, stream>>>(hidden, resid, fnw, d_out, flag);
}

// Round 8
// 2016.734 us; speedup vs baseline: 2.8992x; 1.0603x over previous
//
#include <hip/hip_runtime.h>

typedef unsigned short u16;
typedef __attribute__((ext_vector_type(8))) short short8;
typedef __attribute__((ext_vector_type(4))) float float4v;

#define B_   16
#define L_   495
#define D_   384
#define DI_  768
#define DS_  16
#define DTR_ 24
#define SEG  8
#define TL   62   // ceil(495/8)
#define M_   (B_ * L_)

__device__ __forceinline__ float bf2f(u16 u) {
    return __uint_as_float(((unsigned)u) << 16);
}
__device__ __forceinline__ u16 f2bf(float f) {
    unsigned u = __float_as_uint(f);
    unsigned r = 0x7fffu + ((u >> 16) & 1u);
    return (u16)((u + r) >> 16);
}
__device__ __forceinline__ float silu_f(float x) {
    return x / (1.f + __expf(-x));
}

// ---- dtype detector (parallel): A_log in [0,2.78] as bf16 => bad==0 -> bf16.
__global__ __launch_bounds__(256) void detect_kernel(
    const u16* __restrict__ alog_raw, int* __restrict__ bad)
{
    int i = blockIdx.x * 256 + threadIdx.x;   // grid 384 -> 98304
    float v = bf2f(alog_raw[i]);
    int b = !(v >= -1e-3f && v <= 2.8f);
    unsigned long long m = __ballot(b);
    if ((threadIdx.x & 63) == 0 && m) atomicAdd(bad, (int)__popcll(m));
}

// ---- batched convert (blockIdx.y = tensor). tobf: emit bf16 instead of f32.
struct CvtArgs {
    const void* src[11];
    void* dst[11];
    int n[11];
    int tobf[11];
};
__global__ __launch_bounds__(256) void cvt_all_kernel(CvtArgs a, const int* __restrict__ bad)
{
    int t = blockIdx.y;
    int i = blockIdx.x * 256 + threadIdx.x;
    if (i >= a.n[t]) return;
    int isbf = (*bad == 0);
    if (a.tobf[t]) {
        u16 v = isbf ? ((const u16*)a.src[t])[i] : f2bf(((const float*)a.src[t])[i]);
        ((u16*)a.dst[t])[i] = v;
    } else {
        float v = isbf ? bf2f(((const u16*)a.src[t])[i]) : ((const float*)a.src[t])[i];
        ((float*)a.dst[t])[i] = v;
    }
}

// hidden[b,l,c] = concat(cjv[:247], cls, cjv[247:]) + pos_embed  (raw inputs)
__global__ __launch_bounds__(256) void build_hidden_kernel(
    const void* __restrict__ cjv, const void* __restrict__ cls,
    const void* __restrict__ pos, float* __restrict__ hidden,
    const int* __restrict__ bad)
{
    int isbf = (*bad == 0);
    int i = blockIdx.x * 256 + threadIdx.x;
    int c = i % D_;
    int l = (i / D_) % L_;
    int b = i / (D_ * L_);
    size_t si;
    const void* sp;
    if (l < 247)       { sp = cjv; si = ((size_t)b * 494 + l) * D_ + c; }
    else if (l == 247) { sp = cls; si = c; }
    else               { sp = cjv; si = ((size_t)b * 494 + (l - 1)) * D_ + c; }
    float v = isbf ? bf2f(((const u16*)sp)[si]) : ((const float*)sp)[si];
    size_t pi = (size_t)l * D_ + c;
    float p = isbf ? bf2f(((const u16*)pos)[pi]) : ((const float*)pos)[pi];
    hidden[i] = v + p;
}

// resid = hidden (+ resid); hbf <- bf16(rmsnorm(resid)*w)
__global__ __launch_bounds__(128) void resnorm_kernel(
    const float* __restrict__ hidden, float* __restrict__ resid,
    const float* __restrict__ w, u16* __restrict__ hbf, int first)
{
    int m = blockIdx.x, tid = threadIdx.x;
    size_t base = (size_t)m * D_;
    float v[3]; float ss = 0.f;
#pragma unroll
    for (int i = 0; i < 3; ++i) {
        int c = tid + i * 128;
        float r = hidden[base + c];
        if (!first) r += resid[base + c];
        resid[base + c] = r;
        v[i] = r; ss += r * r;
    }
    ss += __shfl_xor(ss, 32); ss += __shfl_xor(ss, 16); ss += __shfl_xor(ss, 8);
    ss += __shfl_xor(ss, 4);  ss += __shfl_xor(ss, 2);  ss += __shfl_xor(ss, 1);
    __shared__ float sred[2];
    if ((tid & 63) == 0) sred[tid >> 6] = ss;
    __syncthreads();
    float scale = rsqrtf((sred[0] + sred[1]) * (1.f / D_) + 1e-5f);
#pragma unroll
    for (int i = 0; i < 3; ++i) {
        int c = tid + i * 128;
        hbf[base + c] = f2bf(v[i] * scale * w[c]);
    }
}

// ============ MFMA GEMM: C(M,N) = alpha * A(M,K)bf16 @ W(N,K)bf16^T ============
template<int CF32>
__global__ __launch_bounds__(256) void gemm_mfma_bt(
    const u16* __restrict__ A, const u16* __restrict__ W, void* __restrict__ Cv,
    int M, int N, int K, int ldc, float alpha)
{
    __shared__ __align__(16) u16 As[128 * 40];
    __shared__ __align__(16) u16 Ws[128 * 40];
    int tid = threadIdx.x;
    int wave = tid >> 6, lane = tid & 63;
    int m0 = blockIdx.x * 128, n0 = blockIdx.y * 128;
    int wm = (wave >> 1) * 64, wn = (wave & 1) * 64;
    int ml = lane & 15, quad = lane >> 4;

    float4v acc[4][4];
#pragma unroll
    for (int i = 0; i < 4; ++i)
#pragma unroll
        for (int j = 0; j < 4; ++j)
#pragma unroll
            for (int r = 0; r < 4; ++r) acc[i][j][r] = 0.f;

    int srow = tid >> 2;
    int scol = (tid & 3) * 8;

    for (int k0 = 0; k0 < K; k0 += 32) {
#pragma unroll
        for (int p = 0; p < 2; ++p) {
            int row = srow + p * 64;
            int gm = m0 + row; if (gm >= M) gm = M - 1;
            *(uint4*)&As[row * 40 + scol] =
                *(const uint4*)(A + (size_t)gm * K + k0 + scol);
            int gn = n0 + row;
            *(uint4*)&Ws[row * 40 + scol] =
                *(const uint4*)(W + (size_t)gn * K + k0 + scol);
        }
        __syncthreads();
        short8 af[4], bfr[4];
#pragma unroll
        for (int i = 0; i < 4; ++i) {
            af[i]  = *(const short8*)&As[(wm + i * 16 + ml) * 40 + quad * 8];
            bfr[i] = *(const short8*)&Ws[(wn + i * 16 + ml) * 40 + quad * 8];
        }
#pragma unroll
        for (int i = 0; i < 4; ++i)
#pragma unroll
            for (int j = 0; j < 4; ++j)
                acc[i][j] = __builtin_amdgcn_mfma_f32_16x16x32_bf16(
                    af[i], bfr[j], acc[i][j], 0, 0, 0);
        __syncthreads();
    }

#pragma unroll
    for (int i = 0; i < 4; ++i)
#pragma unroll
        for (int j = 0; j < 4; ++j)
#pragma unroll
            for (int r = 0; r < 4; ++r) {
                int m = m0 + wm + i * 16 + quad * 4 + r;
                if (m >= M) continue;
                int n = n0 + wn + j * 16 + ml;
                float val = alpha * acc[i][j][r];
                if (CF32) ((float*)Cv)[(size_t)m * ldc + n] = val;
                else      ((u16*)Cv)[(size_t)m * ldc + n] = f2bf(val);
            }
}

// causal depthwise conv (K=4) + bias + silu, both dirs (blockIdx.y = dir)
__global__ __launch_bounds__(256) void conv_silu_kernel(
    const u16* __restrict__ xz, const float* __restrict__ cw_l,
    const float* __restrict__ cb_l, u16* __restrict__ xc2)
{
    int dir = blockIdx.y;
    const float* cw = cw_l + (size_t)dir * DI_ * 4;
    const float* cb = cb_l + (size_t)dir * DI_;
    u16* xc = xc2 + (size_t)dir * M_ * DI_;
    int i = blockIdx.x * 256 + threadIdx.x;
    int d = i % DI_;
    int s = (i / DI_) % L_;
    int b = i / (DI_ * L_);
    float acc = cb[d];
#pragma unroll
    for (int k = 0; k < 4; ++k) {
        int t = s - 3 + k;
        if (t >= 0) {
            int lorig = dir ? (L_ - 1 - t) : t;
            acc += cw[d * 4 + k] * bf2f(xz[((size_t)b * L_ + lorig) * 1536 + d]);
        }
    }
    xc[i] = f2bf(silu_f(acc));
}

// dbl2[dir](m,56) = xc2[dir](m,768) @ xpW[dir](56,768)^T
// 16 tokens/block (4/wave); xpW staged to LDS in 14-row chunks (L2 read once
// per block); x rows held in 48 VGPRs as unpacked f32 pairs.
__global__ __launch_bounds__(256) void xproj_kernel(
    const u16* __restrict__ xc2, const float* __restrict__ xpW_l,
    float* __restrict__ dbl2)
{
    int dir = blockIdx.y;
    const u16* xc = xc2 + (size_t)dir * M_ * DI_;
    const float* xpW = xpW_l + (size_t)dir * 56 * DI_;
    float* dbl = dbl2 + (size_t)dir * M_ * 56;
    int tid = threadIdx.x;
    int wave = tid >> 6, lane = tid & 63;
    int m0 = blockIdx.x * 16 + wave * 4;

    float x[4][12];
#pragma unroll
    for (int tk = 0; tk < 4; ++tk)
#pragma unroll
        for (int i = 0; i < 6; ++i) {
            unsigned u = *(const unsigned*)&xc[(size_t)(m0 + tk) * DI_ + 2 * lane + 128 * i];
            x[tk][2 * i]     = __uint_as_float(u << 16);
            x[tk][2 * i + 1] = __uint_as_float(u & 0xffff0000u);
        }

    __shared__ __align__(16) float wsd[14 * DI_];
    for (int ec = 0; ec < 4; ++ec) {
        const float4* wsrc = (const float4*)(xpW + (size_t)ec * 14 * DI_);
        for (int i = tid; i < 14 * DI_ / 4; i += 256)
            ((float4*)wsd)[i] = wsrc[i];
        __syncthreads();
#pragma unroll
        for (int e = 0; e < 14; ++e) {
            const float* wr = wsd + e * DI_;
            float a0 = 0.f, a1 = 0.f, a2 = 0.f, a3 = 0.f;
#pragma unroll
            for (int i = 0; i < 6; ++i) {
                float2 w2 = *(const float2*)&wr[2 * lane + 128 * i];
                a0 += w2.x * x[0][2 * i] + w2.y * x[0][2 * i + 1];
                a1 += w2.x * x[1][2 * i] + w2.y * x[1][2 * i + 1];
                a2 += w2.x * x[2][2 * i] + w2.y * x[2][2 * i + 1];
                a3 += w2.x * x[3][2 * i] + w2.y * x[3][2 * i + 1];
            }
#define RED_(a) a += __shfl_xor(a, 32); a += __shfl_xor(a, 16); a += __shfl_xor(a, 8); \
                a += __shfl_xor(a, 4);  a += __shfl_xor(a, 2);  a += __shfl_xor(a, 1);
            RED_(a0) RED_(a1) RED_(a2) RED_(a3)
#undef RED_
            float val = (lane == 0) ? a0 : (lane == 1) ? a1 : (lane == 2) ? a2 : a3;
            if (lane < 4) dbl[(size_t)(m0 + lane) * 56 + ec * 14 + e] = val;
        }
        __syncthreads();
    }
}

// ================= segmented selective scan =================
__device__ __forceinline__ float dt_delta(
    const float* __restrict__ row, const float* W, float bias)
{
    float s = bias;
    const float4* pd = reinterpret_cast<const float4*>(row);
#pragma unroll
    for (int r = 0; r < 6; ++r) {
        float4 d4 = pd[r];
        s += W[4 * r + 0] * d4.x + W[4 * r + 1] * d4.y
           + W[4 * r + 2] * d4.z + W[4 * r + 3] * d4.w;
    }
    return (s > 20.f) ? s : __logf(1.f + __expf(s));
}

__global__ __launch_bounds__(64) void scan_part1_kernel(
    const u16* __restrict__ xc, const float* __restrict__ dbl,
    const float* __restrict__ dtW, const float* __restrict__ dtb,
    const float* __restrict__ Alog,
    float* __restrict__ P_buf, float* __restrict__ q_buf)
{
    int lane = threadIdx.x;
    int blk = blockIdx.x;
    int s = blk % SEG;
    int bd = blk / SEG;
    int b = bd / 12, dblk = bd % 12;
    int d = dblk * 64 + lane;
    size_t mb = (size_t)b * L_;
    int t0 = s * TL;
    int t1 = (t0 + TL < L_) ? (t0 + TL) : L_;

    float A[16];
    {
        const float4* ap = reinterpret_cast<const float4*>(Alog + (size_t)d * 16);
#pragma unroll
        for (int i = 0; i < 4; ++i) {
            float4 a4 = ap[i];
            A[4 * i + 0] = -__expf(a4.x); A[4 * i + 1] = -__expf(a4.y);
            A[4 * i + 2] = -__expf(a4.z); A[4 * i + 3] = -__expf(a4.w);
        }
    }
    float W[24];
    {
        const float4* wp = reinterpret_cast<const float4*>(dtW + (size_t)d * 24);
#pragma unroll
        for (int i = 0; i < 6; ++i) {
            float4 w4 = wp[i];
            W[4 * i + 0] = w4.x; W[4 * i + 1] = w4.y;
            W[4 * i + 2] = w4.z; W[4 * i + 3] = w4.w;
        }
    }
    float bias = dtb[d];
    float h[16], P[16];
#pragma unroll
    for (int i = 0; i < 16; ++i) { h[i] = 0.f; P[i] = 1.f; }

    for (int t = t0; t < t1; ++t) {
        const float* row = dbl + (mb + t) * 56;
        float dl = dt_delta(row, W, bias);
        float xv = bf2f(xc[(mb + t) * DI_ + d]);
        float dlxv = dl * xv;
        const float4* pb = reinterpret_cast<const float4*>(row + 24);
#pragma unroll
        for (int j = 0; j < 4; ++j) {
            float4 B4 = pb[j];
            float e0 = __expf(dl * A[4 * j + 0]);
            float e1 = __expf(dl * A[4 * j + 1]);
            float e2 = __expf(dl * A[4 * j + 2]);
            float e3 = __expf(dl * A[4 * j + 3]);
            h[4 * j + 0] = e0 * h[4 * j + 0] + dlxv * B4.x;
            h[4 * j + 1] = e1 * h[4 * j + 1] + dlxv * B4.y;
            h[4 * j + 2] = e2 * h[4 * j + 2] + dlxv * B4.z;
            h[4 * j + 3] = e3 * h[4 * j + 3] + dlxv * B4.w;
            P[4 * j + 0] *= e0; P[4 * j + 1] *= e1;
            P[4 * j + 2] *= e2; P[4 * j + 3] *= e3;
        }
    }
    size_t base = ((size_t)blk * 16) * 64 + lane;
#pragma unroll
    for (int n = 0; n < 16; ++n) {
        P_buf[base + (size_t)n * 64] = P[n];
        q_buf[base + (size_t)n * 64] = h[n];
    }
}

// Phase 2: grid (192,4): blockIdx.y = state quad; each thread owns 4 states.
__global__ __launch_bounds__(64) void scan_combine_kernel(
    const float* __restrict__ P_buf, float* __restrict__ q_buf)
{
    int lane = threadIdx.x;
    int bd = blockIdx.x;
    int nq = blockIdx.y;
    float h[4] = {0.f, 0.f, 0.f, 0.f};
    for (int s = 0; s < SEG; ++s) {
        size_t base = ((size_t)(bd * SEG + s) * 16 + nq * 4) * 64 + lane;
#pragma unroll
        for (int n = 0; n < 4; ++n) {
            size_t idx = base + (size_t)n * 64;
            float Pv = P_buf[idx];
            float qv = q_buf[idx];
            q_buf[idx] = h[n];
            h[n] = Pv * h[n] + qv;
        }
    }
}

// Phase 3: rescan from true hin, produce y
template<int REV>
__global__ __launch_bounds__(64) void scan_part3_kernel(
    const u16* __restrict__ xc, const float* __restrict__ dbl,
    const u16* __restrict__ xz, const float* __restrict__ dtW,
    const float* __restrict__ dtb, const float* __restrict__ Alog,
    const float* __restrict__ Dp, const float* __restrict__ q_buf,
    u16* __restrict__ ysum)
{
    int lane = threadIdx.x;
    int blk = blockIdx.x;
    int s = blk % SEG;
    int bd = blk / SEG;
    int b = bd / 12, dblk = bd % 12;
    int d = dblk * 64 + lane;
    size_t mb = (size_t)b * L_;
    int t0 = s * TL;
    int t1 = (t0 + TL < L_) ? (t0 + TL) : L_;

    float A[16];
    {
        const float4* ap = reinterpret_cast<const float4*>(Alog + (size_t)d * 16);
#pragma unroll
        for (int i = 0; i < 4; ++i) {
            float4 a4 = ap[i];
            A[4 * i + 0] = -__expf(a4.x); A[4 * i + 1] = -__expf(a4.y);
            A[4 * i + 2] = -__expf(a4.z); A[4 * i + 3] = -__expf(a4.w);
        }
    }
    float W[24];
    {
        const float4* wp = reinterpret_cast<const float4*>(dtW + (size_t)d * 24);
#pragma unroll
        for (int i = 0; i < 6; ++i) {
            float4 w4 = wp[i];
            W[4 * i + 0] = w4.x; W[4 * i + 1] = w4.y;
            W[4 * i + 2] = w4.z; W[4 * i + 3] = w4.w;
        }
    }
    float bias = dtb[d];
    float Dval = Dp[d];
    float h[16];
    {
        size_t base = ((size_t)blk * 16) * 64 + lane;
#pragma unroll
        for (int n = 0; n < 16; ++n) h[n] = q_buf[base + (size_t)n * 64];
    }

    for (int t = t0; t < t1; ++t) {
        const float* row = dbl + (mb + t) * 56;
        float dl = dt_delta(row, W, bias);
        float xv = bf2f(xc[(mb + t) * DI_ + d]);
        float dlxv = dl * xv;
        const float4* pb = reinterpret_cast<const float4*>(row + 24);
        const float4* pc = reinterpret_cast<const float4*>(row + 40);
        float a0 = 0.f, a1 = 0.f, a2 = 0.f, a3 = 0.f;
#pragma unroll
        for (int j = 0; j < 4; ++j) {
            float4 B4 = pb[j], C4 = pc[j];
            float e0 = __expf(dl * A[4 * j + 0]);
            float e1 = __expf(dl * A[4 * j + 1]);
            float e2 = __expf(dl * A[4 * j + 2]);
            float e3 = __expf(dl * A[4 * j + 3]);
            h[4 * j + 0] = e0 * h[4 * j + 0] + dlxv * B4.x;
            h[4 * j + 1] = e1 * h[4 * j + 1] + dlxv * B4.y;
            h[4 * j + 2] = e2 * h[4 * j + 2] + dlxv * B4.z;
            h[4 * j + 3] = e3 * h[4 * j + 3] + dlxv * B4.w;
            a0 += h[4 * j + 0] * C4.x;
            a1 += h[4 * j + 1] * C4.y;
            a2 += h[4 * j + 2] * C4.z;
            a3 += h[4 * j + 3] * C4.w;
        }
        float y = (a0 + a1) + (a2 + a3) + xv * Dval;
        int lorig = REV ? (L_ - 1 - t) : t;
        y *= silu_f(bf2f(xz[(mb + lorig) * 1536 + 768 + d]));
        if (REV) y += bf2f(ysum[(mb + lorig) * DI_ + d]);
        ysum[(mb + lorig) * DI_ + d] = f2bf(y);
    }
}

// final: residual+hidden, rmsnorm, permute+slice, store bf16 or f32 per flag
__global__ __launch_bounds__(128) void final_kernel(
    const float* __restrict__ hidden, const float* __restrict__ resid,
    const float* __restrict__ w, void* __restrict__ out,
    const int* __restrict__ bad)
{
    int blk = blockIdx.x;
    int b = blk / 446, tok = blk % 446;
    int lorig; size_t dst;
    if (tok == 0)      { lorig = 247; dst = (size_t)b * D_; }
    else if (tok <= 14){ int j = tok - 1; lorig = 49 + j; dst = 6144 + ((size_t)b * 14 + j) * D_; }
    else               { int v = tok - 15; lorig = (v < 184) ? (63 + v) : (64 + v);
                         dst = 92160 + ((size_t)b * 431 + v) * D_; }
    size_t base = ((size_t)b * L_ + lorig) * D_;
    int tid = threadIdx.x;
    float v3[3]; float ss = 0.f;
#pragma unroll
    for (int i = 0; i < 3; ++i) {
        int c = tid + i * 128;
        float r = hidden[base + c] + resid[base + c];
        v3[i] = r; ss += r * r;
    }
    ss += __shfl_xor(ss, 32); ss += __shfl_xor(ss, 16); ss += __shfl_xor(ss, 8);
    ss += __shfl_xor(ss, 4);  ss += __shfl_xor(ss, 2);  ss += __shfl_xor(ss, 1);
    __shared__ float sred[2];
    if ((tid & 63) == 0) sred[tid >> 6] = ss;
    __syncthreads();
    float scale = rsqrtf((sred[0] + sred[1]) * (1.f / D_) + 1e-5f);
    int isbf = (*bad == 0);
#pragma unroll
    for (int i = 0; i < 3; ++i) {
        int c = tid + i * 128;
        float val = v3[i] * scale * w[c];
        if (isbf) ((u16*)out)[dst + c] = f2bf(val);
        else      ((float*)out)[dst + c] = val;
    }
}

extern "C" void kernel_launch(void* const* d_in, const int* in_sizes, int n_in,
                              void* d_out, int out_size, void* d_ws, size_t ws_size,
                              hipStream_t stream) {
    // ---- workspace layout (~117 MB)
    char* wsb = (char*)d_ws;
    int* bad = (int*)wsb;  wsb += 16;

    // canon tensors (11): inW(bf16), cW, cB, xpW, dtW, dtB, Alog, Dsk, outW(bf16), nw, fnw
    const int cn[11] = {2359296, 24576, 6144, 344064, 147456, 6144, 98304,
                        6144, 1179648, 1536, 384};
    const int raw_idx[11] = {4, 5, 6, 7, 8, 9, 10, 11, 12, 13, 14};
    const int tobf[11]    = {1, 0, 0, 0, 0, 0, 0, 0, 1, 0, 0};
    void* canon[11];
    for (int i = 0; i < 11; ++i) {
        canon[i] = (void*)wsb;
        wsb += (size_t)cn[i] * (tobf[i] ? 2 : 4);
    }
    const u16*   inWb = (const u16*)canon[0];
    const float* cW   = (const float*)canon[1];
    const float* cB   = (const float*)canon[2];
    const float* xpW  = (const float*)canon[3];
    const float* dtW  = (const float*)canon[4];
    const float* dtB  = (const float*)canon[5];
    const float* Alog = (const float*)canon[6];
    const float* Dsk  = (const float*)canon[7];
    const u16*   outWb= (const u16*)canon[8];
    const float* nw   = (const float*)canon[9];
    const float* fnw  = (const float*)canon[10];

    float* hidden = (float*)wsb;  wsb += (size_t)M_ * D_ * 4;
    float* resid  = (float*)wsb;  wsb += (size_t)M_ * D_ * 4;
    float* dbl2   = (float*)wsb;  wsb += (size_t)2 * M_ * 56 * 4;
    u16*   xz     = (u16*)wsb;    wsb += (size_t)M_ * 1536 * 2;
    u16*   xc2    = (u16*)wsb;    wsb += (size_t)2 * M_ * DI_ * 2;
    u16*   ysum   = (u16*)wsb;    wsb += (size_t)M_ * DI_ * 2;
    u16*   hbf    = (u16*)wsb;    wsb += (size_t)M_ * D_ * 2;
    float* P_buf  = (float*)wsb;  wsb += (size_t)B_ * 12 * SEG * 16 * 64 * 4;
    float* q_buf  = (float*)wsb;  wsb += (size_t)B_ * 12 * SEG * 16 * 64 * 4;

    hipMemsetAsync(bad, 0, 4, stream);
    detect_kernel<<<384, 256, 0, stream>>>((const u16*)d_in[10], bad);
    {
        CvtArgs ca;
        int maxn = 0;
        for (int i = 0; i < 11; ++i) {
            ca.src[i] = d_in[raw_idx[i]]; ca.dst[i] = canon[i];
            ca.n[i] = cn[i]; ca.tobf[i] = tobf[i];
            if (cn[i] > maxn) maxn = cn[i];
        }
        cvt_all_kernel<<<dim3((maxn + 255) / 256, 11), 256, 0, stream>>>(ca, bad);
    }

    build_hidden_kernel<<<(M_ * D_) / 256, 256, 0, stream>>>(
        d_in[0], d_in[2], d_in[3], hidden, bad);

    const int scan_grid = B_ * 12 * SEG;   // 1536
    const int gmb = (M_ + 127) / 128;      // 62
    for (int l = 0; l < 4; ++l) {
        resnorm_kernel<<<M_, 128, 0, stream>>>(hidden, resid, nw + (size_t)l * D_, hbf, l == 0);
        gemm_mfma_bt<0><<<dim3(gmb, 1536 / 128), 256, 0, stream>>>(
            hbf, inWb + (size_t)l * 1536 * D_, xz, M_, 1536, D_, 1536, 1.f);
        conv_silu_kernel<<<dim3((M_ * DI_) / 256, 2), 256, 0, stream>>>(
            xz, cW + (size_t)l * 2 * DI_ * 4, cB + (size_t)l * 2 * DI_, xc2);
        xproj_kernel<<<dim3(M_ / 16, 2), 256, 0, stream>>>(
            xc2, xpW + (size_t)l * 2 * 56 * DI_, dbl2);
        for (int dir = 0; dir < 2; ++dir) {
            int ld = l * 2 + dir;
            const u16* xcd = xc2 + (size_t)dir * M_ * DI_;
            const float* dbld = dbl2 + (size_t)dir * M_ * 56;
            const float* dtWl = dtW + (size_t)ld * DI_ * DTR_;
            const float* dtBl = dtB + (size_t)ld * DI_;
            const float* All  = Alog + (size_t)ld * DI_ * DS_;
            const float* Dl   = Dsk + (size_t)ld * DI_;
            scan_part1_kernel<<<scan_grid, 64, 0, stream>>>(
                xcd, dbld, dtWl, dtBl, All, P_buf, q_buf);
            scan_combine_kernel<<<dim3(B_ * 12, 4), 64, 0, stream>>>(P_buf, q_buf);
            if (dir == 0)
                scan_part3_kernel<0><<<scan_grid, 64, 0, stream>>>(
                    xcd, dbld, xz, dtWl, dtBl, All, Dl, q_buf, ysum);
            else
                scan_part3_kernel<1><<<scan_grid, 64, 0, stream>>>(
                    xcd, dbld, xz, dtWl, dtBl, All, Dl, q_buf, ysum);
        }
        gemm_mfma_bt<1><<<dim3(gmb, 384 / 128), 256, 0, stream>>>(
            ysum, outWb + (size_t)l * D_ * DI_, hidden, M_, 384, DI_, 384, 0.5f);
    }

    final_kernel<<<B_ * 446, 128, 0, stream>>>(hidden, resid, fnw, d_out, bad);
}

// Round 9
// 1414.535 us; speedup vs baseline: 4.1334x; 1.4257x over previous
//
#include <hip/hip_runtime.h>

typedef unsigned short u16;
typedef __attribute__((ext_vector_type(8))) short short8;
typedef __attribute__((ext_vector_type(4))) float float4v;

#define B_   16
#define L_   495
#define D_   384
#define DI_  768
#define DS_  16
#define DTR_ 24
#define SEG  8
#define TL   62   // ceil(495/8)
#define M_   (B_ * L_)
#define NBD  (B_ * 12)            // 192 (b,d-block) pairs
#define SCAN_GRID (NBD * SEG)     // 1536 per dir

__device__ __forceinline__ float bf2f(u16 u) {
    return __uint_as_float(((unsigned)u) << 16);
}
__device__ __forceinline__ u16 f2bf(float f) {
    unsigned u = __float_as_uint(f);
    unsigned r = 0x7fffu + ((u >> 16) & 1u);
    return (u16)((u + r) >> 16);
}
__device__ __forceinline__ float silu_f(float x) {
    return x / (1.f + __expf(-x));
}

// ---- dtype detector (parallel): A_log in [0,2.78] as bf16 => bad==0 -> bf16.
__global__ __launch_bounds__(256) void detect_kernel(
    const u16* __restrict__ alog_raw, int* __restrict__ bad)
{
    int i = blockIdx.x * 256 + threadIdx.x;   // grid 384 -> 98304
    float v = bf2f(alog_raw[i]);
    int b = !(v >= -1e-3f && v <= 2.8f);
    unsigned long long m = __ballot(b);
    if ((threadIdx.x & 63) == 0 && m) atomicAdd(bad, (int)__popcll(m));
}

// ---- batched convert (blockIdx.y = tensor). tobf: emit bf16 instead of f32.
struct CvtArgs {
    const void* src[11];
    void* dst[11];
    int n[11];
    int tobf[11];
};
__global__ __launch_bounds__(256) void cvt_all_kernel(CvtArgs a, const int* __restrict__ bad)
{
    int t = blockIdx.y;
    int i = blockIdx.x * 256 + threadIdx.x;
    if (i >= a.n[t]) return;
    int isbf = (*bad == 0);
    if (a.tobf[t]) {
        u16 v = isbf ? ((const u16*)a.src[t])[i] : f2bf(((const float*)a.src[t])[i]);
        ((u16*)a.dst[t])[i] = v;
    } else {
        float v = isbf ? bf2f(((const u16*)a.src[t])[i]) : ((const float*)a.src[t])[i];
        ((float*)a.dst[t])[i] = v;
    }
}

// hidden[b,l,c] = concat(cjv[:247], cls, cjv[247:]) + pos_embed  (raw inputs)
__global__ __launch_bounds__(256) void build_hidden_kernel(
    const void* __restrict__ cjv, const void* __restrict__ cls,
    const void* __restrict__ pos, float* __restrict__ hidden,
    const int* __restrict__ bad)
{
    int isbf = (*bad == 0);
    int i = blockIdx.x * 256 + threadIdx.x;
    int c = i % D_;
    int l = (i / D_) % L_;
    int b = i / (D_ * L_);
    size_t si;
    const void* sp;
    if (l < 247)       { sp = cjv; si = ((size_t)b * 494 + l) * D_ + c; }
    else if (l == 247) { sp = cls; si = c; }
    else               { sp = cjv; si = ((size_t)b * 494 + (l - 1)) * D_ + c; }
    float v = isbf ? bf2f(((const u16*)sp)[si]) : ((const float*)sp)[si];
    size_t pi = (size_t)l * D_ + c;
    float p = isbf ? bf2f(((const u16*)pos)[pi]) : ((const float*)pos)[pi];
    hidden[i] = v + p;
}

// resid = hidden (+ resid); hbf <- bf16(rmsnorm(resid)*w)
__global__ __launch_bounds__(128) void resnorm_kernel(
    const float* __restrict__ hidden, float* __restrict__ resid,
    const float* __restrict__ w, u16* __restrict__ hbf, int first)
{
    int m = blockIdx.x, tid = threadIdx.x;
    size_t base = (size_t)m * D_;
    float v[3]; float ss = 0.f;
#pragma unroll
    for (int i = 0; i < 3; ++i) {
        int c = tid + i * 128;
        float r = hidden[base + c];
        if (!first) r += resid[base + c];
        resid[base + c] = r;
        v[i] = r; ss += r * r;
    }
    ss += __shfl_xor(ss, 32); ss += __shfl_xor(ss, 16); ss += __shfl_xor(ss, 8);
    ss += __shfl_xor(ss, 4);  ss += __shfl_xor(ss, 2);  ss += __shfl_xor(ss, 1);
    __shared__ float sred[2];
    if ((tid & 63) == 0) sred[tid >> 6] = ss;
    __syncthreads();
    float scale = rsqrtf((sred[0] + sred[1]) * (1.f / D_) + 1e-5f);
#pragma unroll
    for (int i = 0; i < 3; ++i) {
        int c = tid + i * 128;
        hbf[base + c] = f2bf(v[i] * scale * w[c]);
    }
}

// ===== MFMA GEMM: C(M,N) = alpha * (A [+ A2])(M,K)bf16 @ W(N,K)bf16^T =====
// 128x128 tile, 4 waves (2x2 of 64x64), 4x4 16x16x32 fragments per wave.
template<int CF32, int SUM2>
__global__ __launch_bounds__(256) void gemm_mfma_bt(
    const u16* __restrict__ A, const u16* __restrict__ A2,
    const u16* __restrict__ W, void* __restrict__ Cv,
    int M, int N, int K, int ldc, float alpha)
{
    __shared__ __align__(16) u16 As[128 * 40];
    __shared__ __align__(16) u16 Ws[128 * 40];
    int tid = threadIdx.x;
    int wave = tid >> 6, lane = tid & 63;
    int m0 = blockIdx.x * 128, n0 = blockIdx.y * 128;
    int wm = (wave >> 1) * 64, wn = (wave & 1) * 64;
    int ml = lane & 15, quad = lane >> 4;

    float4v acc[4][4];
#pragma unroll
    for (int i = 0; i < 4; ++i)
#pragma unroll
        for (int j = 0; j < 4; ++j)
#pragma unroll
            for (int r = 0; r < 4; ++r) acc[i][j][r] = 0.f;

    int srow = tid >> 2;
    int scol = (tid & 3) * 8;

    for (int k0 = 0; k0 < K; k0 += 32) {
#pragma unroll
        for (int p = 0; p < 2; ++p) {
            int row = srow + p * 64;
            int gm = m0 + row; if (gm >= M) gm = M - 1;
            if (SUM2) {
                short8 a0 = *(const short8*)(A  + (size_t)gm * K + k0 + scol);
                short8 a1 = *(const short8*)(A2 + (size_t)gm * K + k0 + scol);
                u16 tmp[8];
#pragma unroll
                for (int r = 0; r < 8; ++r)
                    tmp[r] = f2bf(bf2f((u16)a0[r]) + bf2f((u16)a1[r]));
                *(uint4*)&As[row * 40 + scol] = *(const uint4*)tmp;
            } else {
                *(uint4*)&As[row * 40 + scol] =
                    *(const uint4*)(A + (size_t)gm * K + k0 + scol);
            }
            int gn = n0 + row;
            *(uint4*)&Ws[row * 40 + scol] =
                *(const uint4*)(W + (size_t)gn * K + k0 + scol);
        }
        __syncthreads();
        short8 af[4], bfr[4];
#pragma unroll
        for (int i = 0; i < 4; ++i) {
            af[i]  = *(const short8*)&As[(wm + i * 16 + ml) * 40 + quad * 8];
            bfr[i] = *(const short8*)&Ws[(wn + i * 16 + ml) * 40 + quad * 8];
        }
#pragma unroll
        for (int i = 0; i < 4; ++i)
#pragma unroll
            for (int j = 0; j < 4; ++j)
                acc[i][j] = __builtin_amdgcn_mfma_f32_16x16x32_bf16(
                    af[i], bfr[j], acc[i][j], 0, 0, 0);
        __syncthreads();
    }

#pragma unroll
    for (int i = 0; i < 4; ++i)
#pragma unroll
        for (int j = 0; j < 4; ++j)
#pragma unroll
            for (int r = 0; r < 4; ++r) {
                int m = m0 + wm + i * 16 + quad * 4 + r;
                if (m >= M) continue;
                int n = n0 + wn + j * 16 + ml;
                float val = alpha * acc[i][j][r];
                if (CF32) ((float*)Cv)[(size_t)m * ldc + n] = val;
                else      ((u16*)Cv)[(size_t)m * ldc + n] = f2bf(val);
            }
}

// ===== xproj MFMA GEMM: dbl2[dir](m,56) = xc2[dir](M,768) @ xpWb[dir](56,768)^T
// 128x64 tile (N padded 56->64; junk columns discarded at store).
__global__ __launch_bounds__(256) void xproj_gemm_kernel(
    const u16* __restrict__ xc2, const u16* __restrict__ xpWb_l,
    float* __restrict__ dbl2)
{
    int dir = blockIdx.y;
    const u16* A = xc2 + (size_t)dir * M_ * DI_;
    const u16* W = xpWb_l + (size_t)dir * 56 * DI_;
    float* C = dbl2 + (size_t)dir * M_ * 56;

    __shared__ __align__(16) u16 As[128 * 40];
    __shared__ __align__(16) u16 Ws[64 * 40];
    int tid = threadIdx.x;
    int wave = tid >> 6, lane = tid & 63;
    int m0 = blockIdx.x * 128;
    int wm = wave * 32;
    int ml = lane & 15, quad = lane >> 4;

    float4v acc[2][4];
#pragma unroll
    for (int i = 0; i < 2; ++i)
#pragma unroll
        for (int j = 0; j < 4; ++j)
#pragma unroll
            for (int r = 0; r < 4; ++r) acc[i][j][r] = 0.f;

    int srow = tid >> 2;
    int scol = (tid & 3) * 8;

    for (int k0 = 0; k0 < DI_; k0 += 32) {
#pragma unroll
        for (int p = 0; p < 2; ++p) {
            int row = srow + p * 64;
            int gm = m0 + row; if (gm >= M_) gm = M_ - 1;
            *(uint4*)&As[row * 40 + scol] =
                *(const uint4*)(A + (size_t)gm * DI_ + k0 + scol);
        }
        *(uint4*)&Ws[srow * 40 + scol] =
            *(const uint4*)(W + (size_t)srow * DI_ + k0 + scol);
        __syncthreads();
        short8 af[2], bfr[4];
#pragma unroll
        for (int i = 0; i < 2; ++i)
            af[i] = *(const short8*)&As[(wm + i * 16 + ml) * 40 + quad * 8];
#pragma unroll
        for (int j = 0; j < 4; ++j)
            bfr[j] = *(const short8*)&Ws[(j * 16 + ml) * 40 + quad * 8];
#pragma unroll
        for (int i = 0; i < 2; ++i)
#pragma unroll
            for (int j = 0; j < 4; ++j)
                acc[i][j] = __builtin_amdgcn_mfma_f32_16x16x32_bf16(
                    af[i], bfr[j], acc[i][j], 0, 0, 0);
        __syncthreads();
    }

#pragma unroll
    for (int i = 0; i < 2; ++i)
#pragma unroll
        for (int j = 0; j < 4; ++j)
#pragma unroll
            for (int r = 0; r < 4; ++r) {
                int m = m0 + wm + i * 16 + quad * 4 + r;
                int n = j * 16 + ml;
                if (m < M_ && n < 56)
                    C[(size_t)m * 56 + n] = acc[i][j][r];
            }
}

// causal depthwise conv (K=4) + bias + silu, both dirs (blockIdx.y = dir)
__global__ __launch_bounds__(256) void conv_silu_kernel(
    const u16* __restrict__ xz, const float* __restrict__ cw_l,
    const float* __restrict__ cb_l, u16* __restrict__ xc2)
{
    int dir = blockIdx.y;
    const float* cw = cw_l + (size_t)dir * DI_ * 4;
    const float* cb = cb_l + (size_t)dir * DI_;
    u16* xc = xc2 + (size_t)dir * M_ * DI_;
    int i = blockIdx.x * 256 + threadIdx.x;
    int d = i % DI_;
    int s = (i / DI_) % L_;
    int b = i / (DI_ * L_);
    float acc = cb[d];
#pragma unroll
    for (int k = 0; k < 4; ++k) {
        int t = s - 3 + k;
        if (t >= 0) {
            int lorig = dir ? (L_ - 1 - t) : t;
            acc += cw[d * 4 + k] * bf2f(xz[((size_t)b * L_ + lorig) * 1536 + d]);
        }
    }
    xc[i] = f2bf(silu_f(acc));
}

// ================= segmented selective scan (both dirs per launch) ==========
__device__ __forceinline__ float dt_delta(
    const float* __restrict__ row, const float* W, float bias)
{
    float s = bias;
    const float4* pd = reinterpret_cast<const float4*>(row);
#pragma unroll
    for (int r = 0; r < 6; ++r) {
        float4 d4 = pd[r];
        s += W[4 * r + 0] * d4.x + W[4 * r + 1] * d4.y
           + W[4 * r + 2] * d4.z + W[4 * r + 3] * d4.w;
    }
    return (s > 20.f) ? s : __logf(1.f + __expf(s));
}

// grid (1536, 2): blockIdx.y = dir
__global__ __launch_bounds__(64) void scan_part1_kernel(
    const u16* __restrict__ xc2, const float* __restrict__ dbl2,
    const float* __restrict__ dtW_l, const float* __restrict__ dtb_l,
    const float* __restrict__ Alog_l,
    float* __restrict__ P_buf, float* __restrict__ q_buf)
{
    int dir = blockIdx.y;
    const u16* xc = xc2 + (size_t)dir * M_ * DI_;
    const float* dbl = dbl2 + (size_t)dir * M_ * 56;
    const float* dtW = dtW_l + (size_t)dir * DI_ * DTR_;
    const float* dtb = dtb_l + (size_t)dir * DI_;
    const float* Alog = Alog_l + (size_t)dir * DI_ * DS_;

    int lane = threadIdx.x;
    int blk = blockIdx.x;
    int s = blk % SEG;
    int bd = blk / SEG;
    int b = bd / 12, dblk = bd % 12;
    int d = dblk * 64 + lane;
    size_t mb = (size_t)b * L_;
    int t0 = s * TL;
    int t1 = (t0 + TL < L_) ? (t0 + TL) : L_;

    float A[16];
    {
        const float4* ap = reinterpret_cast<const float4*>(Alog + (size_t)d * 16);
#pragma unroll
        for (int i = 0; i < 4; ++i) {
            float4 a4 = ap[i];
            A[4 * i + 0] = -__expf(a4.x); A[4 * i + 1] = -__expf(a4.y);
            A[4 * i + 2] = -__expf(a4.z); A[4 * i + 3] = -__expf(a4.w);
        }
    }
    float W[24];
    {
        const float4* wp = reinterpret_cast<const float4*>(dtW + (size_t)d * 24);
#pragma unroll
        for (int i = 0; i < 6; ++i) {
            float4 w4 = wp[i];
            W[4 * i + 0] = w4.x; W[4 * i + 1] = w4.y;
            W[4 * i + 2] = w4.z; W[4 * i + 3] = w4.w;
        }
    }
    float bias = dtb[d];
    float h[16], P[16];
#pragma unroll
    for (int i = 0; i < 16; ++i) { h[i] = 0.f; P[i] = 1.f; }

    for (int t = t0; t < t1; ++t) {
        const float* row = dbl + (mb + t) * 56;
        float dl = dt_delta(row, W, bias);
        float xv = bf2f(xc[(mb + t) * DI_ + d]);
        float dlxv = dl * xv;
        const float4* pb = reinterpret_cast<const float4*>(row + 24);
#pragma unroll
        for (int j = 0; j < 4; ++j) {
            float4 B4 = pb[j];
            float e0 = __expf(dl * A[4 * j + 0]);
            float e1 = __expf(dl * A[4 * j + 1]);
            float e2 = __expf(dl * A[4 * j + 2]);
            float e3 = __expf(dl * A[4 * j + 3]);
            h[4 * j + 0] = e0 * h[4 * j + 0] + dlxv * B4.x;
            h[4 * j + 1] = e1 * h[4 * j + 1] + dlxv * B4.y;
            h[4 * j + 2] = e2 * h[4 * j + 2] + dlxv * B4.z;
            h[4 * j + 3] = e3 * h[4 * j + 3] + dlxv * B4.w;
            P[4 * j + 0] *= e0; P[4 * j + 1] *= e1;
            P[4 * j + 2] *= e2; P[4 * j + 3] *= e3;
        }
    }
    size_t base = ((size_t)dir * SCAN_GRID + blk) * 16 * 64 + lane;
#pragma unroll
    for (int n = 0; n < 16; ++n) {
        P_buf[base + (size_t)n * 64] = P[n];
        q_buf[base + (size_t)n * 64] = h[n];
    }
}

// Phase 2: grid (192, 4, 2): y = state quad, z = dir.
__global__ __launch_bounds__(64) void scan_combine_kernel(
    const float* __restrict__ P_buf, float* __restrict__ q_buf)
{
    int lane = threadIdx.x;
    int bd = blockIdx.x;
    int nq = blockIdx.y;
    size_t dbase = (size_t)blockIdx.z * SCAN_GRID * 16 * 64;
    float h[4] = {0.f, 0.f, 0.f, 0.f};
    for (int s = 0; s < SEG; ++s) {
        size_t base = dbase + ((size_t)(bd * SEG + s) * 16 + nq * 4) * 64 + lane;
#pragma unroll
        for (int n = 0; n < 4; ++n) {
            size_t idx = base + (size_t)n * 64;
            float Pv = P_buf[idx];
            float qv = q_buf[idx];
            q_buf[idx] = h[n];
            h[n] = Pv * h[n] + qv;
        }
    }
}

// Phase 3: rescan from true hin; dir0 -> y0, dir1 -> y1 (no accumulation).
__global__ __launch_bounds__(64) void scan_part3_kernel(
    const u16* __restrict__ xc2, const float* __restrict__ dbl2,
    const u16* __restrict__ xz, const float* __restrict__ dtW_l,
    const float* __restrict__ dtb_l, const float* __restrict__ Alog_l,
    const float* __restrict__ Dp_l, const float* __restrict__ q_buf,
    u16* __restrict__ y0, u16* __restrict__ y1)
{
    int dir = blockIdx.y;
    const u16* xc = xc2 + (size_t)dir * M_ * DI_;
    const float* dbl = dbl2 + (size_t)dir * M_ * 56;
    const float* dtW = dtW_l + (size_t)dir * DI_ * DTR_;
    const float* dtb = dtb_l + (size_t)dir * DI_;
    const float* Alog = Alog_l + (size_t)dir * DI_ * DS_;
    const float* Dp = Dp_l + (size_t)dir * DI_;
    u16* yb = dir ? y1 : y0;

    int lane = threadIdx.x;
    int blk = blockIdx.x;
    int s = blk % SEG;
    int bd = blk / SEG;
    int b = bd / 12, dblk = bd % 12;
    int d = dblk * 64 + lane;
    size_t mb = (size_t)b * L_;
    int t0 = s * TL;
    int t1 = (t0 + TL < L_) ? (t0 + TL) : L_;

    float A[16];
    {
        const float4* ap = reinterpret_cast<const float4*>(Alog + (size_t)d * 16);
#pragma unroll
        for (int i = 0; i < 4; ++i) {
            float4 a4 = ap[i];
            A[4 * i + 0] = -__expf(a4.x); A[4 * i + 1] = -__expf(a4.y);
            A[4 * i + 2] = -__expf(a4.z); A[4 * i + 3] = -__expf(a4.w);
        }
    }
    float W[24];
    {
        const float4* wp = reinterpret_cast<const float4*>(dtW + (size_t)d * 24);
#pragma unroll
        for (int i = 0; i < 6; ++i) {
            float4 w4 = wp[i];
            W[4 * i + 0] = w4.x; W[4 * i + 1] = w4.y;
            W[4 * i + 2] = w4.z; W[4 * i + 3] = w4.w;
        }
    }
    float bias = dtb[d];
    float Dval = Dp[d];
    float h[16];
    {
        size_t base = ((size_t)dir * SCAN_GRID + blk) * 16 * 64 + lane;
#pragma unroll
        for (int n = 0; n < 16; ++n) h[n] = q_buf[base + (size_t)n * 64];
    }

    for (int t = t0; t < t1; ++t) {
        const float* row = dbl + (mb + t) * 56;
        float dl = dt_delta(row, W, bias);
        float xv = bf2f(xc[(mb + t) * DI_ + d]);
        float dlxv = dl * xv;
        const float4* pb = reinterpret_cast<const float4*>(row + 24);
        const float4* pc = reinterpret_cast<const float4*>(row + 40);
        float a0 = 0.f, a1 = 0.f, a2 = 0.f, a3 = 0.f;
#pragma unroll
        for (int j = 0; j < 4; ++j) {
            float4 B4 = pb[j], C4 = pc[j];
            float e0 = __expf(dl * A[4 * j + 0]);
            float e1 = __expf(dl * A[4 * j + 1]);
            float e2 = __expf(dl * A[4 * j + 2]);
            float e3 = __expf(dl * A[4 * j + 3]);
            h[4 * j + 0] = e0 * h[4 * j + 0] + dlxv * B4.x;
            h[4 * j + 1] = e1 * h[4 * j + 1] + dlxv * B4.y;
            h[4 * j + 2] = e2 * h[4 * j + 2] + dlxv * B4.z;
            h[4 * j + 3] = e3 * h[4 * j + 3] + dlxv * B4.w;
            a0 += h[4 * j + 0] * C4.x;
            a1 += h[4 * j + 1] * C4.y;
            a2 += h[4 * j + 2] * C4.z;
            a3 += h[4 * j + 3] * C4.w;
        }
        float y = (a0 + a1) + (a2 + a3) + xv * Dval;
        int lorig = dir ? (L_ - 1 - t) : t;
        y *= silu_f(bf2f(xz[(mb + lorig) * 1536 + 768 + d]));
        yb[(mb + lorig) * DI_ + d] = f2bf(y);
    }
}

// final: residual+hidden, rmsnorm, permute+slice, store bf16 or f32 per flag
__global__ __launch_bounds__(128) void final_kernel(
    const float* __restrict__ hidden, const float* __restrict__ resid,
    const float* __restrict__ w, void* __restrict__ out,
    const int* __restrict__ bad)
{
    int blk = blockIdx.x;
    int b = blk / 446, tok = blk % 446;
    int lorig; size_t dst;
    if (tok == 0)      { lorig = 247; dst = (size_t)b * D_; }
    else if (tok <= 14){ int j = tok - 1; lorig = 49 + j; dst = 6144 + ((size_t)b * 14 + j) * D_; }
    else               { int v = tok - 15; lorig = (v < 184) ? (63 + v) : (64 + v);
                         dst = 92160 + ((size_t)b * 431 + v) * D_; }
    size_t base = ((size_t)b * L_ + lorig) * D_;
    int tid = threadIdx.x;
    float v3[3]; float ss = 0.f;
#pragma unroll
    for (int i = 0; i < 3; ++i) {
        int c = tid + i * 128;
        float r = hidden[base + c] + resid[base + c];
        v3[i] = r; ss += r * r;
    }
    ss += __shfl_xor(ss, 32); ss += __shfl_xor(ss, 16); ss += __shfl_xor(ss, 8);
    ss += __shfl_xor(ss, 4);  ss += __shfl_xor(ss, 2);  ss += __shfl_xor(ss, 1);
    __shared__ float sred[2];
    if ((tid & 63) == 0) sred[tid >> 6] = ss;
    __syncthreads();
    float scale = rsqrtf((sred[0] + sred[1]) * (1.f / D_) + 1e-5f);
    int isbf = (*bad == 0);
#pragma unroll
    for (int i = 0; i < 3; ++i) {
        int c = tid + i * 128;
        float val = v3[i] * scale * w[c];
        if (isbf) ((u16*)out)[dst + c] = f2bf(val);
        else      ((float*)out)[dst + c] = val;
    }
}

extern "C" void kernel_launch(void* const* d_in, const int* in_sizes, int n_in,
                              void* d_out, int out_size, void* d_ws, size_t ws_size,
                              hipStream_t stream) {
    // ---- workspace layout (~123 MB)
    char* wsb = (char*)d_ws;
    int* bad = (int*)wsb;  wsb += 16;

    // canon (11): inW(bf16), cW, cB, xpW(bf16), dtW, dtB, Alog, Dsk, outW(bf16), nw, fnw
    const int cn[11] = {2359296, 24576, 6144, 344064, 147456, 6144, 98304,
                        6144, 1179648, 1536, 384};
    const int raw_idx[11] = {4, 5, 6, 7, 8, 9, 10, 11, 12, 13, 14};
    const int tobf[11]    = {1, 0, 0, 1, 0, 0, 0, 0, 1, 0, 0};
    void* canon[11];
    for (int i = 0; i < 11; ++i) {
        canon[i] = (void*)wsb;
        wsb += (size_t)cn[i] * (tobf[i] ? 2 : 4);
    }
    const u16*   inWb = (const u16*)canon[0];
    const float* cW   = (const float*)canon[1];
    const float* cB   = (const float*)canon[2];
    const u16*   xpWb = (const u16*)canon[3];
    const float* dtW  = (const float*)canon[4];
    const float* dtB  = (const float*)canon[5];
    const float* Alog = (const float*)canon[6];
    const float* Dsk  = (const float*)canon[7];
    const u16*   outWb= (const u16*)canon[8];
    const float* nw   = (const float*)canon[9];
    const float* fnw  = (const float*)canon[10];

    float* hidden = (float*)wsb;  wsb += (size_t)M_ * D_ * 4;
    float* resid  = (float*)wsb;  wsb += (size_t)M_ * D_ * 4;
    float* dbl2   = (float*)wsb;  wsb += (size_t)2 * M_ * 56 * 4;
    u16*   xz     = (u16*)wsb;    wsb += (size_t)M_ * 1536 * 2;
    u16*   xc2    = (u16*)wsb;    wsb += (size_t)2 * M_ * DI_ * 2;
    u16*   y0     = (u16*)wsb;    wsb += (size_t)M_ * DI_ * 2;       // hbf aliases this
    float* P_buf  = (float*)wsb;  wsb += (size_t)2 * SCAN_GRID * 16 * 64 * 4;  // y1 aliases
    float* q_buf  = (float*)wsb;  wsb += (size_t)2 * SCAN_GRID * 16 * 64 * 4;
    u16* hbf = y0;              // dead once gemm_in consumes it; part3 then writes y0
    u16* y1  = (u16*)P_buf;     // P dead after combine; part3 writes y1

    hipMemsetAsync(bad, 0, 4, stream);
    detect_kernel<<<384, 256, 0, stream>>>((const u16*)d_in[10], bad);
    {
        CvtArgs ca;
        int maxn = 0;
        for (int i = 0; i < 11; ++i) {
            ca.src[i] = d_in[raw_idx[i]]; ca.dst[i] = canon[i];
            ca.n[i] = cn[i]; ca.tobf[i] = tobf[i];
            if (cn[i] > maxn) maxn = cn[i];
        }
        cvt_all_kernel<<<dim3((maxn + 255) / 256, 11), 256, 0, stream>>>(ca, bad);
    }

    build_hidden_kernel<<<(M_ * D_) / 256, 256, 0, stream>>>(
        d_in[0], d_in[2], d_in[3], hidden, bad);

    const int gmb = (M_ + 127) / 128;      // 62
    for (int l = 0; l < 4; ++l) {
        resnorm_kernel<<<M_, 128, 0, stream>>>(hidden, resid, nw + (size_t)l * D_, hbf, l == 0);
        gemm_mfma_bt<0, 0><<<dim3(gmb, 1536 / 128), 256, 0, stream>>>(
            hbf, nullptr, inWb + (size_t)l * 1536 * D_, xz, M_, 1536, D_, 1536, 1.f);
        conv_silu_kernel<<<dim3((M_ * DI_) / 256, 2), 256, 0, stream>>>(
            xz, cW + (size_t)l * 2 * DI_ * 4, cB + (size_t)l * 2 * DI_, xc2);
        xproj_gemm_kernel<<<dim3(gmb, 2), 256, 0, stream>>>(
            xc2, xpWb + (size_t)l * 2 * 56 * DI_, dbl2);
        scan_part1_kernel<<<dim3(SCAN_GRID, 2), 64, 0, stream>>>(
            xc2, dbl2, dtW + (size_t)l * 2 * DI_ * DTR_, dtB + (size_t)l * 2 * DI_,
            Alog + (size_t)l * 2 * DI_ * DS_, P_buf, q_buf);
        scan_combine_kernel<<<dim3(NBD, 4, 2), 64, 0, stream>>>(P_buf, q_buf);
        scan_part3_kernel<<<dim3(SCAN_GRID, 2), 64, 0, stream>>>(
            xc2, dbl2, xz, dtW + (size_t)l * 2 * DI_ * DTR_, dtB + (size_t)l * 2 * DI_,
            Alog + (size_t)l * 2 * DI_ * DS_, Dsk + (size_t)l * 2 * DI_, q_buf, y0, y1);
        gemm_mfma_bt<1, 1><<<dim3(gmb, 384 / 128), 256, 0, stream>>>(
            y0, y1, outWb + (size_t)l * D_ * DI_, hidden, M_, 384, DI_, 384, 0.5f);
    }

    final_kernel<<<B_ * 446, 128, 0, stream>>>(hidden, resid, fnw, d_out, bad);
}

// Round 10
// 1322.585 us; speedup vs baseline: 4.4208x; 1.0695x over previous
//
#include <hip/hip_runtime.h>

typedef unsigned short u16;
typedef __attribute__((ext_vector_type(8))) short short8;
typedef __attribute__((ext_vector_type(4))) float float4v;

#define B_   16
#define L_   495
#define D_   384
#define DI_  768
#define DS_  16
#define DTR_ 24
#define SEG  16
#define TL   31   // ceil(495/16)
#define M_   (B_ * L_)
#define NBD  (B_ * 12)            // 192 (b,d-block) pairs
#define SGRID (NBD * SEG)         // 3072 flat scan units per dir
#define LOG2E 1.44269504f

__device__ __forceinline__ float bf2f(u16 u) {
    return __uint_as_float(((unsigned)u) << 16);
}
__device__ __forceinline__ u16 f2bf(float f) {
    unsigned u = __float_as_uint(f);
    unsigned r = 0x7fffu + ((u >> 16) & 1u);
    return (u16)((u + r) >> 16);
}
__device__ __forceinline__ float silu_f(float x) {
    return x / (1.f + __expf(-x));
}

// ---- dtype detector (parallel): A_log in [0,2.78] as bf16 => bad==0 -> bf16.
__global__ __launch_bounds__(256) void detect_kernel(
    const u16* __restrict__ alog_raw, int* __restrict__ bad)
{
    int i = blockIdx.x * 256 + threadIdx.x;   // grid 384 -> 98304
    float v = bf2f(alog_raw[i]);
    int b = !(v >= -1e-3f && v <= 2.8f);
    unsigned long long m = __ballot(b);
    if ((threadIdx.x & 63) == 0 && m) atomicAdd(bad, (int)__popcll(m));
}

// ---- batched convert (blockIdx.y = tensor). tobf: emit bf16 instead of f32.
struct CvtArgs {
    const void* src[11];
    void* dst[11];
    int n[11];
    int tobf[11];
};
__global__ __launch_bounds__(256) void cvt_all_kernel(CvtArgs a, const int* __restrict__ bad)
{
    int t = blockIdx.y;
    int i = blockIdx.x * 256 + threadIdx.x;
    if (i >= a.n[t]) return;
    int isbf = (*bad == 0);
    if (a.tobf[t]) {
        u16 v = isbf ? ((const u16*)a.src[t])[i] : f2bf(((const float*)a.src[t])[i]);
        ((u16*)a.dst[t])[i] = v;
    } else {
        float v = isbf ? bf2f(((const u16*)a.src[t])[i]) : ((const float*)a.src[t])[i];
        ((float*)a.dst[t])[i] = v;
    }
}

// hidden[b,l,c] = concat(cjv[:247], cls, cjv[247:]) + pos_embed  (raw inputs)
__global__ __launch_bounds__(256) void build_hidden_kernel(
    const void* __restrict__ cjv, const void* __restrict__ cls,
    const void* __restrict__ pos, float* __restrict__ hidden,
    const int* __restrict__ bad)
{
    int isbf = (*bad == 0);
    int i = blockIdx.x * 256 + threadIdx.x;
    int c = i % D_;
    int l = (i / D_) % L_;
    int b = i / (D_ * L_);
    size_t si;
    const void* sp;
    if (l < 247)       { sp = cjv; si = ((size_t)b * 494 + l) * D_ + c; }
    else if (l == 247) { sp = cls; si = c; }
    else               { sp = cjv; si = ((size_t)b * 494 + (l - 1)) * D_ + c; }
    float v = isbf ? bf2f(((const u16*)sp)[si]) : ((const float*)sp)[si];
    size_t pi = (size_t)l * D_ + c;
    float p = isbf ? bf2f(((const u16*)pos)[pi]) : ((const float*)pos)[pi];
    hidden[i] = v + p;
}

// resid = hidden (+ resid); hbf <- bf16(rmsnorm(resid)*w)
__global__ __launch_bounds__(128) void resnorm_kernel(
    const float* __restrict__ hidden, float* __restrict__ resid,
    const float* __restrict__ w, u16* __restrict__ hbf, int first)
{
    int m = blockIdx.x, tid = threadIdx.x;
    size_t base = (size_t)m * D_;
    float v[3]; float ss = 0.f;
#pragma unroll
    for (int i = 0; i < 3; ++i) {
        int c = tid + i * 128;
        float r = hidden[base + c];
        if (!first) r += resid[base + c];
        resid[base + c] = r;
        v[i] = r; ss += r * r;
    }
    ss += __shfl_xor(ss, 32); ss += __shfl_xor(ss, 16); ss += __shfl_xor(ss, 8);
    ss += __shfl_xor(ss, 4);  ss += __shfl_xor(ss, 2);  ss += __shfl_xor(ss, 1);
    __shared__ float sred[2];
    if ((tid & 63) == 0) sred[tid >> 6] = ss;
    __syncthreads();
    float scale = rsqrtf((sred[0] + sred[1]) * (1.f / D_) + 1e-5f);
#pragma unroll
    for (int i = 0; i < 3; ++i) {
        int c = tid + i * 128;
        hbf[base + c] = f2bf(v[i] * scale * w[c]);
    }
}

// ===== MFMA GEMM: C(M,N) = alpha * (A [+ A2])(M,K)bf16 @ W(N,K)bf16^T =====
template<int CF32, int SUM2>
__global__ __launch_bounds__(256) void gemm_mfma_bt(
    const u16* __restrict__ A, const u16* __restrict__ A2,
    const u16* __restrict__ W, void* __restrict__ Cv,
    int M, int N, int K, int ldc, float alpha)
{
    __shared__ __align__(16) u16 As[128 * 40];
    __shared__ __align__(16) u16 Ws[128 * 40];
    int tid = threadIdx.x;
    int wave = tid >> 6, lane = tid & 63;
    int m0 = blockIdx.x * 128, n0 = blockIdx.y * 128;
    int wm = (wave >> 1) * 64, wn = (wave & 1) * 64;
    int ml = lane & 15, quad = lane >> 4;

    float4v acc[4][4];
#pragma unroll
    for (int i = 0; i < 4; ++i)
#pragma unroll
        for (int j = 0; j < 4; ++j)
#pragma unroll
            for (int r = 0; r < 4; ++r) acc[i][j][r] = 0.f;

    int srow = tid >> 2;
    int scol = (tid & 3) * 8;

    for (int k0 = 0; k0 < K; k0 += 32) {
#pragma unroll
        for (int p = 0; p < 2; ++p) {
            int row = srow + p * 64;
            int gm = m0 + row; if (gm >= M) gm = M - 1;
            if (SUM2) {
                short8 a0 = *(const short8*)(A  + (size_t)gm * K + k0 + scol);
                short8 a1 = *(const short8*)(A2 + (size_t)gm * K + k0 + scol);
                u16 tmp[8];
#pragma unroll
                for (int r = 0; r < 8; ++r)
                    tmp[r] = f2bf(bf2f((u16)a0[r]) + bf2f((u16)a1[r]));
                *(uint4*)&As[row * 40 + scol] = *(const uint4*)tmp;
            } else {
                *(uint4*)&As[row * 40 + scol] =
                    *(const uint4*)(A + (size_t)gm * K + k0 + scol);
            }
            int gn = n0 + row;
            *(uint4*)&Ws[row * 40 + scol] =
                *(const uint4*)(W + (size_t)gn * K + k0 + scol);
        }
        __syncthreads();
        short8 af[4], bfr[4];
#pragma unroll
        for (int i = 0; i < 4; ++i) {
            af[i]  = *(const short8*)&As[(wm + i * 16 + ml) * 40 + quad * 8];
            bfr[i] = *(const short8*)&Ws[(wn + i * 16 + ml) * 40 + quad * 8];
        }
#pragma unroll
        for (int i = 0; i < 4; ++i)
#pragma unroll
            for (int j = 0; j < 4; ++j)
                acc[i][j] = __builtin_amdgcn_mfma_f32_16x16x32_bf16(
                    af[i], bfr[j], acc[i][j], 0, 0, 0);
        __syncthreads();
    }

#pragma unroll
    for (int i = 0; i < 4; ++i)
#pragma unroll
        for (int j = 0; j < 4; ++j)
#pragma unroll
            for (int r = 0; r < 4; ++r) {
                int m = m0 + wm + i * 16 + quad * 4 + r;
                if (m >= M) continue;
                int n = n0 + wn + j * 16 + ml;
                float val = alpha * acc[i][j][r];
                if (CF32) ((float*)Cv)[(size_t)m * ldc + n] = val;
                else      ((u16*)Cv)[(size_t)m * ldc + n] = f2bf(val);
            }
}

// ===== xproj MFMA GEMM: dbl2[dir](m,56) = xc2[dir](M,768) @ xpWb[dir](56,768)^T
__global__ __launch_bounds__(256) void xproj_gemm_kernel(
    const u16* __restrict__ xc2, const u16* __restrict__ xpWb_l,
    float* __restrict__ dbl2)
{
    int dir = blockIdx.y;
    const u16* A = xc2 + (size_t)dir * M_ * DI_;
    const u16* W = xpWb_l + (size_t)dir * 56 * DI_;
    float* C = dbl2 + (size_t)dir * M_ * 56;

    __shared__ __align__(16) u16 As[128 * 40];
    __shared__ __align__(16) u16 Ws[64 * 40];
    int tid = threadIdx.x;
    int wave = tid >> 6, lane = tid & 63;
    int m0 = blockIdx.x * 128;
    int wm = wave * 32;
    int ml = lane & 15, quad = lane >> 4;

    float4v acc[2][4];
#pragma unroll
    for (int i = 0; i < 2; ++i)
#pragma unroll
        for (int j = 0; j < 4; ++j)
#pragma unroll
            for (int r = 0; r < 4; ++r) acc[i][j][r] = 0.f;

    int srow = tid >> 2;
    int scol = (tid & 3) * 8;

    for (int k0 = 0; k0 < DI_; k0 += 32) {
#pragma unroll
        for (int p = 0; p < 2; ++p) {
            int row = srow + p * 64;
            int gm = m0 + row; if (gm >= M_) gm = M_ - 1;
            *(uint4*)&As[row * 40 + scol] =
                *(const uint4*)(A + (size_t)gm * DI_ + k0 + scol);
        }
        *(uint4*)&Ws[srow * 40 + scol] =
            *(const uint4*)(W + (size_t)srow * DI_ + k0 + scol);
        __syncthreads();
        short8 af[2], bfr[4];
#pragma unroll
        for (int i = 0; i < 2; ++i)
            af[i] = *(const short8*)&As[(wm + i * 16 + ml) * 40 + quad * 8];
#pragma unroll
        for (int j = 0; j < 4; ++j)
            bfr[j] = *(const short8*)&Ws[(j * 16 + ml) * 40 + quad * 8];
#pragma unroll
        for (int i = 0; i < 2; ++i)
#pragma unroll
            for (int j = 0; j < 4; ++j)
                acc[i][j] = __builtin_amdgcn_mfma_f32_16x16x32_bf16(
                    af[i], bfr[j], acc[i][j], 0, 0, 0);
        __syncthreads();
    }

#pragma unroll
    for (int i = 0; i < 2; ++i)
#pragma unroll
        for (int j = 0; j < 4; ++j)
#pragma unroll
            for (int r = 0; r < 4; ++r) {
                int m = m0 + wm + i * 16 + quad * 4 + r;
                int n = j * 16 + ml;
                if (m < M_ && n < 56)
                    C[(size_t)m * 56 + n] = acc[i][j][r];
            }
}

// causal depthwise conv (K=4) + bias + silu, both dirs (blockIdx.y = dir)
__global__ __launch_bounds__(256) void conv_silu_kernel(
    const u16* __restrict__ xz, const float* __restrict__ cw_l,
    const float* __restrict__ cb_l, u16* __restrict__ xc2)
{
    int dir = blockIdx.y;
    const float* cw = cw_l + (size_t)dir * DI_ * 4;
    const float* cb = cb_l + (size_t)dir * DI_;
    u16* xc = xc2 + (size_t)dir * M_ * DI_;
    int i = blockIdx.x * 256 + threadIdx.x;
    int d = i % DI_;
    int s = (i / DI_) % L_;
    int b = i / (DI_ * L_);
    float acc = cb[d];
#pragma unroll
    for (int k = 0; k < 4; ++k) {
        int t = s - 3 + k;
        if (t >= 0) {
            int lorig = dir ? (L_ - 1 - t) : t;
            acc += cw[d * 4 + k] * bf2f(xz[((size_t)b * L_ + lorig) * 1536 + d]);
        }
    }
    xc[i] = f2bf(silu_f(acc));
}

// ================= segmented selective scan (both dirs per launch) ==========
__device__ __forceinline__ float dt_delta(
    const float* __restrict__ row, const float* W, float bias)
{
    float s = bias;
    const float4* pd = reinterpret_cast<const float4*>(row);
#pragma unroll
    for (int r = 0; r < 6; ++r) {
        float4 d4 = pd[r];
        s += W[4 * r + 0] * d4.x + W[4 * r + 1] * d4.y
           + W[4 * r + 2] * d4.z + W[4 * r + 3] * d4.w;
    }
    return (s > 20.f) ? s : __logf(1.f + __expf(s));
}

// grid (B_*3*SEG, 2) blocks of 256: 4 waves = 4 d-blocks. A pre-scaled by log2e.
__global__ __launch_bounds__(256) void scan_part1_kernel(
    const u16* __restrict__ xc2, const float* __restrict__ dbl2,
    const float* __restrict__ dtW_l, const float* __restrict__ dtb_l,
    const float* __restrict__ Alog_l,
    u16* __restrict__ P_buf, u16* __restrict__ q_buf)
{
    int dir = blockIdx.y;
    const u16* xc = xc2 + (size_t)dir * M_ * DI_;
    const float* dbl = dbl2 + (size_t)dir * M_ * 56;
    const float* dtW = dtW_l + (size_t)dir * DI_ * DTR_;
    const float* dtb = dtb_l + (size_t)dir * DI_;
    const float* Alog = Alog_l + (size_t)dir * DI_ * DS_;

    int tid = threadIdx.x;
    int wave = tid >> 6, lane = tid & 63;
    int s = blockIdx.x % SEG;
    int bq = blockIdx.x / SEG;
    int b = bq / 3, dq = bq % 3;
    int dblk = dq * 4 + wave;
    int d = dblk * 64 + lane;
    size_t mb = (size_t)b * L_;
    int t0 = s * TL;
    int t1 = (t0 + TL < L_) ? (t0 + TL) : L_;

    float A[16];
    {
        const float4* ap = reinterpret_cast<const float4*>(Alog + (size_t)d * 16);
#pragma unroll
        for (int i = 0; i < 4; ++i) {
            float4 a4 = ap[i];
            A[4 * i + 0] = -LOG2E * __expf(a4.x); A[4 * i + 1] = -LOG2E * __expf(a4.y);
            A[4 * i + 2] = -LOG2E * __expf(a4.z); A[4 * i + 3] = -LOG2E * __expf(a4.w);
        }
    }
    float W[24];
    {
        const float4* wp = reinterpret_cast<const float4*>(dtW + (size_t)d * 24);
#pragma unroll
        for (int i = 0; i < 6; ++i) {
            float4 w4 = wp[i];
            W[4 * i + 0] = w4.x; W[4 * i + 1] = w4.y;
            W[4 * i + 2] = w4.z; W[4 * i + 3] = w4.w;
        }
    }
    float bias = dtb[d];
    float h[16], P[16];
#pragma unroll
    for (int i = 0; i < 16; ++i) { h[i] = 0.f; P[i] = 1.f; }

    for (int t = t0; t < t1; ++t) {
        const float* row = dbl + (mb + t) * 56;
        float dl = dt_delta(row, W, bias);
        float xv = bf2f(xc[(mb + t) * DI_ + d]);
        float dlxv = dl * xv;
        const float4* pb = reinterpret_cast<const float4*>(row + 24);
#pragma unroll
        for (int j = 0; j < 4; ++j) {
            float4 B4 = pb[j];
            float e0 = __builtin_amdgcn_exp2f(dl * A[4 * j + 0]);
            float e1 = __builtin_amdgcn_exp2f(dl * A[4 * j + 1]);
            float e2 = __builtin_amdgcn_exp2f(dl * A[4 * j + 2]);
            float e3 = __builtin_amdgcn_exp2f(dl * A[4 * j + 3]);
            h[4 * j + 0] = e0 * h[4 * j + 0] + dlxv * B4.x;
            h[4 * j + 1] = e1 * h[4 * j + 1] + dlxv * B4.y;
            h[4 * j + 2] = e2 * h[4 * j + 2] + dlxv * B4.z;
            h[4 * j + 3] = e3 * h[4 * j + 3] + dlxv * B4.w;
            P[4 * j + 0] *= e0; P[4 * j + 1] *= e1;
            P[4 * j + 2] *= e2; P[4 * j + 3] *= e3;
        }
    }
    int bd = b * 12 + dblk;
    size_t base = ((size_t)dir * SGRID + (size_t)bd * SEG + s) * 16 * 64 + lane;
#pragma unroll
    for (int n = 0; n < 16; ++n) {
        P_buf[base + (size_t)n * 64] = f2bf(P[n]);
        q_buf[base + (size_t)n * 64] = f2bf(h[n]);
    }
}

// Phase 2: grid (192, 4, 2): y = state quad, z = dir.
__global__ __launch_bounds__(64) void scan_combine_kernel(
    const u16* __restrict__ P_buf, u16* __restrict__ q_buf)
{
    int lane = threadIdx.x;
    int bd = blockIdx.x;
    int nq = blockIdx.y;
    size_t dbase = (size_t)blockIdx.z * SGRID * 16 * 64;
    float h[4] = {0.f, 0.f, 0.f, 0.f};
    for (int s = 0; s < SEG; ++s) {
        size_t base = dbase + ((size_t)(bd * SEG + s) * 16 + nq * 4) * 64 + lane;
#pragma unroll
        for (int n = 0; n < 4; ++n) {
            size_t idx = base + (size_t)n * 64;
            float Pv = bf2f(P_buf[idx]);
            float qv = bf2f(q_buf[idx]);
            q_buf[idx] = f2bf(h[n]);
            h[n] = Pv * h[n] + qv;
        }
    }
}

// Phase 3: rescan from true hin; dir0 -> y0, dir1 -> y1.
__global__ __launch_bounds__(256) void scan_part3_kernel(
    const u16* __restrict__ xc2, const float* __restrict__ dbl2,
    const u16* __restrict__ xz, const float* __restrict__ dtW_l,
    const float* __restrict__ dtb_l, const float* __restrict__ Alog_l,
    const float* __restrict__ Dp_l, const u16* __restrict__ q_buf,
    u16* __restrict__ y0, u16* __restrict__ y1)
{
    int dir = blockIdx.y;
    const u16* xc = xc2 + (size_t)dir * M_ * DI_;
    const float* dbl = dbl2 + (size_t)dir * M_ * 56;
    const float* dtW = dtW_l + (size_t)dir * DI_ * DTR_;
    const float* dtb = dtb_l + (size_t)dir * DI_;
    const float* Alog = Alog_l + (size_t)dir * DI_ * DS_;
    const float* Dp = Dp_l + (size_t)dir * DI_;
    u16* yb = dir ? y1 : y0;

    int tid = threadIdx.x;
    int wave = tid >> 6, lane = tid & 63;
    int s = blockIdx.x % SEG;
    int bq = blockIdx.x / SEG;
    int b = bq / 3, dq = bq % 3;
    int dblk = dq * 4 + wave;
    int d = dblk * 64 + lane;
    size_t mb = (size_t)b * L_;
    int t0 = s * TL;
    int t1 = (t0 + TL < L_) ? (t0 + TL) : L_;

    float A[16];
    {
        const float4* ap = reinterpret_cast<const float4*>(Alog + (size_t)d * 16);
#pragma unroll
        for (int i = 0; i < 4; ++i) {
            float4 a4 = ap[i];
            A[4 * i + 0] = -LOG2E * __expf(a4.x); A[4 * i + 1] = -LOG2E * __expf(a4.y);
            A[4 * i + 2] = -LOG2E * __expf(a4.z); A[4 * i + 3] = -LOG2E * __expf(a4.w);
        }
    }
    float W[24];
    {
        const float4* wp = reinterpret_cast<const float4*>(dtW + (size_t)d * 24);
#pragma unroll
        for (int i = 0; i < 6; ++i) {
            float4 w4 = wp[i];
            W[4 * i + 0] = w4.x; W[4 * i + 1] = w4.y;
            W[4 * i + 2] = w4.z; W[4 * i + 3] = w4.w;
        }
    }
    float bias = dtb[d];
    float Dval = Dp[d];
    int bd = b * 12 + dblk;
    float h[16];
    {
        size_t base = ((size_t)dir * SGRID + (size_t)bd * SEG + s) * 16 * 64 + lane;
#pragma unroll
        for (int n = 0; n < 16; ++n) h[n] = bf2f(q_buf[base + (size_t)n * 64]);
    }

    for (int t = t0; t < t1; ++t) {
        const float* row = dbl + (mb + t) * 56;
        float dl = dt_delta(row, W, bias);
        float xv = bf2f(xc[(mb + t) * DI_ + d]);
        float dlxv = dl * xv;
        const float4* pb = reinterpret_cast<const float4*>(row + 24);
        const float4* pc = reinterpret_cast<const float4*>(row + 40);
        float a0 = 0.f, a1 = 0.f, a2 = 0.f, a3 = 0.f;
#pragma unroll
        for (int j = 0; j < 4; ++j) {
            float4 B4 = pb[j], C4 = pc[j];
            float e0 = __builtin_amdgcn_exp2f(dl * A[4 * j + 0]);
            float e1 = __builtin_amdgcn_exp2f(dl * A[4 * j + 1]);
            float e2 = __builtin_amdgcn_exp2f(dl * A[4 * j + 2]);
            float e3 = __builtin_amdgcn_exp2f(dl * A[4 * j + 3]);
            h[4 * j + 0] = e0 * h[4 * j + 0] + dlxv * B4.x;
            h[4 * j + 1] = e1 * h[4 * j + 1] + dlxv * B4.y;
            h[4 * j + 2] = e2 * h[4 * j + 2] + dlxv * B4.z;
            h[4 * j + 3] = e3 * h[4 * j + 3] + dlxv * B4.w;
            a0 += h[4 * j + 0] * C4.x;
            a1 += h[4 * j + 1] * C4.y;
            a2 += h[4 * j + 2] * C4.z;
            a3 += h[4 * j + 3] * C4.w;
        }
        float y = (a0 + a1) + (a2 + a3) + xv * Dval;
        int lorig = dir ? (L_ - 1 - t) : t;
        y *= silu_f(bf2f(xz[(mb + lorig) * 1536 + 768 + d]));
        yb[(mb + lorig) * DI_ + d] = f2bf(y);
    }
}

// final: residual+hidden, rmsnorm, permute+slice, store bf16 or f32 per flag
__global__ __launch_bounds__(128) void final_kernel(
    const float* __restrict__ hidden, const float* __restrict__ resid,
    const float* __restrict__ w, void* __restrict__ out,
    const int* __restrict__ bad)
{
    int blk = blockIdx.x;
    int b = blk / 446, tok = blk % 446;
    int lorig; size_t dst;
    if (tok == 0)      { lorig = 247; dst = (size_t)b * D_; }
    else if (tok <= 14){ int j = tok - 1; lorig = 49 + j; dst = 6144 + ((size_t)b * 14 + j) * D_; }
    else               { int v = tok - 15; lorig = (v < 184) ? (63 + v) : (64 + v);
                         dst = 92160 + ((size_t)b * 431 + v) * D_; }
    size_t base = ((size_t)b * L_ + lorig) * D_;
    int tid = threadIdx.x;
    float v3[3]; float ss = 0.f;
#pragma unroll
    for (int i = 0; i < 3; ++i) {
        int c = tid + i * 128;
        float r = hidden[base + c] + resid[base + c];
        v3[i] = r; ss += r * r;
    }
    ss += __shfl_xor(ss, 32); ss += __shfl_xor(ss, 16); ss += __shfl_xor(ss, 8);
    ss += __shfl_xor(ss, 4);  ss += __shfl_xor(ss, 2);  ss += __shfl_xor(ss, 1);
    __shared__ float sred[2];
    if ((tid & 63) == 0) sred[tid >> 6] = ss;
    __syncthreads();
    float scale = rsqrtf((sred[0] + sred[1]) * (1.f / D_) + 1e-5f);
    int isbf = (*bad == 0);
#pragma unroll
    for (int i = 0; i < 3; ++i) {
        int c = tid + i * 128;
        float val = v3[i] * scale * w[c];
        if (isbf) ((u16*)out)[dst + c] = f2bf(val);
        else      ((float*)out)[dst + c] = val;
    }
}

extern "C" void kernel_launch(void* const* d_in, const int* in_sizes, int n_in,
                              void* d_out, int out_size, void* d_ws, size_t ws_size,
                              hipStream_t stream) {
    // ---- workspace layout (~123 MB)
    char* wsb = (char*)d_ws;
    int* bad = (int*)wsb;  wsb += 16;

    // canon (11): inW(bf16), cW, cB, xpW(bf16), dtW, dtB, Alog, Dsk, outW(bf16), nw, fnw
    const int cn[11] = {2359296, 24576, 6144, 344064, 147456, 6144, 98304,
                        6144, 1179648, 1536, 384};
    const int raw_idx[11] = {4, 5, 6, 7, 8, 9, 10, 11, 12, 13, 14};
    const int tobf[11]    = {1, 0, 0, 1, 0, 0, 0, 0, 1, 0, 0};
    void* canon[11];
    for (int i = 0; i < 11; ++i) {
        canon[i] = (void*)wsb;
        wsb += (size_t)cn[i] * (tobf[i] ? 2 : 4);
    }
    const u16*   inWb = (const u16*)canon[0];
    const float* cW   = (const float*)canon[1];
    const float* cB   = (const float*)canon[2];
    const u16*   xpWb = (const u16*)canon[3];
    const float* dtW  = (const float*)canon[4];
    const float* dtB  = (const float*)canon[5];
    const float* Alog = (const float*)canon[6];
    const float* Dsk  = (const float*)canon[7];
    const u16*   outWb= (const u16*)canon[8];
    const float* nw   = (const float*)canon[9];
    const float* fnw  = (const float*)canon[10];

    float* hidden = (float*)wsb;  wsb += (size_t)M_ * D_ * 4;
    float* resid  = (float*)wsb;  wsb += (size_t)M_ * D_ * 4;
    float* dbl2   = (float*)wsb;  wsb += (size_t)2 * M_ * 56 * 4;
    u16*   xz     = (u16*)wsb;    wsb += (size_t)M_ * 1536 * 2;
    u16*   xc2    = (u16*)wsb;    wsb += (size_t)2 * M_ * DI_ * 2;
    u16*   y0     = (u16*)wsb;    wsb += (size_t)M_ * DI_ * 2;           // hbf aliases
    u16*   P_buf  = (u16*)wsb;    wsb += (size_t)2 * SGRID * 16 * 64 * 2; // y1 aliases
    u16*   q_buf  = (u16*)wsb;    wsb += (size_t)2 * SGRID * 16 * 64 * 2;
    u16* hbf = y0;              // dead once gemm_in consumes it; part3 then writes y0
    u16* y1  = P_buf;           // P dead after combine; part3 writes y1

    hipMemsetAsync(bad, 0, 4, stream);
    detect_kernel<<<384, 256, 0, stream>>>((const u16*)d_in[10], bad);
    {
        CvtArgs ca;
        int maxn = 0;
        for (int i = 0; i < 11; ++i) {
            ca.src[i] = d_in[raw_idx[i]]; ca.dst[i] = canon[i];
            ca.n[i] = cn[i]; ca.tobf[i] = tobf[i];
            if (cn[i] > maxn) maxn = cn[i];
        }
        cvt_all_kernel<<<dim3((maxn + 255) / 256, 11), 256, 0, stream>>>(ca, bad);
    }

    build_hidden_kernel<<<(M_ * D_) / 256, 256, 0, stream>>>(
        d_in[0], d_in[2], d_in[3], hidden, bad);

    const int gmb = (M_ + 127) / 128;      // 62
    for (int l = 0; l < 4; ++l) {
        resnorm_kernel<<<M_, 128, 0, stream>>>(hidden, resid, nw + (size_t)l * D_, hbf, l == 0);
        gemm_mfma_bt<0, 0><<<dim3(gmb, 1536 / 128), 256, 0, stream>>>(
            hbf, nullptr, inWb + (size_t)l * 1536 * D_, xz, M_, 1536, D_, 1536, 1.f);
        conv_silu_kernel<<<dim3((M_ * DI_) / 256, 2), 256, 0, stream>>>(
            xz, cW + (size_t)l * 2 * DI_ * 4, cB + (size_t)l * 2 * DI_, xc2);
        xproj_gemm_kernel<<<dim3(gmb, 2), 256, 0, stream>>>(
            xc2, xpWb + (size_t)l * 2 * 56 * DI_, dbl2);
        scan_part1_kernel<<<dim3(B_ * 3 * SEG, 2), 256, 0, stream>>>(
            xc2, dbl2, dtW + (size_t)l * 2 * DI_ * DTR_, dtB + (size_t)l * 2 * DI_,
            Alog + (size_t)l * 2 * DI_ * DS_, P_buf, q_buf);
        scan_combine_kernel<<<dim3(NBD, 4, 2), 64, 0, stream>>>(P_buf, q_buf);
        scan_part3_kernel<<<dim3(B_ * 3 * SEG, 2), 256, 0, stream>>>(
            xc2, dbl2, xz, dtW + (size_t)l * 2 * DI_ * DTR_, dtB + (size_t)l * 2 * DI_,
            Alog + (size_t)l * 2 * DI_ * DS_, Dsk + (size_t)l * 2 * DI_, q_buf, y0, y1);
        gemm_mfma_bt<1, 1><<<dim3(gmb, 384 / 128), 256, 0, stream>>>(
            y0, y1, outWb + (size_t)l * D_ * DI_, hidden, M_, 384, DI_, 384, 0.5f);
    }

    final_kernel<<<B_ * 446, 128, 0, stream>>>(hidden, resid, fnw, d_out, bad);
}

// Round 11
// 1285.624 us; speedup vs baseline: 4.5479x; 1.0287x over previous
//
#include <hip/hip_runtime.h>

typedef unsigned short u16;
typedef __attribute__((ext_vector_type(8))) short short8;
typedef __attribute__((ext_vector_type(4))) float float4v;

#define B_   16
#define L_   495
#define D_   384
#define DI_  768
#define DS_  16
#define DTR_ 24
#define SEG  16
#define TL   31   // ceil(495/16)
#define M_   (B_ * L_)
#define NBD  (B_ * 12)            // 192 (b,d-block) pairs
#define SGRID (NBD * SEG)         // 3072 flat scan units per dir
#define LOG2E 1.44269504f

__device__ __forceinline__ float bf2f(u16 u) {
    return __uint_as_float(((unsigned)u) << 16);
}
__device__ __forceinline__ u16 f2bf(float f) {
    unsigned u = __float_as_uint(f);
    unsigned r = 0x7fffu + ((u >> 16) & 1u);
    return (u16)((u + r) >> 16);
}
__device__ __forceinline__ float silu_f(float x) {
    return x / (1.f + __expf(-x));
}

// ---- dtype detector (parallel): A_log in [0,2.78] as bf16 => bad==0 -> bf16.
__global__ __launch_bounds__(256) void detect_kernel(
    const u16* __restrict__ alog_raw, int* __restrict__ bad)
{
    int i = blockIdx.x * 256 + threadIdx.x;   // grid 384 -> 98304
    float v = bf2f(alog_raw[i]);
    int b = !(v >= -1e-3f && v <= 2.8f);
    unsigned long long m = __ballot(b);
    if ((threadIdx.x & 63) == 0 && m) atomicAdd(bad, (int)__popcll(m));
}

// ---- batched convert (blockIdx.y = tensor). tobf: emit bf16 instead of f32.
struct CvtArgs {
    const void* src[11];
    void* dst[11];
    int n[11];
    int tobf[11];
};
__global__ __launch_bounds__(256) void cvt_all_kernel(CvtArgs a, const int* __restrict__ bad)
{
    int t = blockIdx.y;
    int i = blockIdx.x * 256 + threadIdx.x;
    if (i >= a.n[t]) return;
    int isbf = (*bad == 0);
    if (a.tobf[t]) {
        u16 v = isbf ? ((const u16*)a.src[t])[i] : f2bf(((const float*)a.src[t])[i]);
        ((u16*)a.dst[t])[i] = v;
    } else {
        float v = isbf ? bf2f(((const u16*)a.src[t])[i]) : ((const float*)a.src[t])[i];
        ((float*)a.dst[t])[i] = v;
    }
}

// hidden[b,l,c] = concat(cjv[:247], cls, cjv[247:]) + pos_embed  (raw inputs)
__global__ __launch_bounds__(256) void build_hidden_kernel(
    const void* __restrict__ cjv, const void* __restrict__ cls,
    const void* __restrict__ pos, float* __restrict__ hidden,
    const int* __restrict__ bad)
{
    int isbf = (*bad == 0);
    int i = blockIdx.x * 256 + threadIdx.x;
    int c = i % D_;
    int l = (i / D_) % L_;
    int b = i / (D_ * L_);
    size_t si;
    const void* sp;
    if (l < 247)       { sp = cjv; si = ((size_t)b * 494 + l) * D_ + c; }
    else if (l == 247) { sp = cls; si = c; }
    else               { sp = cjv; si = ((size_t)b * 494 + (l - 1)) * D_ + c; }
    float v = isbf ? bf2f(((const u16*)sp)[si]) : ((const float*)sp)[si];
    size_t pi = (size_t)l * D_ + c;
    float p = isbf ? bf2f(((const u16*)pos)[pi]) : ((const float*)pos)[pi];
    hidden[i] = v + p;
}

// resid = hidden (+ resid); hbf <- bf16(rmsnorm(resid)*w)
__global__ __launch_bounds__(128) void resnorm_kernel(
    const float* __restrict__ hidden, float* __restrict__ resid,
    const float* __restrict__ w, u16* __restrict__ hbf, int first)
{
    int m = blockIdx.x, tid = threadIdx.x;
    size_t base = (size_t)m * D_;
    float v[3]; float ss = 0.f;
#pragma unroll
    for (int i = 0; i < 3; ++i) {
        int c = tid + i * 128;
        float r = hidden[base + c];
        if (!first) r += resid[base + c];
        resid[base + c] = r;
        v[i] = r; ss += r * r;
    }
    ss += __shfl_xor(ss, 32); ss += __shfl_xor(ss, 16); ss += __shfl_xor(ss, 8);
    ss += __shfl_xor(ss, 4);  ss += __shfl_xor(ss, 2);  ss += __shfl_xor(ss, 1);
    __shared__ float sred[2];
    if ((tid & 63) == 0) sred[tid >> 6] = ss;
    __syncthreads();
    float scale = rsqrtf((sred[0] + sred[1]) * (1.f / D_) + 1e-5f);
#pragma unroll
    for (int i = 0; i < 3; ++i) {
        int c = tid + i * 128;
        hbf[base + c] = f2bf(v[i] * scale * w[c]);
    }
}

// ===== MFMA GEMM: C(M,N) = alpha * (A [+ A2])(M,K)bf16 @ W(N,K)bf16^T =====
template<int CF32, int SUM2>
__global__ __launch_bounds__(256) void gemm_mfma_bt(
    const u16* __restrict__ A, const u16* __restrict__ A2,
    const u16* __restrict__ W, void* __restrict__ Cv,
    int M, int N, int K, int ldc, float alpha)
{
    __shared__ __align__(16) u16 As[128 * 40];
    __shared__ __align__(16) u16 Ws[128 * 40];
    int tid = threadIdx.x;
    int wave = tid >> 6, lane = tid & 63;
    int m0 = blockIdx.x * 128, n0 = blockIdx.y * 128;
    int wm = (wave >> 1) * 64, wn = (wave & 1) * 64;
    int ml = lane & 15, quad = lane >> 4;

    float4v acc[4][4];
#pragma unroll
    for (int i = 0; i < 4; ++i)
#pragma unroll
        for (int j = 0; j < 4; ++j)
#pragma unroll
            for (int r = 0; r < 4; ++r) acc[i][j][r] = 0.f;

    int srow = tid >> 2;
    int scol = (tid & 3) * 8;

    for (int k0 = 0; k0 < K; k0 += 32) {
#pragma unroll
        for (int p = 0; p < 2; ++p) {
            int row = srow + p * 64;
            int gm = m0 + row; if (gm >= M) gm = M - 1;
            if (SUM2) {
                short8 a0 = *(const short8*)(A  + (size_t)gm * K + k0 + scol);
                short8 a1 = *(const short8*)(A2 + (size_t)gm * K + k0 + scol);
                u16 tmp[8];
#pragma unroll
                for (int r = 0; r < 8; ++r)
                    tmp[r] = f2bf(bf2f((u16)a0[r]) + bf2f((u16)a1[r]));
                *(uint4*)&As[row * 40 + scol] = *(const uint4*)tmp;
            } else {
                *(uint4*)&As[row * 40 + scol] =
                    *(const uint4*)(A + (size_t)gm * K + k0 + scol);
            }
            int gn = n0 + row;
            *(uint4*)&Ws[row * 40 + scol] =
                *(const uint4*)(W + (size_t)gn * K + k0 + scol);
        }
        __syncthreads();
        short8 af[4], bfr[4];
#pragma unroll
        for (int i = 0; i < 4; ++i) {
            af[i]  = *(const short8*)&As[(wm + i * 16 + ml) * 40 + quad * 8];
            bfr[i] = *(const short8*)&Ws[(wn + i * 16 + ml) * 40 + quad * 8];
        }
#pragma unroll
        for (int i = 0; i < 4; ++i)
#pragma unroll
            for (int j = 0; j < 4; ++j)
                acc[i][j] = __builtin_amdgcn_mfma_f32_16x16x32_bf16(
                    af[i], bfr[j], acc[i][j], 0, 0, 0);
        __syncthreads();
    }

#pragma unroll
    for (int i = 0; i < 4; ++i)
#pragma unroll
        for (int j = 0; j < 4; ++j)
#pragma unroll
            for (int r = 0; r < 4; ++r) {
                int m = m0 + wm + i * 16 + quad * 4 + r;
                if (m >= M) continue;
                int n = n0 + wn + j * 16 + ml;
                float val = alpha * acc[i][j][r];
                if (CF32) ((float*)Cv)[(size_t)m * ldc + n] = val;
                else      ((u16*)Cv)[(size_t)m * ldc + n] = f2bf(val);
            }
}

// ===== xproj MFMA GEMM: dbl2[dir](m,56) = xc2[dir](M,768) @ xpWb[dir](56,768)^T
__global__ __launch_bounds__(256) void xproj_gemm_kernel(
    const u16* __restrict__ xc2, const u16* __restrict__ xpWb_l,
    float* __restrict__ dbl2)
{
    int dir = blockIdx.y;
    const u16* A = xc2 + (size_t)dir * M_ * DI_;
    const u16* W = xpWb_l + (size_t)dir * 56 * DI_;
    float* C = dbl2 + (size_t)dir * M_ * 56;

    __shared__ __align__(16) u16 As[128 * 40];
    __shared__ __align__(16) u16 Ws[64 * 40];
    int tid = threadIdx.x;
    int wave = tid >> 6, lane = tid & 63;
    int m0 = blockIdx.x * 128;
    int wm = wave * 32;
    int ml = lane & 15, quad = lane >> 4;

    float4v acc[2][4];
#pragma unroll
    for (int i = 0; i < 2; ++i)
#pragma unroll
        for (int j = 0; j < 4; ++j)
#pragma unroll
            for (int r = 0; r < 4; ++r) acc[i][j][r] = 0.f;

    int srow = tid >> 2;
    int scol = (tid & 3) * 8;

    for (int k0 = 0; k0 < DI_; k0 += 32) {
#pragma unroll
        for (int p = 0; p < 2; ++p) {
            int row = srow + p * 64;
            int gm = m0 + row; if (gm >= M_) gm = M_ - 1;
            *(uint4*)&As[row * 40 + scol] =
                *(const uint4*)(A + (size_t)gm * DI_ + k0 + scol);
        }
        *(uint4*)&Ws[srow * 40 + scol] =
            *(const uint4*)(W + (size_t)srow * DI_ + k0 + scol);
        __syncthreads();
        short8 af[2], bfr[4];
#pragma unroll
        for (int i = 0; i < 2; ++i)
            af[i] = *(const short8*)&As[(wm + i * 16 + ml) * 40 + quad * 8];
#pragma unroll
        for (int j = 0; j < 4; ++j)
            bfr[j] = *(const short8*)&Ws[(j * 16 + ml) * 40 + quad * 8];
#pragma unroll
        for (int i = 0; i < 2; ++i)
#pragma unroll
            for (int j = 0; j < 4; ++j)
                acc[i][j] = __builtin_amdgcn_mfma_f32_16x16x32_bf16(
                    af[i], bfr[j], acc[i][j], 0, 0, 0);
        __syncthreads();
    }

#pragma unroll
    for (int i = 0; i < 2; ++i)
#pragma unroll
        for (int j = 0; j < 4; ++j)
#pragma unroll
            for (int r = 0; r < 4; ++r) {
                int m = m0 + wm + i * 16 + quad * 4 + r;
                int n = j * 16 + ml;
                if (m < M_ && n < 56)
                    C[(size_t)m * 56 + n] = acc[i][j][r];
            }
}

// causal depthwise conv (K=4) + bias + silu, 2 channels/thread, both dirs
__global__ __launch_bounds__(256) void conv_silu_kernel(
    const u16* __restrict__ xz, const float* __restrict__ cw_l,
    const float* __restrict__ cb_l, u16* __restrict__ xc2)
{
    int dir = blockIdx.y;
    const float* cw = cw_l + (size_t)dir * DI_ * 4;
    const float* cb = cb_l + (size_t)dir * DI_;
    u16* xc = xc2 + (size_t)dir * M_ * DI_;
    int i = blockIdx.x * 256 + threadIdx.x;   // pair index
    int dp = i % (DI_ / 2);
    int d = dp * 2;
    int s = (i / (DI_ / 2)) % L_;
    int b = i / ((DI_ / 2) * L_);
    float a0 = cb[d], a1 = cb[d + 1];
#pragma unroll
    for (int k = 0; k < 4; ++k) {
        int t = s - 3 + k;
        if (t >= 0) {
            int lorig = dir ? (L_ - 1 - t) : t;
            unsigned u = *(const unsigned*)&xz[((size_t)b * L_ + lorig) * 1536 + d];
            a0 += cw[d * 4 + k] * bf2f((u16)(u & 0xffff));
            a1 += cw[(d + 1) * 4 + k] * bf2f((u16)(u >> 16));
        }
    }
    unsigned out = (unsigned)f2bf(silu_f(a0)) | ((unsigned)f2bf(silu_f(a1)) << 16);
    *(unsigned*)&xc[(size_t)i * 2] = out;
}

// ================= segmented selective scan (both dirs per launch) ==========
__device__ __forceinline__ float dt_delta(
    const float* __restrict__ row, const float* W, float bias)
{
    float s = bias;
    const float4* pd = reinterpret_cast<const float4*>(row);
#pragma unroll
    for (int r = 0; r < 6; ++r) {
        float4 d4 = pd[r];
        s += W[4 * r + 0] * d4.x + W[4 * r + 1] * d4.y
           + W[4 * r + 2] * d4.z + W[4 * r + 3] * d4.w;
    }
    return (s > 20.f) ? s : __logf(1.f + __expf(s));
}

// grid (B_*3*SEG, 2) blocks of 256: 4 waves = 4 d-blocks. A pre-scaled by log2e.
// P computed algebraically: P[n] = exp2(A[n] * sum(dl)).
template<int STORE_D>
__global__ __launch_bounds__(256) void scan_part1_kernel(
    const u16* __restrict__ xc2, const float* __restrict__ dbl2,
    const float* __restrict__ dtW_l, const float* __restrict__ dtb_l,
    const float* __restrict__ Alog_l,
    u16* __restrict__ P_buf, u16* __restrict__ q_buf, u16* __restrict__ delta2)
{
    int dir = blockIdx.y;
    const u16* xc = xc2 + (size_t)dir * M_ * DI_;
    const float* dbl = dbl2 + (size_t)dir * M_ * 56;
    const float* dtW = dtW_l + (size_t)dir * DI_ * DTR_;
    const float* dtb = dtb_l + (size_t)dir * DI_;
    const float* Alog = Alog_l + (size_t)dir * DI_ * DS_;
    u16* dout = delta2 + (size_t)dir * M_ * DI_;

    int tid = threadIdx.x;
    int wave = tid >> 6, lane = tid & 63;
    int s = blockIdx.x % SEG;
    int bq = blockIdx.x / SEG;
    int b = bq / 3, dq = bq % 3;
    int dblk = dq * 4 + wave;
    int d = dblk * 64 + lane;
    size_t mb = (size_t)b * L_;
    int t0 = s * TL;
    int t1 = (t0 + TL < L_) ? (t0 + TL) : L_;

    float A[16];
    {
        const float4* ap = reinterpret_cast<const float4*>(Alog + (size_t)d * 16);
#pragma unroll
        for (int i = 0; i < 4; ++i) {
            float4 a4 = ap[i];
            A[4 * i + 0] = -LOG2E * __expf(a4.x); A[4 * i + 1] = -LOG2E * __expf(a4.y);
            A[4 * i + 2] = -LOG2E * __expf(a4.z); A[4 * i + 3] = -LOG2E * __expf(a4.w);
        }
    }
    float W[24];
    {
        const float4* wp = reinterpret_cast<const float4*>(dtW + (size_t)d * 24);
#pragma unroll
        for (int i = 0; i < 6; ++i) {
            float4 w4 = wp[i];
            W[4 * i + 0] = w4.x; W[4 * i + 1] = w4.y;
            W[4 * i + 2] = w4.z; W[4 * i + 3] = w4.w;
        }
    }
    float bias = dtb[d];
    float h[16];
    float S = 0.f;
#pragma unroll
    for (int i = 0; i < 16; ++i) h[i] = 0.f;

    for (int t = t0; t < t1; ++t) {
        const float* row = dbl + (mb + t) * 56;
        float dl = dt_delta(row, W, bias);
        if (STORE_D) dout[(mb + t) * DI_ + d] = f2bf(dl);
        S += dl;
        float xv = bf2f(xc[(mb + t) * DI_ + d]);
        float dlxv = dl * xv;
        const float4* pb = reinterpret_cast<const float4*>(row + 24);
#pragma unroll
        for (int j = 0; j < 4; ++j) {
            float4 B4 = pb[j];
            float e0 = __builtin_amdgcn_exp2f(dl * A[4 * j + 0]);
            float e1 = __builtin_amdgcn_exp2f(dl * A[4 * j + 1]);
            float e2 = __builtin_amdgcn_exp2f(dl * A[4 * j + 2]);
            float e3 = __builtin_amdgcn_exp2f(dl * A[4 * j + 3]);
            h[4 * j + 0] = e0 * h[4 * j + 0] + dlxv * B4.x;
            h[4 * j + 1] = e1 * h[4 * j + 1] + dlxv * B4.y;
            h[4 * j + 2] = e2 * h[4 * j + 2] + dlxv * B4.z;
            h[4 * j + 3] = e3 * h[4 * j + 3] + dlxv * B4.w;
        }
    }
    int bd = b * 12 + dblk;
    size_t base = ((size_t)dir * SGRID + (size_t)bd * SEG + s) * 16 * 64 + lane;
#pragma unroll
    for (int n = 0; n < 16; ++n) {
        P_buf[base + (size_t)n * 64] = f2bf(__builtin_amdgcn_exp2f(A[n] * S));
        q_buf[base + (size_t)n * 64] = f2bf(h[n]);
    }
}

// Phase 2: grid (192, 4, 2): y = state quad, z = dir.
__global__ __launch_bounds__(64) void scan_combine_kernel(
    const u16* __restrict__ P_buf, u16* __restrict__ q_buf)
{
    int lane = threadIdx.x;
    int bd = blockIdx.x;
    int nq = blockIdx.y;
    size_t dbase = (size_t)blockIdx.z * SGRID * 16 * 64;
    float h[4] = {0.f, 0.f, 0.f, 0.f};
    for (int s = 0; s < SEG; ++s) {
        size_t base = dbase + ((size_t)(bd * SEG + s) * 16 + nq * 4) * 64 + lane;
#pragma unroll
        for (int n = 0; n < 4; ++n) {
            size_t idx = base + (size_t)n * 64;
            float Pv = bf2f(P_buf[idx]);
            float qv = bf2f(q_buf[idx]);
            q_buf[idx] = f2bf(h[n]);
            h[n] = Pv * h[n] + qv;
        }
    }
}

// Phase 3: rescan from true hin; dir0 -> y0, dir1 -> y1.
// USE_D: read delta stored by part1 instead of recomputing dt_proj+softplus.
template<int USE_D>
__global__ __launch_bounds__(256) void scan_part3_kernel(
    const u16* __restrict__ xc2, const float* __restrict__ dbl2,
    const u16* __restrict__ xz, const float* __restrict__ dtW_l,
    const float* __restrict__ dtb_l, const float* __restrict__ Alog_l,
    const float* __restrict__ Dp_l, const u16* __restrict__ q_buf,
    u16* __restrict__ y0, u16* __restrict__ y1, const u16* __restrict__ delta2)
{
    int dir = blockIdx.y;
    const u16* xc = xc2 + (size_t)dir * M_ * DI_;
    const float* dbl = dbl2 + (size_t)dir * M_ * 56;
    const float* Alog = Alog_l + (size_t)dir * DI_ * DS_;
    const float* Dp = Dp_l + (size_t)dir * DI_;
    const u16* din = delta2 + (size_t)dir * M_ * DI_;
    u16* yb = dir ? y1 : y0;

    int tid = threadIdx.x;
    int wave = tid >> 6, lane = tid & 63;
    int s = blockIdx.x % SEG;
    int bq = blockIdx.x / SEG;
    int b = bq / 3, dq = bq % 3;
    int dblk = dq * 4 + wave;
    int d = dblk * 64 + lane;
    size_t mb = (size_t)b * L_;
    int t0 = s * TL;
    int t1 = (t0 + TL < L_) ? (t0 + TL) : L_;

    float A[16];
    {
        const float4* ap = reinterpret_cast<const float4*>(Alog + (size_t)d * 16);
#pragma unroll
        for (int i = 0; i < 4; ++i) {
            float4 a4 = ap[i];
            A[4 * i + 0] = -LOG2E * __expf(a4.x); A[4 * i + 1] = -LOG2E * __expf(a4.y);
            A[4 * i + 2] = -LOG2E * __expf(a4.z); A[4 * i + 3] = -LOG2E * __expf(a4.w);
        }
    }
    float W[24];
    float bias = 0.f;
    if (!USE_D) {
        const float* dtW = dtW_l + (size_t)dir * DI_ * DTR_;
        const float4* wp = reinterpret_cast<const float4*>(dtW + (size_t)d * 24);
#pragma unroll
        for (int i = 0; i < 6; ++i) {
            float4 w4 = wp[i];
            W[4 * i + 0] = w4.x; W[4 * i + 1] = w4.y;
            W[4 * i + 2] = w4.z; W[4 * i + 3] = w4.w;
        }
        bias = (dtb_l + (size_t)dir * DI_)[d];
    }
    float Dval = Dp[d];
    int bd = b * 12 + dblk;
    float h[16];
    {
        size_t base = ((size_t)dir * SGRID + (size_t)bd * SEG + s) * 16 * 64 + lane;
#pragma unroll
        for (int n = 0; n < 16; ++n) h[n] = bf2f(q_buf[base + (size_t)n * 64]);
    }

    for (int t = t0; t < t1; ++t) {
        const float* row = dbl + (mb + t) * 56;
        float dl;
        if (USE_D) dl = bf2f(din[(mb + t) * DI_ + d]);
        else       dl = dt_delta(row, W, bias);
        float xv = bf2f(xc[(mb + t) * DI_ + d]);
        float dlxv = dl * xv;
        const float4* pb = reinterpret_cast<const float4*>(row + 24);
        const float4* pc = reinterpret_cast<const float4*>(row + 40);
        float a0 = 0.f, a1 = 0.f, a2 = 0.f, a3 = 0.f;
#pragma unroll
        for (int j = 0; j < 4; ++j) {
            float4 B4 = pb[j], C4 = pc[j];
            float e0 = __builtin_amdgcn_exp2f(dl * A[4 * j + 0]);
            float e1 = __builtin_amdgcn_exp2f(dl * A[4 * j + 1]);
            float e2 = __builtin_amdgcn_exp2f(dl * A[4 * j + 2]);
            float e3 = __builtin_amdgcn_exp2f(dl * A[4 * j + 3]);
            h[4 * j + 0] = e0 * h[4 * j + 0] + dlxv * B4.x;
            h[4 * j + 1] = e1 * h[4 * j + 1] + dlxv * B4.y;
            h[4 * j + 2] = e2 * h[4 * j + 2] + dlxv * B4.z;
            h[4 * j + 3] = e3 * h[4 * j + 3] + dlxv * B4.w;
            a0 += h[4 * j + 0] * C4.x;
            a1 += h[4 * j + 1] * C4.y;
            a2 += h[4 * j + 2] * C4.z;
            a3 += h[4 * j + 3] * C4.w;
        }
        float y = (a0 + a1) + (a2 + a3) + xv * Dval;
        int lorig = dir ? (L_ - 1 - t) : t;
        y *= silu_f(bf2f(xz[(mb + lorig) * 1536 + 768 + d]));
        yb[(mb + lorig) * DI_ + d] = f2bf(y);
    }
}

// final: residual+hidden, rmsnorm, permute+slice, store bf16 or f32 per flag
__global__ __launch_bounds__(128) void final_kernel(
    const float* __restrict__ hidden, const float* __restrict__ resid,
    const float* __restrict__ w, void* __restrict__ out,
    const int* __restrict__ bad)
{
    int blk = blockIdx.x;
    int b = blk / 446, tok = blk % 446;
    int lorig; size_t dst;
    if (tok == 0)      { lorig = 247; dst = (size_t)b * D_; }
    else if (tok <= 14){ int j = tok - 1; lorig = 49 + j; dst = 6144 + ((size_t)b * 14 + j) * D_; }
    else               { int v = tok - 15; lorig = (v < 184) ? (63 + v) : (64 + v);
                         dst = 92160 + ((size_t)b * 431 + v) * D_; }
    size_t base = ((size_t)b * L_ + lorig) * D_;
    int tid = threadIdx.x;
    float v3[3]; float ss = 0.f;
#pragma unroll
    for (int i = 0; i < 3; ++i) {
        int c = tid + i * 128;
        float r = hidden[base + c] + resid[base + c];
        v3[i] = r; ss += r * r;
    }
    ss += __shfl_xor(ss, 32); ss += __shfl_xor(ss, 16); ss += __shfl_xor(ss, 8);
    ss += __shfl_xor(ss, 4);  ss += __shfl_xor(ss, 2);  ss += __shfl_xor(ss, 1);
    __shared__ float sred[2];
    if ((tid & 63) == 0) sred[tid >> 6] = ss;
    __syncthreads();
    float scale = rsqrtf((sred[0] + sred[1]) * (1.f / D_) + 1e-5f);
    int isbf = (*bad == 0);
#pragma unroll
    for (int i = 0; i < 3; ++i) {
        int c = tid + i * 128;
        float val = v3[i] * scale * w[c];
        if (isbf) ((u16*)out)[dst + c] = f2bf(val);
        else      ((float*)out)[dst + c] = val;
    }
}

extern "C" void kernel_launch(void* const* d_in, const int* in_sizes, int n_in,
                              void* d_out, int out_size, void* d_ws, size_t ws_size,
                              hipStream_t stream) {
    char* wsb = (char*)d_ws;
    int* bad = (int*)wsb;  wsb += 16;

    // canon (11): inW(bf16), cW, cB, xpW(bf16), dtW, dtB, Alog, Dsk, outW(bf16), nw, fnw
    const int cn[11] = {2359296, 24576, 6144, 344064, 147456, 6144, 98304,
                        6144, 1179648, 1536, 384};
    const int raw_idx[11] = {4, 5, 6, 7, 8, 9, 10, 11, 12, 13, 14};
    const int tobf[11]    = {1, 0, 0, 1, 0, 0, 0, 0, 1, 0, 0};
    void* canon[11];
    for (int i = 0; i < 11; ++i) {
        canon[i] = (void*)wsb;
        wsb += (size_t)cn[i] * (tobf[i] ? 2 : 4);
    }
    const u16*   inWb = (const u16*)canon[0];
    const float* cW   = (const float*)canon[1];
    const float* cB   = (const float*)canon[2];
    const u16*   xpWb = (const u16*)canon[3];
    const float* dtW  = (const float*)canon[4];
    const float* dtB  = (const float*)canon[5];
    const float* Alog = (const float*)canon[6];
    const float* Dsk  = (const float*)canon[7];
    const u16*   outWb= (const u16*)canon[8];
    const float* nw   = (const float*)canon[9];
    const float* fnw  = (const float*)canon[10];

    float* hidden = (float*)wsb;  wsb += (size_t)M_ * D_ * 4;
    float* resid  = (float*)wsb;  wsb += (size_t)M_ * D_ * 4;
    float* dbl2   = (float*)wsb;  wsb += (size_t)2 * M_ * 56 * 4;
    u16*   xz     = (u16*)wsb;    wsb += (size_t)M_ * 1536 * 2;
    u16*   xc2    = (u16*)wsb;    wsb += (size_t)2 * M_ * DI_ * 2;
    u16*   y0     = (u16*)wsb;    wsb += (size_t)M_ * DI_ * 2;           // hbf aliases
    u16*   P_buf  = (u16*)wsb;    wsb += (size_t)2 * SGRID * 16 * 64 * 2; // y1 aliases
    u16*   q_buf  = (u16*)wsb;    wsb += (size_t)2 * SGRID * 16 * 64 * 2;
    u16*   delta2 = (u16*)wsb;    wsb += (size_t)2 * M_ * DI_ * 2;       // optional, +24.3MB
    u16* hbf = y0;
    u16* y1  = P_buf;
    // delta path only if workspace is large enough (ws_size constant per session
    // -> deterministic launch sequence, graph-capture safe)
    int use_delta = ((size_t)(wsb - (char*)d_ws) <= ws_size);

    hipMemsetAsync(bad, 0, 4, stream);
    detect_kernel<<<384, 256, 0, stream>>>((const u16*)d_in[10], bad);
    {
        CvtArgs ca;
        int maxn = 0;
        for (int i = 0; i < 11; ++i) {
            ca.src[i] = d_in[raw_idx[i]]; ca.dst[i] = canon[i];
            ca.n[i] = cn[i]; ca.tobf[i] = tobf[i];
            if (cn[i] > maxn) maxn = cn[i];
        }
        cvt_all_kernel<<<dim3((maxn + 255) / 256, 11), 256, 0, stream>>>(ca, bad);
    }

    build_hidden_kernel<<<(M_ * D_) / 256, 256, 0, stream>>>(
        d_in[0], d_in[2], d_in[3], hidden, bad);

    const int gmb = (M_ + 127) / 128;      // 62
    for (int l = 0; l < 4; ++l) {
        const float* dtWl = dtW + (size_t)l * 2 * DI_ * DTR_;
        const float* dtBl = dtB + (size_t)l * 2 * DI_;
        const float* All  = Alog + (size_t)l * 2 * DI_ * DS_;
        const float* Dl   = Dsk + (size_t)l * 2 * DI_;
        resnorm_kernel<<<M_, 128, 0, stream>>>(hidden, resid, nw + (size_t)l * D_, hbf, l == 0);
        gemm_mfma_bt<0, 0><<<dim3(gmb, 1536 / 128), 256, 0, stream>>>(
            hbf, nullptr, inWb + (size_t)l * 1536 * D_, xz, M_, 1536, D_, 1536, 1.f);
        conv_silu_kernel<<<dim3((M_ * DI_ / 2) / 256, 2), 256, 0, stream>>>(
            xz, cW + (size_t)l * 2 * DI_ * 4, cB + (size_t)l * 2 * DI_, xc2);
        xproj_gemm_kernel<<<dim3(gmb, 2), 256, 0, stream>>>(
            xc2, xpWb + (size_t)l * 2 * 56 * DI_, dbl2);
        if (use_delta)
            scan_part1_kernel<1><<<dim3(B_ * 3 * SEG, 2), 256, 0, stream>>>(
                xc2, dbl2, dtWl, dtBl, All, P_buf, q_buf, delta2);
        else
            scan_part1_kernel<0><<<dim3(B_ * 3 * SEG, 2), 256, 0, stream>>>(
                xc2, dbl2, dtWl, dtBl, All, P_buf, q_buf, delta2);
        scan_combine_kernel<<<dim3(NBD, 4, 2), 64, 0, stream>>>(P_buf, q_buf);
        if (use_delta)
            scan_part3_kernel<1><<<dim3(B_ * 3 * SEG, 2), 256, 0, stream>>>(
                xc2, dbl2, xz, dtWl, dtBl, All, Dl, q_buf, y0, y1, delta2);
        else
            scan_part3_kernel<0><<<dim3(B_ * 3 * SEG, 2), 256, 0, stream>>>(
                xc2, dbl2, xz, dtWl, dtBl, All, Dl, q_buf, y0, y1, delta2);
        gemm_mfma_bt<1, 1><<<dim3(gmb, 384 / 128), 256, 0, stream>>>(
            y0, y1, outWb + (size_t)l * D_ * DI_, hidden, M_, 384, DI_, 384, 0.5f);
    }

    final_kernel<<<B_ * 446, 128, 0, stream>>>(hidden, resid, fnw, d_out, bad);
}

// Round 12
// 1017.252 us; speedup vs baseline: 5.7477x; 1.2638x over previous
//
#include <hip/hip_runtime.h>

typedef unsigned short u16;
typedef __attribute__((ext_vector_type(8))) short short8;
typedef __attribute__((ext_vector_type(4))) float float4v;

#define B_   16
#define L_   495
#define D_   384
#define DI_  768
#define DS_  16
#define DTR_ 24
#define SEG  16
#define TL   31   // ceil(495/16)
#define M_   (B_ * L_)
#define NBD  (B_ * 12)            // 192 (b,d-block) pairs
#define SGRID (NBD * SEG)         // 3072 flat scan units per dir
#define LOG2E 1.44269504f
#define CNCH 15
#define CTL  34   // 15*34 = 510 >= 498 (t in [0, L+3))

__device__ __forceinline__ float bf2f(u16 u) {
    return __uint_as_float(((unsigned)u) << 16);
}
__device__ __forceinline__ u16 f2bf(float f) {
    unsigned u = __float_as_uint(f);
    unsigned r = 0x7fffu + ((u >> 16) & 1u);
    return (u16)((u + r) >> 16);
}
__device__ __forceinline__ float silu_f(float x) {
    return x / (1.f + __expf(-x));
}

// ---- dtype detector (parallel): A_log in [0,2.78] as bf16 => bad==0 -> bf16.
__global__ __launch_bounds__(256) void detect_kernel(
    const u16* __restrict__ alog_raw, int* __restrict__ bad)
{
    int i = blockIdx.x * 256 + threadIdx.x;   // grid 384 -> 98304
    float v = bf2f(alog_raw[i]);
    int b = !(v >= -1e-3f && v <= 2.8f);
    unsigned long long m = __ballot(b);
    if ((threadIdx.x & 63) == 0 && m) atomicAdd(bad, (int)__popcll(m));
}

// ---- batched convert (blockIdx.y = tensor). tobf: emit bf16 instead of f32.
struct CvtArgs {
    const void* src[11];
    void* dst[11];
    int n[11];
    int tobf[11];
};
__global__ __launch_bounds__(256) void cvt_all_kernel(CvtArgs a, const int* __restrict__ bad)
{
    int t = blockIdx.y;
    int i = blockIdx.x * 256 + threadIdx.x;
    if (i >= a.n[t]) return;
    int isbf = (*bad == 0);
    if (a.tobf[t]) {
        u16 v = isbf ? ((const u16*)a.src[t])[i] : f2bf(((const float*)a.src[t])[i]);
        ((u16*)a.dst[t])[i] = v;
    } else {
        float v = isbf ? bf2f(((const u16*)a.src[t])[i]) : ((const float*)a.src[t])[i];
        ((float*)a.dst[t])[i] = v;
    }
}

// hidden[b,l,c] = concat(cjv[:247], cls, cjv[247:]) + pos_embed  (raw inputs)
__global__ __launch_bounds__(256) void build_hidden_kernel(
    const void* __restrict__ cjv, const void* __restrict__ cls,
    const void* __restrict__ pos, float* __restrict__ hidden,
    const int* __restrict__ bad)
{
    int isbf = (*bad == 0);
    int i = blockIdx.x * 256 + threadIdx.x;
    int c = i % D_;
    int l = (i / D_) % L_;
    int b = i / (D_ * L_);
    size_t si;
    const void* sp;
    if (l < 247)       { sp = cjv; si = ((size_t)b * 494 + l) * D_ + c; }
    else if (l == 247) { sp = cls; si = c; }
    else               { sp = cjv; si = ((size_t)b * 494 + (l - 1)) * D_ + c; }
    float v = isbf ? bf2f(((const u16*)sp)[si]) : ((const float*)sp)[si];
    size_t pi = (size_t)l * D_ + c;
    float p = isbf ? bf2f(((const u16*)pos)[pi]) : ((const float*)pos)[pi];
    hidden[i] = v + p;
}

// resid = hidden (+ resid); hbf <- bf16(rmsnorm(resid)*w)
__global__ __launch_bounds__(128) void resnorm_kernel(
    const float* __restrict__ hidden, float* __restrict__ resid,
    const float* __restrict__ w, u16* __restrict__ hbf, int first)
{
    int m = blockIdx.x, tid = threadIdx.x;
    size_t base = (size_t)m * D_;
    float v[3]; float ss = 0.f;
#pragma unroll
    for (int i = 0; i < 3; ++i) {
        int c = tid + i * 128;
        float r = hidden[base + c];
        if (!first) r += resid[base + c];
        resid[base + c] = r;
        v[i] = r; ss += r * r;
    }
    ss += __shfl_xor(ss, 32); ss += __shfl_xor(ss, 16); ss += __shfl_xor(ss, 8);
    ss += __shfl_xor(ss, 4);  ss += __shfl_xor(ss, 2);  ss += __shfl_xor(ss, 1);
    __shared__ float sred[2];
    if ((tid & 63) == 0) sred[tid >> 6] = ss;
    __syncthreads();
    float scale = rsqrtf((sred[0] + sred[1]) * (1.f / D_) + 1e-5f);
#pragma unroll
    for (int i = 0; i < 3; ++i) {
        int c = tid + i * 128;
        hbf[base + c] = f2bf(v[i] * scale * w[c]);
    }
}

// ===== MFMA GEMM: C(M,N) = alpha * (A [+ A2])(M,K)bf16 @ W(N,K)bf16^T =====
template<int CF32, int SUM2>
__global__ __launch_bounds__(256) void gemm_mfma_bt(
    const u16* __restrict__ A, const u16* __restrict__ A2,
    const u16* __restrict__ W, void* __restrict__ Cv,
    int M, int N, int K, int ldc, float alpha)
{
    __shared__ __align__(16) u16 As[128 * 40];
    __shared__ __align__(16) u16 Ws[128 * 40];
    int tid = threadIdx.x;
    int wave = tid >> 6, lane = tid & 63;
    int m0 = blockIdx.x * 128, n0 = blockIdx.y * 128;
    int wm = (wave >> 1) * 64, wn = (wave & 1) * 64;
    int ml = lane & 15, quad = lane >> 4;

    float4v acc[4][4];
#pragma unroll
    for (int i = 0; i < 4; ++i)
#pragma unroll
        for (int j = 0; j < 4; ++j)
#pragma unroll
            for (int r = 0; r < 4; ++r) acc[i][j][r] = 0.f;

    int srow = tid >> 2;
    int scol = (tid & 3) * 8;

    for (int k0 = 0; k0 < K; k0 += 32) {
#pragma unroll
        for (int p = 0; p < 2; ++p) {
            int row = srow + p * 64;
            int gm = m0 + row; if (gm >= M) gm = M - 1;
            if (SUM2) {
                short8 a0 = *(const short8*)(A  + (size_t)gm * K + k0 + scol);
                short8 a1 = *(const short8*)(A2 + (size_t)gm * K + k0 + scol);
                u16 tmp[8];
#pragma unroll
                for (int r = 0; r < 8; ++r)
                    tmp[r] = f2bf(bf2f((u16)a0[r]) + bf2f((u16)a1[r]));
                *(uint4*)&As[row * 40 + scol] = *(const uint4*)tmp;
            } else {
                *(uint4*)&As[row * 40 + scol] =
                    *(const uint4*)(A + (size_t)gm * K + k0 + scol);
            }
            int gn = n0 + row;
            *(uint4*)&Ws[row * 40 + scol] =
                *(const uint4*)(W + (size_t)gn * K + k0 + scol);
        }
        __syncthreads();
        short8 af[4], bfr[4];
#pragma unroll
        for (int i = 0; i < 4; ++i) {
            af[i]  = *(const short8*)&As[(wm + i * 16 + ml) * 40 + quad * 8];
            bfr[i] = *(const short8*)&Ws[(wn + i * 16 + ml) * 40 + quad * 8];
        }
#pragma unroll
        for (int i = 0; i < 4; ++i)
#pragma unroll
            for (int j = 0; j < 4; ++j)
                acc[i][j] = __builtin_amdgcn_mfma_f32_16x16x32_bf16(
                    af[i], bfr[j], acc[i][j], 0, 0, 0);
        __syncthreads();
    }

#pragma unroll
    for (int i = 0; i < 4; ++i)
#pragma unroll
        for (int j = 0; j < 4; ++j)
#pragma unroll
            for (int r = 0; r < 4; ++r) {
                int m = m0 + wm + i * 16 + quad * 4 + r;
                if (m >= M) continue;
                int n = n0 + wn + j * 16 + ml;
                float val = alpha * acc[i][j][r];
                if (CF32) ((float*)Cv)[(size_t)m * ldc + n] = val;
                else      ((u16*)Cv)[(size_t)m * ldc + n] = f2bf(val);
            }
}

// ===== xproj MFMA GEMM: dbl2[dir](m,56) = xc2[dir](M,768) @ xpWb[dir](56,768)^T
__global__ __launch_bounds__(256) void xproj_gemm_kernel(
    const u16* __restrict__ xc2, const u16* __restrict__ xpWb_l,
    float* __restrict__ dbl2)
{
    int dir = blockIdx.y;
    const u16* A = xc2 + (size_t)dir * M_ * DI_;
    const u16* W = xpWb_l + (size_t)dir * 56 * DI_;
    float* C = dbl2 + (size_t)dir * M_ * 56;

    __shared__ __align__(16) u16 As[128 * 40];
    __shared__ __align__(16) u16 Ws[64 * 40];
    int tid = threadIdx.x;
    int wave = tid >> 6, lane = tid & 63;
    int m0 = blockIdx.x * 128;
    int wm = wave * 32;
    int ml = lane & 15, quad = lane >> 4;

    float4v acc[2][4];
#pragma unroll
    for (int i = 0; i < 2; ++i)
#pragma unroll
        for (int j = 0; j < 4; ++j)
#pragma unroll
            for (int r = 0; r < 4; ++r) acc[i][j][r] = 0.f;

    int srow = tid >> 2;
    int scol = (tid & 3) * 8;

    for (int k0 = 0; k0 < DI_; k0 += 32) {
#pragma unroll
        for (int p = 0; p < 2; ++p) {
            int row = srow + p * 64;
            int gm = m0 + row; if (gm >= M_) gm = M_ - 1;
            *(uint4*)&As[row * 40 + scol] =
                *(const uint4*)(A + (size_t)gm * DI_ + k0 + scol);
        }
        *(uint4*)&Ws[srow * 40 + scol] =
            *(const uint4*)(W + (size_t)srow * DI_ + k0 + scol);
        __syncthreads();
        short8 af[2], bfr[4];
#pragma unroll
        for (int i = 0; i < 2; ++i)
            af[i] = *(const short8*)&As[(wm + i * 16 + ml) * 40 + quad * 8];
#pragma unroll
        for (int j = 0; j < 4; ++j)
            bfr[j] = *(const short8*)&Ws[(j * 16 + ml) * 40 + quad * 8];
#pragma unroll
        for (int i = 0; i < 2; ++i)
#pragma unroll
            for (int j = 0; j < 4; ++j)
                acc[i][j] = __builtin_amdgcn_mfma_f32_16x16x32_bf16(
                    af[i], bfr[j], acc[i][j], 0, 0, 0);
        __syncthreads();
    }

#pragma unroll
    for (int i = 0; i < 2; ++i)
#pragma unroll
        for (int j = 0; j < 4; ++j)
#pragma unroll
            for (int r = 0; r < 4; ++r) {
                int m = m0 + wm + i * 16 + quad * 4 + r;
                int n = j * 16 + ml;
                if (m < M_ && n < 56)
                    C[(size_t)m * 56 + n] = acc[i][j][r];
            }
}

// ===== fused dual-direction causal depthwise conv (K=4) + bias + silu =====
// One thread per (b, channel-pair, t-chunk); sliding 4-row register window.
// Window rows t-3..t serve dir0 output at t (taps in order) AND dir1 output
// at s1 = L+2-t (taps reversed). Weights loaded once per thread (amortized).
__global__ __launch_bounds__(384) void conv_fused_kernel(
    const u16* __restrict__ xz, const float* __restrict__ cw_l,
    const float* __restrict__ cb_l, u16* __restrict__ xc2)
{
    int dp = threadIdx.x;          // 0..383 channel pair
    int d = dp * 2;
    int blk = blockIdx.x;          // B_ * CNCH
    int b = blk / CNCH, c = blk % CNCH;
    int t0 = c * CTL;
    int t1 = t0 + CTL; if (t1 > L_ + 3) t1 = L_ + 3;
    size_t mb = (size_t)b * L_;
    u16* xc0 = xc2;
    u16* xc1 = xc2 + (size_t)M_ * DI_;

    float w0[2][4], w1[2][4];
    {
        float4 a = *(const float4*)&cw_l[d * 4];
        float4 bq = *(const float4*)&cw_l[d * 4 + 4];
        w0[0][0] = a.x; w0[0][1] = a.y; w0[0][2] = a.z; w0[0][3] = a.w;
        w0[1][0] = bq.x; w0[1][1] = bq.y; w0[1][2] = bq.z; w0[1][3] = bq.w;
        float4 e = *(const float4*)&cw_l[DI_ * 4 + d * 4];
        float4 f = *(const float4*)&cw_l[DI_ * 4 + d * 4 + 4];
        w1[0][0] = e.x; w1[0][1] = e.y; w1[0][2] = e.z; w1[0][3] = e.w;
        w1[1][0] = f.x; w1[1][1] = f.y; w1[1][2] = f.z; w1[1][3] = f.w;
    }
    float b00 = cb_l[d], b01 = cb_l[d + 1];
    float b10 = cb_l[DI_ + d], b11 = cb_l[DI_ + d + 1];

    unsigned win[4];
#pragma unroll
    for (int m = 0; m < 3; ++m) {
        int r = t0 - 3 + m;
        win[m] = (r >= 0 && r < L_) ?
            *(const unsigned*)&xz[(mb + r) * 1536 + d] : 0u;
    }

    for (int t = t0; t < t1; ++t) {
        win[3] = (t < L_) ? *(const unsigned*)&xz[(mb + t) * 1536 + d] : 0u;
        float x0[4], x1[4];
#pragma unroll
        for (int m = 0; m < 4; ++m) {
            x0[m] = __uint_as_float(win[m] << 16);
            x1[m] = __uint_as_float(win[m] & 0xffff0000u);
        }
        if (t < L_) {
            float a0 = b00 + w0[0][0] * x0[0] + w0[0][1] * x0[1]
                           + w0[0][2] * x0[2] + w0[0][3] * x0[3];
            float a1 = b01 + w0[1][0] * x1[0] + w0[1][1] * x1[1]
                           + w0[1][2] * x1[2] + w0[1][3] * x1[3];
            unsigned o = (unsigned)f2bf(silu_f(a0)) | ((unsigned)f2bf(silu_f(a1)) << 16);
            *(unsigned*)&xc0[(mb + t) * DI_ + d] = o;
        }
        if (t >= 3) {
            int s1 = L_ + 2 - t;   // in [0, L) for t in [3, L+2]
            float a0 = b10 + w1[0][3] * x0[0] + w1[0][2] * x0[1]
                           + w1[0][1] * x0[2] + w1[0][0] * x0[3];
            float a1 = b11 + w1[1][3] * x1[0] + w1[1][2] * x1[1]
                           + w1[1][1] * x1[2] + w1[1][0] * x1[3];
            unsigned o = (unsigned)f2bf(silu_f(a0)) | ((unsigned)f2bf(silu_f(a1)) << 16);
            *(unsigned*)&xc1[(mb + s1) * DI_ + d] = o;
        }
        win[0] = win[1]; win[1] = win[2]; win[2] = win[3];
    }
}

// ================= segmented selective scan (both dirs per launch) ==========
__device__ __forceinline__ float dt_delta(
    const float* __restrict__ row, const float* W, float bias)
{
    float s = bias;
    const float4* pd = reinterpret_cast<const float4*>(row);
#pragma unroll
    for (int r = 0; r < 6; ++r) {
        float4 d4 = pd[r];
        s += W[4 * r + 0] * d4.x + W[4 * r + 1] * d4.y
           + W[4 * r + 2] * d4.z + W[4 * r + 3] * d4.w;
    }
    return (s > 20.f) ? s : __logf(1.f + __expf(s));
}

// grid (B_*3*SEG, 2) blocks of 256: 4 waves = 4 d-blocks. A pre-scaled by log2e.
// P computed algebraically: P[n] = exp2(A[n] * sum(dl)).
template<int STORE_D>
__global__ __launch_bounds__(256) void scan_part1_kernel(
    const u16* __restrict__ xc2, const float* __restrict__ dbl2,
    const float* __restrict__ dtW_l, const float* __restrict__ dtb_l,
    const float* __restrict__ Alog_l,
    u16* __restrict__ P_buf, u16* __restrict__ q_buf, u16* __restrict__ delta2)
{
    int dir = blockIdx.y;
    const u16* xc = xc2 + (size_t)dir * M_ * DI_;
    const float* dbl = dbl2 + (size_t)dir * M_ * 56;
    const float* dtW = dtW_l + (size_t)dir * DI_ * DTR_;
    const float* dtb = dtb_l + (size_t)dir * DI_;
    const float* Alog = Alog_l + (size_t)dir * DI_ * DS_;
    u16* dout = delta2 + (size_t)dir * M_ * DI_;

    int tid = threadIdx.x;
    int wave = tid >> 6, lane = tid & 63;
    int s = blockIdx.x % SEG;
    int bq = blockIdx.x / SEG;
    int b = bq / 3, dq = bq % 3;
    int dblk = dq * 4 + wave;
    int d = dblk * 64 + lane;
    size_t mb = (size_t)b * L_;
    int t0 = s * TL;
    int t1 = (t0 + TL < L_) ? (t0 + TL) : L_;

    float A[16];
    {
        const float4* ap = reinterpret_cast<const float4*>(Alog + (size_t)d * 16);
#pragma unroll
        for (int i = 0; i < 4; ++i) {
            float4 a4 = ap[i];
            A[4 * i + 0] = -LOG2E * __expf(a4.x); A[4 * i + 1] = -LOG2E * __expf(a4.y);
            A[4 * i + 2] = -LOG2E * __expf(a4.z); A[4 * i + 3] = -LOG2E * __expf(a4.w);
        }
    }
    float W[24];
    {
        const float4* wp = reinterpret_cast<const float4*>(dtW + (size_t)d * 24);
#pragma unroll
        for (int i = 0; i < 6; ++i) {
            float4 w4 = wp[i];
            W[4 * i + 0] = w4.x; W[4 * i + 1] = w4.y;
            W[4 * i + 2] = w4.z; W[4 * i + 3] = w4.w;
        }
    }
    float bias = dtb[d];
    float h[16];
    float S = 0.f;
#pragma unroll
    for (int i = 0; i < 16; ++i) h[i] = 0.f;

    for (int t = t0; t < t1; ++t) {
        const float* row = dbl + (mb + t) * 56;
        float dl = dt_delta(row, W, bias);
        if (STORE_D) dout[(mb + t) * DI_ + d] = f2bf(dl);
        S += dl;
        float xv = bf2f(xc[(mb + t) * DI_ + d]);
        float dlxv = dl * xv;
        const float4* pb = reinterpret_cast<const float4*>(row + 24);
#pragma unroll
        for (int j = 0; j < 4; ++j) {
            float4 B4 = pb[j];
            float e0 = __builtin_amdgcn_exp2f(dl * A[4 * j + 0]);
            float e1 = __builtin_amdgcn_exp2f(dl * A[4 * j + 1]);
            float e2 = __builtin_amdgcn_exp2f(dl * A[4 * j + 2]);
            float e3 = __builtin_amdgcn_exp2f(dl * A[4 * j + 3]);
            h[4 * j + 0] = e0 * h[4 * j + 0] + dlxv * B4.x;
            h[4 * j + 1] = e1 * h[4 * j + 1] + dlxv * B4.y;
            h[4 * j + 2] = e2 * h[4 * j + 2] + dlxv * B4.z;
            h[4 * j + 3] = e3 * h[4 * j + 3] + dlxv * B4.w;
        }
    }
    int bd = b * 12 + dblk;
    size_t base = ((size_t)dir * SGRID + (size_t)bd * SEG + s) * 16 * 64 + lane;
#pragma unroll
    for (int n = 0; n < 16; ++n) {
        P_buf[base + (size_t)n * 64] = f2bf(__builtin_amdgcn_exp2f(A[n] * S));
        q_buf[base + (size_t)n * 64] = f2bf(h[n]);
    }
}

// Phase 2: grid (192, 4, 2): y = state quad, z = dir.
__global__ __launch_bounds__(64) void scan_combine_kernel(
    const u16* __restrict__ P_buf, u16* __restrict__ q_buf)
{
    int lane = threadIdx.x;
    int bd = blockIdx.x;
    int nq = blockIdx.y;
    size_t dbase = (size_t)blockIdx.z * SGRID * 16 * 64;
    float h[4] = {0.f, 0.f, 0.f, 0.f};
    for (int s = 0; s < SEG; ++s) {
        size_t base = dbase + ((size_t)(bd * SEG + s) * 16 + nq * 4) * 64 + lane;
#pragma unroll
        for (int n = 0; n < 4; ++n) {
            size_t idx = base + (size_t)n * 64;
            float Pv = bf2f(P_buf[idx]);
            float qv = bf2f(q_buf[idx]);
            q_buf[idx] = f2bf(h[n]);
            h[n] = Pv * h[n] + qv;
        }
    }
}

// Phase 3: rescan from true hin; dir0 -> y0, dir1 -> y1.
template<int USE_D>
__global__ __launch_bounds__(256) void scan_part3_kernel(
    const u16* __restrict__ xc2, const float* __restrict__ dbl2,
    const u16* __restrict__ xz, const float* __restrict__ dtW_l,
    const float* __restrict__ dtb_l, const float* __restrict__ Alog_l,
    const float* __restrict__ Dp_l, const u16* __restrict__ q_buf,
    u16* __restrict__ y0, u16* __restrict__ y1, const u16* __restrict__ delta2)
{
    int dir = blockIdx.y;
    const u16* xc = xc2 + (size_t)dir * M_ * DI_;
    const float* dbl = dbl2 + (size_t)dir * M_ * 56;
    const float* Alog = Alog_l + (size_t)dir * DI_ * DS_;
    const float* Dp = Dp_l + (size_t)dir * DI_;
    const u16* din = delta2 + (size_t)dir * M_ * DI_;
    u16* yb = dir ? y1 : y0;

    int tid = threadIdx.x;
    int wave = tid >> 6, lane = tid & 63;
    int s = blockIdx.x % SEG;
    int bq = blockIdx.x / SEG;
    int b = bq / 3, dq = bq % 3;
    int dblk = dq * 4 + wave;
    int d = dblk * 64 + lane;
    size_t mb = (size_t)b * L_;
    int t0 = s * TL;
    int t1 = (t0 + TL < L_) ? (t0 + TL) : L_;

    float A[16];
    {
        const float4* ap = reinterpret_cast<const float4*>(Alog + (size_t)d * 16);
#pragma unroll
        for (int i = 0; i < 4; ++i) {
            float4 a4 = ap[i];
            A[4 * i + 0] = -LOG2E * __expf(a4.x); A[4 * i + 1] = -LOG2E * __expf(a4.y);
            A[4 * i + 2] = -LOG2E * __expf(a4.z); A[4 * i + 3] = -LOG2E * __expf(a4.w);
        }
    }
    float W[24];
    float bias = 0.f;
    if (!USE_D) {
        const float* dtW = dtW_l + (size_t)dir * DI_ * DTR_;
        const float4* wp = reinterpret_cast<const float4*>(dtW + (size_t)d * 24);
#pragma unroll
        for (int i = 0; i < 6; ++i) {
            float4 w4 = wp[i];
            W[4 * i + 0] = w4.x; W[4 * i + 1] = w4.y;
            W[4 * i + 2] = w4.z; W[4 * i + 3] = w4.w;
        }
        bias = (dtb_l + (size_t)dir * DI_)[d];
    }
    float Dval = Dp[d];
    int bd = b * 12 + dblk;
    float h[16];
    {
        size_t base = ((size_t)dir * SGRID + (size_t)bd * SEG + s) * 16 * 64 + lane;
#pragma unroll
        for (int n = 0; n < 16; ++n) h[n] = bf2f(q_buf[base + (size_t)n * 64]);
    }

    for (int t = t0; t < t1; ++t) {
        const float* row = dbl + (mb + t) * 56;
        float dl;
        if (USE_D) dl = bf2f(din[(mb + t) * DI_ + d]);
        else       dl = dt_delta(row, W, bias);
        float xv = bf2f(xc[(mb + t) * DI_ + d]);
        float dlxv = dl * xv;
        const float4* pb = reinterpret_cast<const float4*>(row + 24);
        const float4* pc = reinterpret_cast<const float4*>(row + 40);
        float a0 = 0.f, a1 = 0.f, a2 = 0.f, a3 = 0.f;
#pragma unroll
        for (int j = 0; j < 4; ++j) {
            float4 B4 = pb[j], C4 = pc[j];
            float e0 = __builtin_amdgcn_exp2f(dl * A[4 * j + 0]);
            float e1 = __builtin_amdgcn_exp2f(dl * A[4 * j + 1]);
            float e2 = __builtin_amdgcn_exp2f(dl * A[4 * j + 2]);
            float e3 = __builtin_amdgcn_exp2f(dl * A[4 * j + 3]);
            h[4 * j + 0] = e0 * h[4 * j + 0] + dlxv * B4.x;
            h[4 * j + 1] = e1 * h[4 * j + 1] + dlxv * B4.y;
            h[4 * j + 2] = e2 * h[4 * j + 2] + dlxv * B4.z;
            h[4 * j + 3] = e3 * h[4 * j + 3] + dlxv * B4.w;
            a0 += h[4 * j + 0] * C4.x;
            a1 += h[4 * j + 1] * C4.y;
            a2 += h[4 * j + 2] * C4.z;
            a3 += h[4 * j + 3] * C4.w;
        }
        float y = (a0 + a1) + (a2 + a3) + xv * Dval;
        int lorig = dir ? (L_ - 1 - t) : t;
        y *= silu_f(bf2f(xz[(mb + lorig) * 1536 + 768 + d]));
        yb[(mb + lorig) * DI_ + d] = f2bf(y);
    }
}

// final: residual+hidden, rmsnorm, permute+slice, store bf16 or f32 per flag
__global__ __launch_bounds__(128) void final_kernel(
    const float* __restrict__ hidden, const float* __restrict__ resid,
    const float* __restrict__ w, void* __restrict__ out,
    const int* __restrict__ bad)
{
    int blk = blockIdx.x;
    int b = blk / 446, tok = blk % 446;
    int lorig; size_t dst;
    if (tok == 0)      { lorig = 247; dst = (size_t)b * D_; }
    else if (tok <= 14){ int j = tok - 1; lorig = 49 + j; dst = 6144 + ((size_t)b * 14 + j) * D_; }
    else               { int v = tok - 15; lorig = (v < 184) ? (63 + v) : (64 + v);
                         dst = 92160 + ((size_t)b * 431 + v) * D_; }
    size_t base = ((size_t)b * L_ + lorig) * D_;
    int tid = threadIdx.x;
    float v3[3]; float ss = 0.f;
#pragma unroll
    for (int i = 0; i < 3; ++i) {
        int c = tid + i * 128;
        float r = hidden[base + c] + resid[base + c];
        v3[i] = r; ss += r * r;
    }
    ss += __shfl_xor(ss, 32); ss += __shfl_xor(ss, 16); ss += __shfl_xor(ss, 8);
    ss += __shfl_xor(ss, 4);  ss += __shfl_xor(ss, 2);  ss += __shfl_xor(ss, 1);
    __shared__ float sred[2];
    if ((tid & 63) == 0) sred[tid >> 6] = ss;
    __syncthreads();
    float scale = rsqrtf((sred[0] + sred[1]) * (1.f / D_) + 1e-5f);
    int isbf = (*bad == 0);
#pragma unroll
    for (int i = 0; i < 3; ++i) {
        int c = tid + i * 128;
        float val = v3[i] * scale * w[c];
        if (isbf) ((u16*)out)[dst + c] = f2bf(val);
        else      ((float*)out)[dst + c] = val;
    }
}

extern "C" void kernel_launch(void* const* d_in, const int* in_sizes, int n_in,
                              void* d_out, int out_size, void* d_ws, size_t ws_size,
                              hipStream_t stream) {
    char* wsb = (char*)d_ws;
    int* bad = (int*)wsb;  wsb += 16;

    // canon (11): inW(bf16), cW, cB, xpW(bf16), dtW, dtB, Alog, Dsk, outW(bf16), nw, fnw
    const int cn[11] = {2359296, 24576, 6144, 344064, 147456, 6144, 98304,
                        6144, 1179648, 1536, 384};
    const int raw_idx[11] = {4, 5, 6, 7, 8, 9, 10, 11, 12, 13, 14};
    const int tobf[11]    = {1, 0, 0, 1, 0, 0, 0, 0, 1, 0, 0};
    void* canon[11];
    for (int i = 0; i < 11; ++i) {
        canon[i] = (void*)wsb;
        wsb += (size_t)cn[i] * (tobf[i] ? 2 : 4);
    }
    const u16*   inWb = (const u16*)canon[0];
    const float* cW   = (const float*)canon[1];
    const float* cB   = (const float*)canon[2];
    const u16*   xpWb = (const u16*)canon[3];
    const float* dtW  = (const float*)canon[4];
    const float* dtB  = (const float*)canon[5];
    const float* Alog = (const float*)canon[6];
    const float* Dsk  = (const float*)canon[7];
    const u16*   outWb= (const u16*)canon[8];
    const float* nw   = (const float*)canon[9];
    const float* fnw  = (const float*)canon[10];

    float* hidden = (float*)wsb;  wsb += (size_t)M_ * D_ * 4;
    float* resid  = (float*)wsb;  wsb += (size_t)M_ * D_ * 4;
    float* dbl2   = (float*)wsb;  wsb += (size_t)2 * M_ * 56 * 4;
    u16*   xz     = (u16*)wsb;    wsb += (size_t)M_ * 1536 * 2;
    u16*   xc2    = (u16*)wsb;    wsb += (size_t)2 * M_ * DI_ * 2;
    u16*   y0     = (u16*)wsb;    wsb += (size_t)M_ * DI_ * 2;           // hbf aliases
    u16*   P_buf  = (u16*)wsb;    wsb += (size_t)2 * SGRID * 16 * 64 * 2; // y1 aliases
    u16*   q_buf  = (u16*)wsb;    wsb += (size_t)2 * SGRID * 16 * 64 * 2;
    u16*   delta2 = (u16*)wsb;    wsb += (size_t)2 * M_ * DI_ * 2;       // optional, +24.3MB
    u16* hbf = y0;
    u16* y1  = P_buf;
    int use_delta = ((size_t)(wsb - (char*)d_ws) <= ws_size);

    hipMemsetAsync(bad, 0, 4, stream);
    detect_kernel<<<384, 256, 0, stream>>>((const u16*)d_in[10], bad);
    {
        CvtArgs ca;
        int maxn = 0;
        for (int i = 0; i < 11; ++i) {
            ca.src[i] = d_in[raw_idx[i]]; ca.dst[i] = canon[i];
            ca.n[i] = cn[i]; ca.tobf[i] = tobf[i];
            if (cn[i] > maxn) maxn = cn[i];
        }
        cvt_all_kernel<<<dim3((maxn + 255) / 256, 11), 256, 0, stream>>>(ca, bad);
    }

    build_hidden_kernel<<<(M_ * D_) / 256, 256, 0, stream>>>(
        d_in[0], d_in[2], d_in[3], hidden, bad);

    const int gmb = (M_ + 127) / 128;      // 62
    for (int l = 0; l < 4; ++l) {
        const float* dtWl = dtW + (size_t)l * 2 * DI_ * DTR_;
        const float* dtBl = dtB + (size_t)l * 2 * DI_;
        const float* All  = Alog + (size_t)l * 2 * DI_ * DS_;
        const float* Dl   = Dsk + (size_t)l * 2 * DI_;
        resnorm_kernel<<<M_, 128, 0, stream>>>(hidden, resid, nw + (size_t)l * D_, hbf, l == 0);
        gemm_mfma_bt<0, 0><<<dim3(gmb, 1536 / 128), 256, 0, stream>>>(
            hbf, nullptr, inWb + (size_t)l * 1536 * D_, xz, M_, 1536, D_, 1536, 1.f);
        conv_fused_kernel<<<B_ * CNCH, 384, 0, stream>>>(
            xz, cW + (size_t)l * 2 * DI_ * 4, cB + (size_t)l * 2 * DI_, xc2);
        xproj_gemm_kernel<<<dim3(gmb, 2), 256, 0, stream>>>(
            xc2, xpWb + (size_t)l * 2 * 56 * DI_, dbl2);
        if (use_delta)
            scan_part1_kernel<1><<<dim3(B_ * 3 * SEG, 2), 256, 0, stream>>>(
                xc2, dbl2, dtWl, dtBl, All, P_buf, q_buf, delta2);
        else
            scan_part1_kernel<0><<<dim3(B_ * 3 * SEG, 2), 256, 0, stream>>>(
                xc2, dbl2, dtWl, dtBl, All, P_buf, q_buf, delta2);
        scan_combine_kernel<<<dim3(NBD, 4, 2), 64, 0, stream>>>(P_buf, q_buf);
        if (use_delta)
            scan_part3_kernel<1><<<dim3(B_ * 3 * SEG, 2), 256, 0, stream>>>(
                xc2, dbl2, xz, dtWl, dtBl, All, Dl, q_buf, y0, y1, delta2);
        else
            scan_part3_kernel<0><<<dim3(B_ * 3 * SEG, 2), 256, 0, stream>>>(
                xc2, dbl2, xz, dtWl, dtBl, All, Dl, q_buf, y0, y1, delta2);
        gemm_mfma_bt<1, 1><<<dim3(gmb, 384 / 128), 256, 0, stream>>>(
            y0, y1, outWb + (size_t)l * D_ * DI_, hidden, M_, 384, DI_, 384, 0.5f);
    }

    final_kernel<<<B_ * 446, 128, 0, stream>>>(hidden, resid, fnw, d_out, bad);
}

// Round 13
// 1008.058 us; speedup vs baseline: 5.8002x; 1.0091x over previous
//
#include <hip/hip_runtime.h>

typedef unsigned short u16;
typedef __attribute__((ext_vector_type(8))) short short8;
typedef __attribute__((ext_vector_type(4))) float float4v;

#define B_   16
#define L_   495
#define D_   384
#define DI_  768
#define DS_  16
#define DTR_ 24
#define SEG  16
#define TL   31   // ceil(495/16)
#define M_   (B_ * L_)
#define NBD  (B_ * 12)            // 192 (b,d-block) pairs
#define SGRID (NBD * SEG)         // 3072 flat scan units per dir
#define LOG2E 1.44269504f
#define CNCH 15
#define CTL  34   // 15*34 = 510 >= 498 (t in [0, L+3))

__device__ __forceinline__ float bf2f(u16 u) {
    return __uint_as_float(((unsigned)u) << 16);
}
__device__ __forceinline__ u16 f2bf(float f) {
    unsigned u = __float_as_uint(f);
    unsigned r = 0x7fffu + ((u >> 16) & 1u);
    return (u16)((u + r) >> 16);
}
__device__ __forceinline__ float silu_f(float x) {
    return x / (1.f + __expf(-x));
}

// ---- dtype detector (parallel): A_log in [0,2.78] as bf16 => bad==0 -> bf16.
__global__ __launch_bounds__(256) void detect_kernel(
    const u16* __restrict__ alog_raw, int* __restrict__ bad)
{
    int i = blockIdx.x * 256 + threadIdx.x;   // grid 384 -> 98304
    float v = bf2f(alog_raw[i]);
    int b = !(v >= -1e-3f && v <= 2.8f);
    unsigned long long m = __ballot(b);
    if ((threadIdx.x & 63) == 0 && m) atomicAdd(bad, (int)__popcll(m));
}

// ---- batched convert (blockIdx.y = tensor). tobf: emit bf16 instead of f32.
struct CvtArgs {
    const void* src[11];
    void* dst[11];
    int n[11];
    int tobf[11];
};
__global__ __launch_bounds__(256) void cvt_all_kernel(CvtArgs a, const int* __restrict__ bad)
{
    int t = blockIdx.y;
    int i = blockIdx.x * 256 + threadIdx.x;
    if (i >= a.n[t]) return;
    int isbf = (*bad == 0);
    if (a.tobf[t]) {
        u16 v = isbf ? ((const u16*)a.src[t])[i] : f2bf(((const float*)a.src[t])[i]);
        ((u16*)a.dst[t])[i] = v;
    } else {
        float v = isbf ? bf2f(((const u16*)a.src[t])[i]) : ((const float*)a.src[t])[i];
        ((float*)a.dst[t])[i] = v;
    }
}

// hidden[b,l,c] = concat(cjv[:247], cls, cjv[247:]) + pos_embed  (raw inputs)
__global__ __launch_bounds__(256) void build_hidden_kernel(
    const void* __restrict__ cjv, const void* __restrict__ cls,
    const void* __restrict__ pos, float* __restrict__ hidden,
    const int* __restrict__ bad)
{
    int isbf = (*bad == 0);
    int i = blockIdx.x * 256 + threadIdx.x;
    int c = i % D_;
    int l = (i / D_) % L_;
    int b = i / (D_ * L_);
    size_t si;
    const void* sp;
    if (l < 247)       { sp = cjv; si = ((size_t)b * 494 + l) * D_ + c; }
    else if (l == 247) { sp = cls; si = c; }
    else               { sp = cjv; si = ((size_t)b * 494 + (l - 1)) * D_ + c; }
    float v = isbf ? bf2f(((const u16*)sp)[si]) : ((const float*)sp)[si];
    size_t pi = (size_t)l * D_ + c;
    float p = isbf ? bf2f(((const u16*)pos)[pi]) : ((const float*)pos)[pi];
    hidden[i] = v + p;
}

// resid = hidden (+ resid); hbf <- bf16(rmsnorm(resid)*w)
__global__ __launch_bounds__(128) void resnorm_kernel(
    const float* __restrict__ hidden, float* __restrict__ resid,
    const float* __restrict__ w, u16* __restrict__ hbf, int first)
{
    int m = blockIdx.x, tid = threadIdx.x;
    size_t base = (size_t)m * D_;
    float v[3]; float ss = 0.f;
#pragma unroll
    for (int i = 0; i < 3; ++i) {
        int c = tid + i * 128;
        float r = hidden[base + c];
        if (!first) r += resid[base + c];
        resid[base + c] = r;
        v[i] = r; ss += r * r;
    }
    ss += __shfl_xor(ss, 32); ss += __shfl_xor(ss, 16); ss += __shfl_xor(ss, 8);
    ss += __shfl_xor(ss, 4);  ss += __shfl_xor(ss, 2);  ss += __shfl_xor(ss, 1);
    __shared__ float sred[2];
    if ((tid & 63) == 0) sred[tid >> 6] = ss;
    __syncthreads();
    float scale = rsqrtf((sred[0] + sred[1]) * (1.f / D_) + 1e-5f);
#pragma unroll
    for (int i = 0; i < 3; ++i) {
        int c = tid + i * 128;
        hbf[base + c] = f2bf(v[i] * scale * w[c]);
    }
}

// ===== MFMA GEMM: C(M,N) = alpha * (A [+ A2])(M,K)bf16 @ W(N,K)bf16^T =====
template<int CF32, int SUM2>
__global__ __launch_bounds__(256) void gemm_mfma_bt(
    const u16* __restrict__ A, const u16* __restrict__ A2,
    const u16* __restrict__ W, void* __restrict__ Cv,
    int M, int N, int K, int ldc, float alpha)
{
    __shared__ __align__(16) u16 As[128 * 40];
    __shared__ __align__(16) u16 Ws[128 * 40];
    int tid = threadIdx.x;
    int wave = tid >> 6, lane = tid & 63;
    int m0 = blockIdx.x * 128, n0 = blockIdx.y * 128;
    int wm = (wave >> 1) * 64, wn = (wave & 1) * 64;
    int ml = lane & 15, quad = lane >> 4;

    float4v acc[4][4];
#pragma unroll
    for (int i = 0; i < 4; ++i)
#pragma unroll
        for (int j = 0; j < 4; ++j)
#pragma unroll
            for (int r = 0; r < 4; ++r) acc[i][j][r] = 0.f;

    int srow = tid >> 2;
    int scol = (tid & 3) * 8;

    for (int k0 = 0; k0 < K; k0 += 32) {
#pragma unroll
        for (int p = 0; p < 2; ++p) {
            int row = srow + p * 64;
            int gm = m0 + row; if (gm >= M) gm = M - 1;
            if (SUM2) {
                short8 a0 = *(const short8*)(A  + (size_t)gm * K + k0 + scol);
                short8 a1 = *(const short8*)(A2 + (size_t)gm * K + k0 + scol);
                u16 tmp[8];
#pragma unroll
                for (int r = 0; r < 8; ++r)
                    tmp[r] = f2bf(bf2f((u16)a0[r]) + bf2f((u16)a1[r]));
                *(uint4*)&As[row * 40 + scol] = *(const uint4*)tmp;
            } else {
                *(uint4*)&As[row * 40 + scol] =
                    *(const uint4*)(A + (size_t)gm * K + k0 + scol);
            }
            int gn = n0 + row;
            *(uint4*)&Ws[row * 40 + scol] =
                *(const uint4*)(W + (size_t)gn * K + k0 + scol);
        }
        __syncthreads();
        short8 af[4], bfr[4];
#pragma unroll
        for (int i = 0; i < 4; ++i) {
            af[i]  = *(const short8*)&As[(wm + i * 16 + ml) * 40 + quad * 8];
            bfr[i] = *(const short8*)&Ws[(wn + i * 16 + ml) * 40 + quad * 8];
        }
#pragma unroll
        for (int i = 0; i < 4; ++i)
#pragma unroll
            for (int j = 0; j < 4; ++j)
                acc[i][j] = __builtin_amdgcn_mfma_f32_16x16x32_bf16(
                    af[i], bfr[j], acc[i][j], 0, 0, 0);
        __syncthreads();
    }

#pragma unroll
    for (int i = 0; i < 4; ++i)
#pragma unroll
        for (int j = 0; j < 4; ++j)
#pragma unroll
            for (int r = 0; r < 4; ++r) {
                int m = m0 + wm + i * 16 + quad * 4 + r;
                if (m >= M) continue;
                int n = n0 + wn + j * 16 + ml;
                float val = alpha * acc[i][j][r];
                if (CF32) ((float*)Cv)[(size_t)m * ldc + n] = val;
                else      ((u16*)Cv)[(size_t)m * ldc + n] = f2bf(val);
            }
}

// ===== xproj MFMA GEMM: dbl2[dir](m,56) = xc2[dir](M,768) @ xpWb[dir](56,768)^T
__global__ __launch_bounds__(256) void xproj_gemm_kernel(
    const u16* __restrict__ xc2, const u16* __restrict__ xpWb_l,
    float* __restrict__ dbl2)
{
    int dir = blockIdx.y;
    const u16* A = xc2 + (size_t)dir * M_ * DI_;
    const u16* W = xpWb_l + (size_t)dir * 56 * DI_;
    float* C = dbl2 + (size_t)dir * M_ * 56;

    __shared__ __align__(16) u16 As[128 * 40];
    __shared__ __align__(16) u16 Ws[64 * 40];
    int tid = threadIdx.x;
    int wave = tid >> 6, lane = tid & 63;
    int m0 = blockIdx.x * 128;
    int wm = wave * 32;
    int ml = lane & 15, quad = lane >> 4;

    float4v acc[2][4];
#pragma unroll
    for (int i = 0; i < 2; ++i)
#pragma unroll
        for (int j = 0; j < 4; ++j)
#pragma unroll
            for (int r = 0; r < 4; ++r) acc[i][j][r] = 0.f;

    int srow = tid >> 2;
    int scol = (tid & 3) * 8;

    for (int k0 = 0; k0 < DI_; k0 += 32) {
#pragma unroll
        for (int p = 0; p < 2; ++p) {
            int row = srow + p * 64;
            int gm = m0 + row; if (gm >= M_) gm = M_ - 1;
            *(uint4*)&As[row * 40 + scol] =
                *(const uint4*)(A + (size_t)gm * DI_ + k0 + scol);
        }
        *(uint4*)&Ws[srow * 40 + scol] =
            *(const uint4*)(W + (size_t)srow * DI_ + k0 + scol);
        __syncthreads();
        short8 af[2], bfr[4];
#pragma unroll
        for (int i = 0; i < 2; ++i)
            af[i] = *(const short8*)&As[(wm + i * 16 + ml) * 40 + quad * 8];
#pragma unroll
        for (int j = 0; j < 4; ++j)
            bfr[j] = *(const short8*)&Ws[(j * 16 + ml) * 40 + quad * 8];
#pragma unroll
        for (int i = 0; i < 2; ++i)
#pragma unroll
            for (int j = 0; j < 4; ++j)
                acc[i][j] = __builtin_amdgcn_mfma_f32_16x16x32_bf16(
                    af[i], bfr[j], acc[i][j], 0, 0, 0);
        __syncthreads();
    }

#pragma unroll
    for (int i = 0; i < 2; ++i)
#pragma unroll
        for (int j = 0; j < 4; ++j)
#pragma unroll
            for (int r = 0; r < 4; ++r) {
                int m = m0 + wm + i * 16 + quad * 4 + r;
                int n = j * 16 + ml;
                if (m < M_ && n < 56)
                    C[(size_t)m * 56 + n] = acc[i][j][r];
            }
}

// ===== dtproj MFMA GEMM: delta2[dir](M,768) = softplus(dt(M,24)@dtW(768,24)^T + dtb)
// K padded 24->32 with zeros; single K-step; softplus epilogue; bf16 out.
__global__ __launch_bounds__(256) void dtproj_gemm_kernel(
    const float* __restrict__ dbl2, const float* __restrict__ dtW_l,
    const float* __restrict__ dtb_l, u16* __restrict__ delta2)
{
    int dir = blockIdx.z;
    const float* dbl = dbl2 + (size_t)dir * M_ * 56;
    const float* dtW = dtW_l + (size_t)dir * DI_ * DTR_;
    const float* dtb = dtb_l + (size_t)dir * DI_;
    u16* dout = delta2 + (size_t)dir * M_ * DI_;

    __shared__ __align__(16) u16 As[128 * 40];
    __shared__ __align__(16) u16 Ws[128 * 40];
    int tid = threadIdx.x;
    int wave = tid >> 6, lane = tid & 63;
    int m0 = blockIdx.x * 128, n0 = blockIdx.y * 128;
    int wm = (wave >> 1) * 64, wn = (wave & 1) * 64;
    int ml = lane & 15, quad = lane >> 4;

    // stage A (dt cols of dbl rows) and W (dtW rows), pad K 24->32 with zeros
    {
        int r = tid >> 1, hh = tid & 1;
        int gm = m0 + r; if (gm >= M_) gm = M_ - 1;
        const float* srcA = dbl + (size_t)gm * 56 + hh * 12;
        const float* srcW = dtW + (size_t)(n0 + r) * DTR_ + hh * 12;
#pragma unroll
        for (int i = 0; i < 6; ++i) {
            unsigned a = (unsigned)f2bf(srcA[2 * i]) | ((unsigned)f2bf(srcA[2 * i + 1]) << 16);
            unsigned w = (unsigned)f2bf(srcW[2 * i]) | ((unsigned)f2bf(srcW[2 * i + 1]) << 16);
            *(unsigned*)&As[r * 40 + hh * 12 + 2 * i] = a;
            *(unsigned*)&Ws[r * 40 + hh * 12 + 2 * i] = w;
        }
        if (hh) {   // zero pad cols 24..31  (byte offset r*80+48, 16B aligned)
            *(uint4*)&As[r * 40 + 24] = make_uint4(0, 0, 0, 0);
            *(uint4*)&Ws[r * 40 + 24] = make_uint4(0, 0, 0, 0);
        }
    }
    __syncthreads();

    float4v acc[4][4];
#pragma unroll
    for (int i = 0; i < 4; ++i)
#pragma unroll
        for (int j = 0; j < 4; ++j)
#pragma unroll
            for (int r = 0; r < 4; ++r) acc[i][j][r] = 0.f;

    short8 af[4], bfr[4];
#pragma unroll
    for (int i = 0; i < 4; ++i) {
        af[i]  = *(const short8*)&As[(wm + i * 16 + ml) * 40 + quad * 8];
        bfr[i] = *(const short8*)&Ws[(wn + i * 16 + ml) * 40 + quad * 8];
    }
#pragma unroll
    for (int i = 0; i < 4; ++i)
#pragma unroll
        for (int j = 0; j < 4; ++j)
            acc[i][j] = __builtin_amdgcn_mfma_f32_16x16x32_bf16(
                af[i], bfr[j], acc[i][j], 0, 0, 0);

#pragma unroll
    for (int i = 0; i < 4; ++i)
#pragma unroll
        for (int j = 0; j < 4; ++j) {
            int n = n0 + wn + j * 16 + ml;
            float bv = dtb[n];
#pragma unroll
            for (int r = 0; r < 4; ++r) {
                int m = m0 + wm + i * 16 + quad * 4 + r;
                if (m >= M_) continue;
                float s = acc[i][j][r] + bv;
                float dl = (s > 20.f) ? s : __logf(1.f + __expf(s));
                dout[(size_t)m * DI_ + n] = f2bf(dl);
            }
        }
}

// ===== fused dual-direction causal depthwise conv (K=4) + bias + silu =====
__global__ __launch_bounds__(384) void conv_fused_kernel(
    const u16* __restrict__ xz, const float* __restrict__ cw_l,
    const float* __restrict__ cb_l, u16* __restrict__ xc2)
{
    int dp = threadIdx.x;          // 0..383 channel pair
    int d = dp * 2;
    int blk = blockIdx.x;          // B_ * CNCH
    int b = blk / CNCH, c = blk % CNCH;
    int t0 = c * CTL;
    int t1 = t0 + CTL; if (t1 > L_ + 3) t1 = L_ + 3;
    size_t mb = (size_t)b * L_;
    u16* xc0 = xc2;
    u16* xc1 = xc2 + (size_t)M_ * DI_;

    float w0[2][4], w1[2][4];
    {
        float4 a = *(const float4*)&cw_l[d * 4];
        float4 bq = *(const float4*)&cw_l[d * 4 + 4];
        w0[0][0] = a.x; w0[0][1] = a.y; w0[0][2] = a.z; w0[0][3] = a.w;
        w0[1][0] = bq.x; w0[1][1] = bq.y; w0[1][2] = bq.z; w0[1][3] = bq.w;
        float4 e = *(const float4*)&cw_l[DI_ * 4 + d * 4];
        float4 f = *(const float4*)&cw_l[DI_ * 4 + d * 4 + 4];
        w1[0][0] = e.x; w1[0][1] = e.y; w1[0][2] = e.z; w1[0][3] = e.w;
        w1[1][0] = f.x; w1[1][1] = f.y; w1[1][2] = f.z; w1[1][3] = f.w;
    }
    float b00 = cb_l[d], b01 = cb_l[d + 1];
    float b10 = cb_l[DI_ + d], b11 = cb_l[DI_ + d + 1];

    unsigned win[4];
#pragma unroll
    for (int m = 0; m < 3; ++m) {
        int r = t0 - 3 + m;
        win[m] = (r >= 0 && r < L_) ?
            *(const unsigned*)&xz[(mb + r) * 1536 + d] : 0u;
    }

    for (int t = t0; t < t1; ++t) {
        win[3] = (t < L_) ? *(const unsigned*)&xz[(mb + t) * 1536 + d] : 0u;
        float x0[4], x1[4];
#pragma unroll
        for (int m = 0; m < 4; ++m) {
            x0[m] = __uint_as_float(win[m] << 16);
            x1[m] = __uint_as_float(win[m] & 0xffff0000u);
        }
        if (t < L_) {
            float a0 = b00 + w0[0][0] * x0[0] + w0[0][1] * x0[1]
                           + w0[0][2] * x0[2] + w0[0][3] * x0[3];
            float a1 = b01 + w0[1][0] * x1[0] + w0[1][1] * x1[1]
                           + w0[1][2] * x1[2] + w0[1][3] * x1[3];
            unsigned o = (unsigned)f2bf(silu_f(a0)) | ((unsigned)f2bf(silu_f(a1)) << 16);
            *(unsigned*)&xc0[(mb + t) * DI_ + d] = o;
        }
        if (t >= 3) {
            int s1 = L_ + 2 - t;
            float a0 = b10 + w1[0][3] * x0[0] + w1[0][2] * x0[1]
                           + w1[0][1] * x0[2] + w1[0][0] * x0[3];
            float a1 = b11 + w1[1][3] * x1[0] + w1[1][2] * x1[1]
                           + w1[1][1] * x1[2] + w1[1][0] * x1[3];
            unsigned o = (unsigned)f2bf(silu_f(a0)) | ((unsigned)f2bf(silu_f(a1)) << 16);
            *(unsigned*)&xc1[(mb + s1) * DI_ + d] = o;
        }
        win[0] = win[1]; win[1] = win[2]; win[2] = win[3];
    }
}

// ================= segmented selective scan (both dirs per launch) ==========
// Part 1: local scan consuming precomputed delta; P algebraic via sum(dl).
__global__ __launch_bounds__(256) void scan_part1_kernel(
    const u16* __restrict__ xc2, const float* __restrict__ dbl2,
    const u16* __restrict__ delta2, const float* __restrict__ Alog_l,
    u16* __restrict__ P_buf, u16* __restrict__ q_buf)
{
    int dir = blockIdx.y;
    const u16* xc = xc2 + (size_t)dir * M_ * DI_;
    const float* dbl = dbl2 + (size_t)dir * M_ * 56;
    const u16* din = delta2 + (size_t)dir * M_ * DI_;
    const float* Alog = Alog_l + (size_t)dir * DI_ * DS_;

    int tid = threadIdx.x;
    int wave = tid >> 6, lane = tid & 63;
    int s = blockIdx.x % SEG;
    int bq = blockIdx.x / SEG;
    int b = bq / 3, dq = bq % 3;
    int dblk = dq * 4 + wave;
    int d = dblk * 64 + lane;
    size_t mb = (size_t)b * L_;
    int t0 = s * TL;
    int t1 = (t0 + TL < L_) ? (t0 + TL) : L_;

    float A[16];
    {
        const float4* ap = reinterpret_cast<const float4*>(Alog + (size_t)d * 16);
#pragma unroll
        for (int i = 0; i < 4; ++i) {
            float4 a4 = ap[i];
            A[4 * i + 0] = -LOG2E * __expf(a4.x); A[4 * i + 1] = -LOG2E * __expf(a4.y);
            A[4 * i + 2] = -LOG2E * __expf(a4.z); A[4 * i + 3] = -LOG2E * __expf(a4.w);
        }
    }
    float h[16];
    float S = 0.f;
#pragma unroll
    for (int i = 0; i < 16; ++i) h[i] = 0.f;

    for (int t = t0; t < t1; ++t) {
        const float* row = dbl + (mb + t) * 56;
        float dl = bf2f(din[(mb + t) * DI_ + d]);
        S += dl;
        float xv = bf2f(xc[(mb + t) * DI_ + d]);
        float dlxv = dl * xv;
        const float4* pb = reinterpret_cast<const float4*>(row + 24);
#pragma unroll
        for (int j = 0; j < 4; ++j) {
            float4 B4 = pb[j];
            float e0 = __builtin_amdgcn_exp2f(dl * A[4 * j + 0]);
            float e1 = __builtin_amdgcn_exp2f(dl * A[4 * j + 1]);
            float e2 = __builtin_amdgcn_exp2f(dl * A[4 * j + 2]);
            float e3 = __builtin_amdgcn_exp2f(dl * A[4 * j + 3]);
            h[4 * j + 0] = e0 * h[4 * j + 0] + dlxv * B4.x;
            h[4 * j + 1] = e1 * h[4 * j + 1] + dlxv * B4.y;
            h[4 * j + 2] = e2 * h[4 * j + 2] + dlxv * B4.z;
            h[4 * j + 3] = e3 * h[4 * j + 3] + dlxv * B4.w;
        }
    }
    int bd = b * 12 + dblk;
    size_t base = ((size_t)dir * SGRID + (size_t)bd * SEG + s) * 16 * 64 + lane;
#pragma unroll
    for (int n = 0; n < 16; ++n) {
        P_buf[base + (size_t)n * 64] = f2bf(__builtin_amdgcn_exp2f(A[n] * S));
        q_buf[base + (size_t)n * 64] = f2bf(h[n]);
    }
}

// Phase 2: grid (192, 4, 2): y = state quad, z = dir.
__global__ __launch_bounds__(64) void scan_combine_kernel(
    const u16* __restrict__ P_buf, u16* __restrict__ q_buf)
{
    int lane = threadIdx.x;
    int bd = blockIdx.x;
    int nq = blockIdx.y;
    size_t dbase = (size_t)blockIdx.z * SGRID * 16 * 64;
    float h[4] = {0.f, 0.f, 0.f, 0.f};
    for (int s = 0; s < SEG; ++s) {
        size_t base = dbase + ((size_t)(bd * SEG + s) * 16 + nq * 4) * 64 + lane;
#pragma unroll
        for (int n = 0; n < 4; ++n) {
            size_t idx = base + (size_t)n * 64;
            float Pv = bf2f(P_buf[idx]);
            float qv = bf2f(q_buf[idx]);
            q_buf[idx] = f2bf(h[n]);
            h[n] = Pv * h[n] + qv;
        }
    }
}

// Phase 3: rescan from true hin; dir0 -> y0, dir1 -> y1. delta precomputed.
__global__ __launch_bounds__(256) void scan_part3_kernel(
    const u16* __restrict__ xc2, const float* __restrict__ dbl2,
    const u16* __restrict__ xz, const float* __restrict__ Alog_l,
    const float* __restrict__ Dp_l, const u16* __restrict__ q_buf,
    u16* __restrict__ y0, u16* __restrict__ y1, const u16* __restrict__ delta2)
{
    int dir = blockIdx.y;
    const u16* xc = xc2 + (size_t)dir * M_ * DI_;
    const float* dbl = dbl2 + (size_t)dir * M_ * 56;
    const float* Alog = Alog_l + (size_t)dir * DI_ * DS_;
    const float* Dp = Dp_l + (size_t)dir * DI_;
    const u16* din = delta2 + (size_t)dir * M_ * DI_;
    u16* yb = dir ? y1 : y0;

    int tid = threadIdx.x;
    int wave = tid >> 6, lane = tid & 63;
    int s = blockIdx.x % SEG;
    int bq = blockIdx.x / SEG;
    int b = bq / 3, dq = bq % 3;
    int dblk = dq * 4 + wave;
    int d = dblk * 64 + lane;
    size_t mb = (size_t)b * L_;
    int t0 = s * TL;
    int t1 = (t0 + TL < L_) ? (t0 + TL) : L_;

    float A[16];
    {
        const float4* ap = reinterpret_cast<const float4*>(Alog + (size_t)d * 16);
#pragma unroll
        for (int i = 0; i < 4; ++i) {
            float4 a4 = ap[i];
            A[4 * i + 0] = -LOG2E * __expf(a4.x); A[4 * i + 1] = -LOG2E * __expf(a4.y);
            A[4 * i + 2] = -LOG2E * __expf(a4.z); A[4 * i + 3] = -LOG2E * __expf(a4.w);
        }
    }
    float Dval = Dp[d];
    int bd = b * 12 + dblk;
    float h[16];
    {
        size_t base = ((size_t)dir * SGRID + (size_t)bd * SEG + s) * 16 * 64 + lane;
#pragma unroll
        for (int n = 0; n < 16; ++n) h[n] = bf2f(q_buf[base + (size_t)n * 64]);
    }

    for (int t = t0; t < t1; ++t) {
        const float* row = dbl + (mb + t) * 56;
        float dl = bf2f(din[(mb + t) * DI_ + d]);
        float xv = bf2f(xc[(mb + t) * DI_ + d]);
        float dlxv = dl * xv;
        const float4* pb = reinterpret_cast<const float4*>(row + 24);
        const float4* pc = reinterpret_cast<const float4*>(row + 40);
        float a0 = 0.f, a1 = 0.f, a2 = 0.f, a3 = 0.f;
#pragma unroll
        for (int j = 0; j < 4; ++j) {
            float4 B4 = pb[j], C4 = pc[j];
            float e0 = __builtin_amdgcn_exp2f(dl * A[4 * j + 0]);
            float e1 = __builtin_amdgcn_exp2f(dl * A[4 * j + 1]);
            float e2 = __builtin_amdgcn_exp2f(dl * A[4 * j + 2]);
            float e3 = __builtin_amdgcn_exp2f(dl * A[4 * j + 3]);
            h[4 * j + 0] = e0 * h[4 * j + 0] + dlxv * B4.x;
            h[4 * j + 1] = e1 * h[4 * j + 1] + dlxv * B4.y;
            h[4 * j + 2] = e2 * h[4 * j + 2] + dlxv * B4.z;
            h[4 * j + 3] = e3 * h[4 * j + 3] + dlxv * B4.w;
            a0 += h[4 * j + 0] * C4.x;
            a1 += h[4 * j + 1] * C4.y;
            a2 += h[4 * j + 2] * C4.z;
            a3 += h[4 * j + 3] * C4.w;
        }
        float y = (a0 + a1) + (a2 + a3) + xv * Dval;
        int lorig = dir ? (L_ - 1 - t) : t;
        y *= silu_f(bf2f(xz[(mb + lorig) * 1536 + 768 + d]));
        yb[(mb + lorig) * DI_ + d] = f2bf(y);
    }
}

// final: residual+hidden, rmsnorm, permute+slice, store bf16 or f32 per flag
__global__ __launch_bounds__(128) void final_kernel(
    const float* __restrict__ hidden, const float* __restrict__ resid,
    const float* __restrict__ w, void* __restrict__ out,
    const int* __restrict__ bad)
{
    int blk = blockIdx.x;
    int b = blk / 446, tok = blk % 446;
    int lorig; size_t dst;
    if (tok == 0)      { lorig = 247; dst = (size_t)b * D_; }
    else if (tok <= 14){ int j = tok - 1; lorig = 49 + j; dst = 6144 + ((size_t)b * 14 + j) * D_; }
    else               { int v = tok - 15; lorig = (v < 184) ? (63 + v) : (64 + v);
                         dst = 92160 + ((size_t)b * 431 + v) * D_; }
    size_t base = ((size_t)b * L_ + lorig) * D_;
    int tid = threadIdx.x;
    float v3[3]; float ss = 0.f;
#pragma unroll
    for (int i = 0; i < 3; ++i) {
        int c = tid + i * 128;
        float r = hidden[base + c] + resid[base + c];
        v3[i] = r; ss += r * r;
    }
    ss += __shfl_xor(ss, 32); ss += __shfl_xor(ss, 16); ss += __shfl_xor(ss, 8);
    ss += __shfl_xor(ss, 4);  ss += __shfl_xor(ss, 2);  ss += __shfl_xor(ss, 1);
    __shared__ float sred[2];
    if ((tid & 63) == 0) sred[tid >> 6] = ss;
    __syncthreads();
    float scale = rsqrtf((sred[0] + sred[1]) * (1.f / D_) + 1e-5f);
    int isbf = (*bad == 0);
#pragma unroll
    for (int i = 0; i < 3; ++i) {
        int c = tid + i * 128;
        float val = v3[i] * scale * w[c];
        if (isbf) ((u16*)out)[dst + c] = f2bf(val);
        else      ((float*)out)[dst + c] = val;
    }
}

extern "C" void kernel_launch(void* const* d_in, const int* in_sizes, int n_in,
                              void* d_out, int out_size, void* d_ws, size_t ws_size,
                              hipStream_t stream) {
    char* wsb = (char*)d_ws;
    int* bad = (int*)wsb;  wsb += 16;

    // canon (11): inW(bf16), cW, cB, xpW(bf16), dtW, dtB, Alog, Dsk, outW(bf16), nw, fnw
    const int cn[11] = {2359296, 24576, 6144, 344064, 147456, 6144, 98304,
                        6144, 1179648, 1536, 384};
    const int raw_idx[11] = {4, 5, 6, 7, 8, 9, 10, 11, 12, 13, 14};
    const int tobf[11]    = {1, 0, 0, 1, 0, 0, 0, 0, 1, 0, 0};
    void* canon[11];
    for (int i = 0; i < 11; ++i) {
        canon[i] = (void*)wsb;
        wsb += (size_t)cn[i] * (tobf[i] ? 2 : 4);
    }
    const u16*   inWb = (const u16*)canon[0];
    const float* cW   = (const float*)canon[1];
    const float* cB   = (const float*)canon[2];
    const u16*   xpWb = (const u16*)canon[3];
    const float* dtW  = (const float*)canon[4];
    const float* dtB  = (const float*)canon[5];
    const float* Alog = (const float*)canon[6];
    const float* Dsk  = (const float*)canon[7];
    const u16*   outWb= (const u16*)canon[8];
    const float* nw   = (const float*)canon[9];
    const float* fnw  = (const float*)canon[10];

    float* hidden = (float*)wsb;  wsb += (size_t)M_ * D_ * 4;
    float* resid  = (float*)wsb;  wsb += (size_t)M_ * D_ * 4;
    float* dbl2   = (float*)wsb;  wsb += (size_t)2 * M_ * 56 * 4;
    u16*   xz     = (u16*)wsb;    wsb += (size_t)M_ * 1536 * 2;
    u16*   xc2    = (u16*)wsb;    wsb += (size_t)2 * M_ * DI_ * 2;
    u16*   y0     = (u16*)wsb;    wsb += (size_t)M_ * DI_ * 2;           // hbf aliases
    u16*   P_buf  = (u16*)wsb;    wsb += (size_t)2 * SGRID * 16 * 64 * 2; // y1 aliases
    u16*   q_buf  = (u16*)wsb;    wsb += (size_t)2 * SGRID * 16 * 64 * 2;
    u16*   delta2 = (u16*)wsb;    wsb += (size_t)2 * M_ * DI_ * 2;       // 24.3MB (ws >=147MB proven)
    u16* hbf = y0;
    u16* y1  = P_buf;   // P dead after combine; part3 then writes y1

    hipMemsetAsync(bad, 0, 4, stream);
    detect_kernel<<<384, 256, 0, stream>>>((const u16*)d_in[10], bad);
    {
        CvtArgs ca;
        int maxn = 0;
        for (int i = 0; i < 11; ++i) {
            ca.src[i] = d_in[raw_idx[i]]; ca.dst[i] = canon[i];
            ca.n[i] = cn[i]; ca.tobf[i] = tobf[i];
            if (cn[i] > maxn) maxn = cn[i];
        }
        cvt_all_kernel<<<dim3((maxn + 255) / 256, 11), 256, 0, stream>>>(ca, bad);
    }

    build_hidden_kernel<<<(M_ * D_) / 256, 256, 0, stream>>>(
        d_in[0], d_in[2], d_in[3], hidden, bad);

    const int gmb = (M_ + 127) / 128;      // 62
    for (int l = 0; l < 4; ++l) {
        const float* dtWl = dtW + (size_t)l * 2 * DI_ * DTR_;
        const float* dtBl = dtB + (size_t)l * 2 * DI_;
        const float* All  = Alog + (size_t)l * 2 * DI_ * DS_;
        const float* Dl   = Dsk + (size_t)l * 2 * DI_;
        resnorm_kernel<<<M_, 128, 0, stream>>>(hidden, resid, nw + (size_t)l * D_, hbf, l == 0);
        gemm_mfma_bt<0, 0><<<dim3(gmb, 1536 / 128), 256, 0, stream>>>(
            hbf, nullptr, inWb + (size_t)l * 1536 * D_, xz, M_, 1536, D_, 1536, 1.f);
        conv_fused_kernel<<<B_ * CNCH, 384, 0, stream>>>(
            xz, cW + (size_t)l * 2 * DI_ * 4, cB + (size_t)l * 2 * DI_, xc2);
        xproj_gemm_kernel<<<dim3(gmb, 2), 256, 0, stream>>>(
            xc2, xpWb + (size_t)l * 2 * 56 * DI_, dbl2);
        dtproj_gemm_kernel<<<dim3(gmb, DI_ / 128, 2), 256, 0, stream>>>(
            dbl2, dtWl, dtBl, delta2);
        scan_part1_kernel<<<dim3(B_ * 3 * SEG, 2), 256, 0, stream>>>(
            xc2, dbl2, delta2, All, P_buf, q_buf);
        scan_combine_kernel<<<dim3(NBD, 4, 2), 64, 0, stream>>>(P_buf, q_buf);
        scan_part3_kernel<<<dim3(B_ * 3 * SEG, 2), 256, 0, stream>>>(
            xc2, dbl2, xz, All, Dl, q_buf, y0, y1, delta2);
        gemm_mfma_bt<1, 1><<<dim3(gmb, 384 / 128), 256, 0, stream>>>(
            y0, y1, outWb + (size_t)l * D_ * DI_, hidden, M_, 384, DI_, 384, 0.5f);
    }

    final_kernel<<<B_ * 446, 128, 0, stream>>>(hidden, resid, fnw, d_out, bad);
}